// Round 15
// baseline (311.836 us; speedup 1.0000x reference)
//
#include <hip/hip_runtime.h>
#include <hip/hip_bf16.h>
#include <math.h>
#include <stdint.h>

// ---- problem constants ----
static constexpr int B_    = 2;
static constexpr int N_    = 12544;   // 112*112
static constexpr int DIM_  = 512;
static constexpr int D0_   = 64;
static constexpr int DL_   = 448;
static constexpr int Himg  = 112;
static constexpr int Wimg  = 112;
static constexpr int HS_   = 56;
static constexpr int NR_   = 3136;    // 56*56
static constexpr int NH_   = 8;
static constexpr int HD_   = 28;
static constexpr int NSPLIT = 8;

typedef unsigned short ushort_t;
typedef __attribute__((ext_vector_type(8))) short short8_t;
typedef __attribute__((ext_vector_type(4))) float float4v;
typedef __attribute__((ext_vector_type(4))) unsigned uint4v;
typedef __attribute__((ext_vector_type(2))) unsigned uint2v;

// round-to-nearest-even f32 -> bf16
static __device__ inline ushort_t bf16r(float x) {
    unsigned u = __builtin_bit_cast(unsigned, x);
    u = (u + 0x7FFFu + ((u >> 16) & 1u)) >> 16;
    return (ushort_t)u;
}
static __device__ inline float bf16tof(ushort_t h) {
    unsigned u = ((unsigned)h) << 16;
    return __builtin_bit_cast(float, u);
}
// pack two f32 -> u32 of 2 bf16 (lo, hi) -- software RNE
static __device__ inline unsigned pack_bf16(float lo, float hi) {
    unsigned a = __builtin_bit_cast(unsigned, lo);
    unsigned b = __builtin_bit_cast(unsigned, hi);
    a = (a + 0x7FFFu + ((a >> 16) & 1u)) >> 16;
    b = (b + 0x7FFFu + ((b >> 16) & 1u)) >> 16;
    return a | (b << 16);
}
// HW v_cvt_pk_bf16_f32 path (RNE, identical bits) for VALU-bound kernels
static __device__ inline unsigned cvtpk(float lo, float hi) {
    float2 f2; f2.x = lo; f2.y = hi;
    __hip_bfloat162 h = __float22bfloat162_rn(f2);
    unsigned u;
    __builtin_memcpy(&u, &h, 4);
    return u;
}

using gptr_t = const __attribute__((address_space(1))) void*;
using lptr_t = __attribute__((address_space(3))) void*;
static __device__ inline void gload16(const void* g, void* l) {
    __builtin_amdgcn_global_load_lds((gptr_t)(uintptr_t)g, (lptr_t)(uintptr_t)l, 16, 0, 0);
}

// =====================================================================
// bf16 MFMA GEMM: C[M][ldc] = A[M][K](bf16) @ Bt[Npad][K](bf16)^T
// OUT16: write bf16 output (for q, consumed only by attention)
// =====================================================================
template<bool HASBIAS, bool OUT16>
__global__ __launch_bounds__(256, 2)
void gemm_bf16_kernel(const ushort_t* __restrict__ A,
                      const ushort_t* __restrict__ Bt,
                      const float* __restrict__ bias,
                      void* __restrict__ Cv,
                      int Nn, int K, int ldc) {
    constexpr int BM = 128, BK = 64;
    __shared__ __align__(16) ushort_t As[BM * BK];
    __shared__ __align__(16) ushort_t Bs[BM * BK];
    const int bm = blockIdx.x * BM;
    const int bn = blockIdx.y * BM;
    const int tid = threadIdx.x;
    const int l15 = tid & 15;
    const int g   = (tid & 63) >> 4;
    const int w   = tid >> 6;
    const int wr  = w >> 1, wc = w & 1;

    float4v acc[4][4];
    #pragma unroll
    for (int m = 0; m < 4; ++m)
        #pragma unroll
        for (int n = 0; n < 4; ++n) acc[m][n] = (float4v){0.f, 0.f, 0.f, 0.f};

    for (int k0 = 0; k0 < K; k0 += BK) {
        #pragma unroll
        for (int i = 0; i < 4; ++i) {
            int c = i * 256 + tid;
            int r = c >> 3, ch = c & 7;
            int sch = ch ^ (r & 7);
            gload16(A  + (size_t)(bm + r) * K + k0 + sch * 8, (void*)(As + c * 8));
            gload16(Bt + (size_t)(bn + r) * K + k0 + sch * 8, (void*)(Bs + c * 8));
        }
        __syncthreads();

        short8_t af[4][2], bfr[4][2];
        #pragma unroll
        for (int m = 0; m < 4; ++m) {
            int ar = wr * 64 + m * 16 + l15;
            #pragma unroll
            for (int h = 0; h < 2; ++h)
                af[m][h] = *(const short8_t*)((const char*)As + ar * 128 + (((h * 4 + g) ^ (ar & 7)) * 16));
        }
        #pragma unroll
        for (int n = 0; n < 4; ++n) {
            int br = wc * 64 + n * 16 + l15;
            #pragma unroll
            for (int h = 0; h < 2; ++h)
                bfr[n][h] = *(const short8_t*)((const char*)Bs + br * 128 + (((h * 4 + g) ^ (br & 7)) * 16));
        }
        #pragma unroll
        for (int m = 0; m < 4; ++m)
            #pragma unroll
            for (int n = 0; n < 4; ++n) {
                acc[m][n] = __builtin_amdgcn_mfma_f32_16x16x32_bf16(af[m][0], bfr[n][0], acc[m][n], 0, 0, 0);
                acc[m][n] = __builtin_amdgcn_mfma_f32_16x16x32_bf16(af[m][1], bfr[n][1], acc[m][n], 0, 0, 0);
            }
        __syncthreads();
    }

    #pragma unroll
    for (int n = 0; n < 4; ++n) {
        int ccol = bn + wc * 64 + n * 16 + l15;
        if (ccol < Nn) {
            float bv = HASBIAS ? bias[ccol] : 0.f;
            #pragma unroll
            for (int m = 0; m < 4; ++m) {
                int crow = bm + wr * 64 + m * 16 + g * 4;
                #pragma unroll
                for (int j = 0; j < 4; ++j) {
                    float v = acc[m][n][j] + bv;
                    if (OUT16)
                        ((ushort_t*)Cv)[(size_t)(crow + j) * ldc + ccol] = bf16r(v);
                    else
                        ((float*)Cv)[(size_t)(crow + j) * ldc + ccol] = v;
                }
            }
        }
    }
}

// =====================================================================
// weight convert: Wt[Npad][K] bf16 from W
// =====================================================================
__global__ __launch_bounds__(256)
void convw_kernel(const float* __restrict__ W, ushort_t* __restrict__ Wt,
                  int K, int Nn, int transpose) {
    int idx = blockIdx.x * 256 + threadIdx.x;
    int n = idx / K, k = idx % K;
    float v = 0.f;
    if (n < Nn) v = transpose ? W[(size_t)k * Nn + n] : W[(size_t)n * K + k];
    Wt[idx] = bf16r(v);
}

// sr_w transpose: wT[f][o] = sr_w[o*256 + f]
__global__ __launch_bounds__(256)
void srwt_kernel(const float* __restrict__ W, float* __restrict__ wT) {
    int idx = blockIdx.x * 256 + threadIdx.x;
    int f = idx >> 6, o = idx & 63;
    wT[idx] = W[o * 256 + f];
}

// fp32 -> bf16 bulk convert, 8 elems/thread
__global__ __launch_bounds__(256)
void convx_kernel(const float* __restrict__ in, ushort_t* __restrict__ outp) {
    int i = blockIdx.x * 256 + threadIdx.x;
    const float4v* p = (const float4v*)(in + (size_t)i * 8);
    float4v a = p[0], b = p[1];
    uint4v u;
    u[0] = pack_bf16(a[0], a[1]);
    u[1] = pack_bf16(a[2], a[3]);
    u[2] = pack_bf16(b[0], b[1]);
    u[3] = pack_bf16(b[2], b[3]);
    *(uint4v*)(outp + (size_t)i * 8) = u;
}

// =====================================================================
// sr-conv (coalesced wT) + LayerNorm(64) + kv GEMM (64->128)
// K written as bf16 PRE-SCALED by 0.125*log2(e)
// =====================================================================
__global__ __launch_bounds__(64)
void srlnkv_kernel(const float* __restrict__ x,
                   const float* __restrict__ wT, const float* __restrict__ sr_b,
                   const float* __restrict__ ln_g, const float* __restrict__ ln_b,
                   const float* __restrict__ wkv,
                   ushort_t* __restrict__ kgb, float* __restrict__ vg) {
    const int pos = blockIdx.x;
    const int b = pos / NR_, n = pos % NR_;
    const int y = n / HS_, xx = n % HS_;
    const int o = threadIdx.x;
    __shared__ float xs[4][64];
    __shared__ float lnv_s[64];
    #pragma unroll
    for (int tap = 0; tap < 4; ++tap) {
        int ky = tap / 2, kx = tap % 2;
        xs[tap][o] = x[((size_t)b * N_ + (2 * y + ky) * Wimg + 2 * xx + kx) * DIM_ + o];
    }
    __syncthreads();
    float sum = sr_b[o];
    for (int i = 0; i < 64; ++i) {
        const float* wr = wT + (i * 4) * 64 + o;
        sum += xs[0][i] * wr[0] + xs[1][i] * wr[64] + xs[2][i] * wr[128] + xs[3][i] * wr[192];
    }
    float m = sum;
    #pragma unroll
    for (int off = 1; off < 64; off <<= 1) m += __shfl_xor(m, off);
    m *= (1.0f / 64.0f);
    float d = sum - m;
    float v = d * d;
    #pragma unroll
    for (int off = 1; off < 64; off <<= 1) v += __shfl_xor(v, off);
    v *= (1.0f / 64.0f);
    float lnv = d * rsqrtf(v + 1e-5f) * ln_g[o] + ln_b[o];
    lnv_s[o] = lnv;
    __syncthreads();
    float s0 = 0.f, s1 = 0.f;
    for (int i = 0; i < 64; ++i) {
        float lv = lnv_s[i];
        s0 += lv * wkv[i * 128 + o];
        s1 += lv * wkv[i * 128 + o + 64];
    }
    const float SCK = 0.125f * 1.44269504088896340736f;
    kgb[((size_t)b * NR_ + n) * 64 + o] = bf16r(s0 * SCK);
    vg[((size_t)b * NR_ + n) * 64 + o] = s1;
}

// =====================================================================
// depthwise 3x3 + bias on v_g image; vg2 = vg + conv (fp32)
// =====================================================================
__global__ __launch_bounds__(256)
void lcg_kernel(const float* __restrict__ vg, const float* __restrict__ w,
                const float* __restrict__ bias, float* __restrict__ vg2) {
    int idx = blockIdx.x * 256 + threadIdx.x;
    if (idx >= B_ * NR_ * 64) return;
    int c = idx % 64;
    int n = (idx / 64) % NR_;
    int b = idx / (64 * NR_);
    int y = n / HS_, xx = n % HS_;
    float sum = vg[idx] + bias[c];
    #pragma unroll
    for (int ky = 0; ky < 3; ++ky)
        #pragma unroll
        for (int kx = 0; kx < 3; ++kx) {
            int yy = y + ky - 1, x2 = xx + kx - 1;
            if (yy >= 0 && yy < HS_ && x2 >= 0 && x2 < HS_)
                sum += vg[((size_t)b * NR_ + yy * HS_ + x2) * 64 + c] * w[c * 9 + ky * 3 + kx];
        }
    vg2[idx] = sum;
}

// =====================================================================
// transpose+convert: vg2 fp32 [B][NR][64] -> vtb bf16 [B][64][NR]
// =====================================================================
__global__ __launch_bounds__(256)
void vtrans_kernel(const float* __restrict__ vg2, ushort_t* __restrict__ vtb) {
    __shared__ float ld[64][65];
    const int b = blockIdx.y, n0 = blockIdx.x * 64, tid = threadIdx.x;
    #pragma unroll
    for (int i = 0; i < 16; ++i) {
        int idx = i * 256 + tid;
        int n = idx >> 6, c = idx & 63;
        ld[n][c] = vg2[((size_t)b * NR_ + n0 + n) * 64 + c];
    }
    __syncthreads();
    #pragma unroll
    for (int i = 0; i < 16; ++i) {
        int idx = i * 256 + tid;
        int d = idx >> 6, nn = idx & 63;
        vtb[(size_t)(b * 64 + d) * NR_ + n0 + nn] = bf16r(ld[nn][d]);
    }
}

// =====================================================================
// Global-branch flash attention, split-K=8, bf16 MFMA, register-PV via
// K row-permutation pi. Q raw bf16 (K pre-scaled). osp stored bf16.
// =====================================================================
__global__ __launch_bounds__(256)
void attn_global_split2(const ushort_t* __restrict__ q16,
                        const ushort_t* __restrict__ kgb,
                        const ushort_t* __restrict__ vtb,
                        ushort_t* __restrict__ osp16, float* __restrict__ mls) {
    __shared__ __align__(16) ushort_t Ks[64 * 64];
    __shared__ __align__(16) ushort_t Vs[64 * 64];
    const int split = blockIdx.y & 7;
    const int b     = blockIdx.y >> 3;
    const int q0    = blockIdx.x * 64;
    const int tid   = threadIdx.x;
    const int w     = tid >> 6;
    const int l     = tid & 63;
    const int l15   = l & 15;
    const int g     = l >> 4;
    const int lx    = l15 & 7;

    // Q fragments: raw bf16 loads (scale folded into K producer)
    short8_t qf[2];
    {
        const ushort_t* qrow = q16 + ((size_t)b * N_ + q0 + w * 16 + l15) * DIM_;
        qf[0] = *(const short8_t*)(qrow + g * 8);
        qf[1] = *(const short8_t*)(qrow + g * 8 + 32);
    }

    float4v o[4];
    #pragma unroll
    for (int i = 0; i < 4; ++i) o[i] = (float4v){0.f, 0.f, 0.f, 0.f};
    float m_run = -3.0e38f, l_run = 0.f;

    const int t0 = (split * 49) / 8;
    const int t1 = ((split + 1) * 49) / 8;
    for (int t = t0; t < t1; ++t) {
        const int k0 = t * 64;
        #pragma unroll
        for (int i = 0; i < 2; ++i) {
            int c = i * 256 + tid;
            int r = c >> 3, ch = c & 7;
            int sch = ch ^ (r & 7);
            int pr = (r & 32) | (((r >> 2) & 3) << 3) | (((r >> 4) & 1) << 2) | (r & 3);
            gload16(kgb + ((size_t)(b * NR_ + k0 + pr) << 6) + sch * 8, (void*)(Ks + c * 8));
            gload16(vtb + (size_t)(b * 64 + r) * NR_ + k0 + sch * 8, (void*)(Vs + c * 8));
        }
        __syncthreads();

        float4v sc[4];
        #pragma unroll
        for (int c = 0; c < 4; ++c) {
            float4v acc = (float4v){0.f, 0.f, 0.f, 0.f};
            #pragma unroll
            for (int dc = 0; dc < 2; ++dc) {
                int row = c * 16 + l15;
                short8_t ak = *(const short8_t*)((const char*)Ks + row * 128 + (((g + 4 * dc) ^ lx) * 16));
                acc = __builtin_amdgcn_mfma_f32_16x16x32_bf16(ak, qf[dc], acc, 0, 0, 0);
            }
            sc[c] = acc;
        }

        float tmax = fmaxf(fmaxf(fmaxf(sc[0][0], sc[0][1]), fmaxf(sc[0][2], sc[0][3])),
                           fmaxf(fmaxf(sc[1][0], sc[1][1]), fmaxf(sc[1][2], sc[1][3])));
        tmax = fmaxf(tmax, fmaxf(fmaxf(fmaxf(sc[2][0], sc[2][1]), fmaxf(sc[2][2], sc[2][3])),
                                 fmaxf(fmaxf(sc[3][0], sc[3][1]), fmaxf(sc[3][2], sc[3][3]))));
        tmax = fmaxf(tmax, __shfl_xor(tmax, 16));
        tmax = fmaxf(tmax, __shfl_xor(tmax, 32));

        if (__any(tmax > m_run + 11.0f)) {
            float m_new = fmaxf(m_run, tmax);
            float corr = __builtin_amdgcn_exp2f(m_run - m_new);
            float co[4];
            #pragma unroll
            for (int r = 0; r < 4; ++r) co[r] = __shfl(corr, g * 4 + r);
            #pragma unroll
            for (int dc = 0; dc < 4; ++dc)
                #pragma unroll
                for (int r = 0; r < 4; ++r) o[dc][r] *= co[r];
            l_run *= corr;
            m_run = m_new;
        }

        float p[4][4];
        float ladd = 0.f;
        #pragma unroll
        for (int c = 0; c < 4; ++c)
            #pragma unroll
            for (int r = 0; r < 4; ++r) {
                float pe = __builtin_amdgcn_exp2f(sc[c][r] - m_run);
                p[c][r] = pe;
                ladd += pe;
            }
        ladd += __shfl_xor(ladd, 16);
        ladd += __shfl_xor(ladd, 32);
        l_run += ladd;

        #pragma unroll
        for (int kkc = 0; kkc < 2; ++kkc) {
            uint4v au;
            au[0] = cvtpk(p[2 * kkc][0],     p[2 * kkc][1]);
            au[1] = cvtpk(p[2 * kkc][2],     p[2 * kkc][3]);
            au[2] = cvtpk(p[2 * kkc + 1][0], p[2 * kkc + 1][1]);
            au[3] = cvtpk(p[2 * kkc + 1][2], p[2 * kkc + 1][3]);
            short8_t ap = __builtin_bit_cast(short8_t, au);
            #pragma unroll
            for (int dc = 0; dc < 4; ++dc) {
                int vrow = dc * 16 + l15;
                short8_t bv = *(const short8_t*)((const char*)Vs + vrow * 128 + (((kkc * 4 + g) ^ lx) * 16));
                o[dc] = __builtin_amdgcn_mfma_f32_16x16x32_bf16(ap, bv, o[dc], 0, 0, 0);
            }
        }
        __syncthreads();
    }

    const size_t rbase = (size_t)(split * B_ + b) * N_;
    #pragma unroll
    for (int dc = 0; dc < 4; ++dc)
        #pragma unroll
        for (int r = 0; r < 4; ++r) {
            int row = q0 + w * 16 + g * 4 + r;
            osp16[(rbase + row) * 64 + dc * 16 + l15] = bf16r(o[dc][r]);
        }
    if (l < 16) {
        int row = q0 + w * 16 + l15;
        mls[(rbase + row) * 2]     = m_run;
        mls[(rbase + row) * 2 + 1] = l_run;
    }
}

// =====================================================================
// combine the 8 splits (exp2 domain, bf16 osp) -> catb cols [0,64)
// =====================================================================
__global__ __launch_bounds__(256)
void attn_combine(const ushort_t* __restrict__ osp16, const float* __restrict__ mls,
                  ushort_t* __restrict__ catb) {
    int idx = blockIdx.x * 256 + threadIdx.x;
    int col = idx & 63;
    size_t rn = (size_t)(idx >> 6);
    const size_t BN = (size_t)B_ * N_;
    float ms[NSPLIT], ls[NSPLIT];
    float m = -3.0e38f;
    #pragma unroll
    for (int s = 0; s < NSPLIT; ++s) {
        ms[s] = mls[(s * BN + rn) * 2];
        ls[s] = mls[(s * BN + rn) * 2 + 1];
        m = fmaxf(m, ms[s]);
    }
    float lsum = 0.f, acc = 0.f;
    #pragma unroll
    for (int s = 0; s < NSPLIT; ++s) {
        float wgt = __builtin_amdgcn_exp2f(ms[s] - m);
        lsum += ls[s] * wgt;
        acc  += bf16tof(osp16[(s * BN + rn) * 64 + col]) * wgt;
    }
    catb[rn * DIM_ + col] = bf16r(acc / lsum);
}

// =====================================================================
// depthwise 3x3 + bias on x_l, vectorized: 4 channels x 4 y-rows / thread
// =====================================================================
__global__ __launch_bounds__(256)
void dwt_kernel(const float* __restrict__ x, const float* __restrict__ w,
                const float* __restrict__ bias, ushort_t* __restrict__ out) {
    int idx = blockIdx.x * 256 + threadIdx.x;
    int c4 = idx % 112;
    int t1 = idx / 112;
    int xx = t1 % 112;
    int t2 = t1 / 112;
    int yg = t2 % 28;
    int b  = t2 / 28;
    int c0 = c4 * 4;
    int y0 = yg * 4;

    float4v w4[9];
    #pragma unroll
    for (int kt = 0; kt < 9; ++kt) {
        w4[kt][0] = w[(c0 + 0) * 9 + kt];
        w4[kt][1] = w[(c0 + 1) * 9 + kt];
        w4[kt][2] = w[(c0 + 2) * 9 + kt];
        w4[kt][3] = w[(c0 + 3) * 9 + kt];
    }
    float4v bv = *(const float4v*)(bias + c0);
    float4v acc[4];
    #pragma unroll
    for (int o2 = 0; o2 < 4; ++o2) acc[o2] = bv;

    #pragma unroll
    for (int yy = 0; yy < 6; ++yy) {
        int Y = y0 - 1 + yy;
        if (Y < 0 || Y >= Himg) continue;
        #pragma unroll
        for (int xt = 0; xt < 3; ++xt) {
            int X = xx - 1 + xt;
            if (X < 0 || X >= Wimg) continue;
            float4v v = *(const float4v*)(x + ((size_t)b * N_ + Y * Wimg + X) * DIM_ + D0_ + c0);
            constexpr int olo_t[6] = {0, 0, 0, 1, 2, 3};
            constexpr int ohi_t[6] = {0, 1, 2, 3, 3, 3};
            #pragma unroll
            for (int o2 = olo_t[yy]; o2 <= ohi_t[yy]; ++o2) {
                float4v wv = w4[(yy - o2) * 3 + xt];
                acc[o2][0] += v[0] * wv[0];
                acc[o2][1] += v[1] * wv[1];
                acc[o2][2] += v[2] * wv[2];
                acc[o2][3] += v[3] * wv[3];
            }
        }
    }
    #pragma unroll
    for (int o2 = 0; o2 < 4; ++o2) {
        uint2v pk;
        pk[0] = pack_bf16(acc[o2][0], acc[o2][1]);
        pk[1] = pack_bf16(acc[o2][2], acc[o2][3]);
        *(uint2v*)(out + ((size_t)b * N_ + (y0 + o2) * Wimg + xx) * DL_ + c0) = pk;
    }
}

// =====================================================================
// "scrambled mean", block-parallel: one block per (b,h,n).
// =====================================================================
template<int L, int NBW, int STRIDE, int DIL, int CHOFF>
__global__ void local_mean2_kernel(const float* __restrict__ kvl,
                                   float* __restrict__ kvm) {
    __shared__ float slo[L], shi[L];
    const int blk = blockIdx.x;
    const int n = blk % 49;
    const int h = (blk / 49) % NH_;
    const int b = blk / (49 * NH_);
    const int wy = n / 7, wx = n % 7;
    const int t = threadIdx.x;

    if (t < L) {
        const int by = t / NBW, bx = t % NBW;
        int Y = by * STRIDE + DIL * wy;
        int X = bx * STRIDE + DIL * wx;
        if (Y >= Himg) Y = 2 * Himg - 2 - Y;
        if (X >= Wimg) X = 2 * Wimg - 2 - X;
        const float* src = kvl + ((size_t)b * N_ + Y * Wimg + X) * DL_ + CHOFF + h * HD_;
        float v[28];
        #pragma unroll
        for (int i = 0; i < 7; ++i) {
            float4v q4 = ((const float4v*)src)[i];
            v[i * 4] = q4[0]; v[i * 4 + 1] = q4[1]; v[i * 4 + 2] = q4[2]; v[i * 4 + 3] = q4[3];
        }
        const int f0 = t * HD_;
        const int bin0 = f0 / L;
        const int nlo = min(HD_, (bin0 + 1) * L - f0);
        float s0 = 0.f, s1 = 0.f;
        #pragma unroll
        for (int j = 0; j < HD_; ++j) {
            if (j < nlo) s0 += v[j]; else s1 += v[j];
        }
        slo[t] = s0;
        shi[t] = s1;
    }
    __syncthreads();
    if (t < HD_) {
        const int t_lo = (t * L) / HD_;
        const int t_hi = min(L - 1, (t * L + L - 1) / HD_);
        float sum = 0.f;
        for (int u = t_lo; u <= t_hi; ++u) {
            int f0 = u * HD_;
            int b0 = f0 / L;
            int b1 = (f0 + HD_ - 1) / L;
            if (b0 == t) sum += slo[u];
            if (b1 == t && b1 != b0) sum += shi[u];
        }
        kvm[(size_t)blk * HD_ + t] = sum * (1.0f / (float)L);
    }
}

// =====================================================================
// kv = kvm @ fc_w @ sh_w -> (B*NH, 49, 56)
// =====================================================================
__global__ __launch_bounds__(64)
void fcsh_kernel(const float* __restrict__ kvm, const float* __restrict__ fcw,
                 const float* __restrict__ shw, float* __restrict__ out) {
    int bh = blockIdx.x;
    __shared__ float kin[49][28];
    __shared__ float tmp[49][28];
    __shared__ float fw[28 * 28];
    __shared__ float sw[28 * 56];
    int t = threadIdx.x;
    for (int i = t; i < 49 * 28; i += 64) kin[i / 28][i % 28] = kvm[bh * 49 * 28 + i];
    for (int i = t; i < 28 * 28; i += 64) fw[i] = fcw[i];
    for (int i = t; i < 28 * 56; i += 64) sw[i] = shw[i];
    __syncthreads();
    for (int i = t; i < 49 * 28; i += 64) {
        int rr = i / 28, j = i % 28;
        float s = 0.f;
        for (int k = 0; k < 28; ++k) s += kin[rr][k] * fw[k * 28 + j];
        tmp[rr][j] = s;
    }
    __syncthreads();
    for (int i = t; i < 49 * 56; i += 64) {
        int rr = i / 56, j = i % 56;
        float s = 0.f;
        for (int k = 0; k < 28; ++k) s += tmp[rr][k] * sw[k * 56 + j];
        out[bh * 49 * 56 + i] = s;
    }
}

// =====================================================================
// v_ + depthwise3x3(v_img 7x7) + bias -> vc (B*NH, 49, 28)
// =====================================================================
__global__ __launch_bounds__(256)
void vconv_kernel(const float* __restrict__ kvsh, const float* __restrict__ w,
                  const float* __restrict__ bias, float* __restrict__ vc) {
    int idx = blockIdx.x * 256 + threadIdx.x;
    if (idx >= B_ * NH_ * 49 * HD_) return;
    int d  = idx % HD_;
    int n  = (idx / HD_) % 49;
    int bh = idx / (HD_ * 49);
    int h  = bh % NH_;
    int y = n / 7, xx = n % 7;
    int c = h * HD_ + d;
    float sum = kvsh[(bh * 49 + n) * 56 + 28 + d] + bias[c];
    #pragma unroll
    for (int ky = 0; ky < 3; ++ky)
        #pragma unroll
        for (int kx = 0; kx < 3; ++kx) {
            int yy = y + ky - 1, x2 = xx + kx - 1;
            if (yy >= 0 && yy < 7 && x2 >= 0 && x2 < 7)
                sum += kvsh[(bh * 49 + yy * 7 + x2) * 56 + 28 + d] * w[c * 9 + ky * 3 + kx];
        }
    vc[idx] = sum;
}

// =====================================================================
// Local attention via MFMA, both branches fused. One block = 64 q-rows
// of one (b,h,branch). K pre-scaled by 28^-0.5*log2e at staging; Q raw
// bf16 (g==3 upper half zeroed; K d-pad is zero).
// =====================================================================
__global__ __launch_bounds__(256)
void attn_local_mfma(const ushort_t* __restrict__ q16,
                     const float* __restrict__ kv1, const float* __restrict__ v1c,
                     const float* __restrict__ kv2, const float* __restrict__ v2c,
                     ushort_t* __restrict__ catb) {
    __shared__ __align__(16) ushort_t Ks[64 * 32];   // [pi-row][d pad32]
    __shared__ __align__(16) ushort_t Vt[32 * 64];   // [d pad32][kcol pad64]
    const int ybh    = blockIdx.y;          // 0..31
    const int branch = ybh & 1;
    const int bh     = ybh >> 1;            // b*NH + h
    const int b      = bh >> 3, h = bh & 7;
    const int q0     = blockIdx.x * 64;
    const int tid    = threadIdx.x;
    const int w      = tid >> 6;
    const int l      = tid & 63;
    const int l15    = l & 15;
    const int g      = l >> 4;
    const float SC2K = 0.1889822365046136f * 1.44269504088896340736f; // 28^-.5 * log2e

    const float* kvsh = branch ? kv2 : kv1;
    const float* vc   = branch ? v2c : v1c;
    const int qoff    = D0_ + h * 56 + branch * 28;
    const int outoff  = (branch ? D0_ + 224 : D0_) + h * HD_;

    // ---- stage K (pre-scaled): LDS row r <- kcol pi(r), d padded to 32 ----
    {
        int row = tid >> 2, lc = tid & 3;
        int pr = (row & 32) | (((row >> 2) & 3) << 3) | (((row >> 4) & 1) << 2) | (row & 3);
        uint4v u = (uint4v){0u, 0u, 0u, 0u};
        if (pr < 49) {
            const float* src = kvsh + (bh * 49 + pr) * 56 + lc * 8;
            float vv[8];
            #pragma unroll
            for (int j2 = 0; j2 < 8; ++j2)
                vv[j2] = (lc * 8 + j2 < 28) ? src[j2] * SC2K : 0.f;
            u[0] = cvtpk(vv[0], vv[1]);
            u[1] = cvtpk(vv[2], vv[3]);
            u[2] = cvtpk(vv[4], vv[5]);
            u[3] = cvtpk(vv[6], vv[7]);
        }
        *(uint4v*)(Ks + row * 32 + (lc ^ (row & 3)) * 8) = u;
    }
    // ---- stage Vt[d][kcol] ----
    {
        int row = tid >> 3, lc = tid & 7;
        uint4v u = (uint4v){0u, 0u, 0u, 0u};
        if (row < 28) {
            float vv[8];
            #pragma unroll
            for (int j2 = 0; j2 < 8; ++j2) {
                int kc = lc * 8 + j2;
                vv[j2] = (kc < 49) ? vc[(bh * 49 + kc) * 28 + row] : 0.f;
            }
            u[0] = cvtpk(vv[0], vv[1]);
            u[1] = cvtpk(vv[2], vv[3]);
            u[2] = cvtpk(vv[4], vv[5]);
            u[3] = cvtpk(vv[6], vv[7]);
        }
        *(uint4v*)(Vt + row * 64 + (lc ^ (row & 7)) * 8) = u;
    }
    // ---- Q fragment: raw bf16 (8B loads; g==3 upper half zero) ----
    short8_t qf;
    {
        const ushort_t* qp = q16 + ((size_t)b * N_ + q0 + w * 16 + l15) * DIM_ + qoff + g * 8;
        uint2v a01 = *(const uint2v*)qp;
        uint2v a23 = (g < 3) ? *(const uint2v*)(qp + 4) : (uint2v){0u, 0u};
        uint4v uv;
        uv[0] = a01[0]; uv[1] = a01[1]; uv[2] = a23[0]; uv[3] = a23[1];
        qf = __builtin_bit_cast(short8_t, uv);
    }
    __syncthreads();

    // ---- scores ----
    float4v sc4[4];
    #pragma unroll
    for (int c = 0; c < 4; ++c) {
        int row = c * 16 + l15;
        short8_t ak = *(const short8_t*)(Ks + row * 32 + ((g ^ (row & 3)) * 8));
        float4v acc = (float4v){0.f, 0.f, 0.f, 0.f};
        sc4[c] = __builtin_amdgcn_mfma_f32_16x16x32_bf16(ak, qf, acc, 0, 0, 0);
    }

    // ---- softmax over 49 keys ----
    float tmax = fmaxf(fmaxf(fmaxf(sc4[0][0], sc4[0][1]), fmaxf(sc4[0][2], sc4[0][3])),
                       fmaxf(fmaxf(sc4[1][0], sc4[1][1]), fmaxf(sc4[1][2], sc4[1][3])));
    tmax = fmaxf(tmax, fmaxf(fmaxf(fmaxf(sc4[2][0], sc4[2][1]), fmaxf(sc4[2][2], sc4[2][3])),
                             fmaxf(fmaxf(sc4[3][0], sc4[3][1]), fmaxf(sc4[3][2], sc4[3][3]))));
    tmax = fmaxf(tmax, __shfl_xor(tmax, 16));
    tmax = fmaxf(tmax, __shfl_xor(tmax, 32));

    float p[4][4];
    float lsum = 0.f;
    #pragma unroll
    for (int c = 0; c < 4; ++c)
        #pragma unroll
        for (int r = 0; r < 4; ++r) {
            float pe = __builtin_amdgcn_exp2f(sc4[c][r] - tmax);
            if (c >= 2 && (8 * g + 4 * (c & 1) + r) >= 17) pe = 0.f;
            p[c][r] = pe;
            lsum += pe;
        }
    lsum += __shfl_xor(lsum, 16);
    lsum += __shfl_xor(lsum, 32);
    float inv = 1.0f / lsum;

    // ---- PV ----
    float4v o2[2];
    o2[0] = (float4v){0.f, 0.f, 0.f, 0.f};
    o2[1] = (float4v){0.f, 0.f, 0.f, 0.f};
    #pragma unroll
    for (int kkc = 0; kkc < 2; ++kkc) {
        uint4v au;
        au[0] = cvtpk(p[2 * kkc][0],     p[2 * kkc][1]);
        au[1] = cvtpk(p[2 * kkc][2],     p[2 * kkc][3]);
        au[2] = cvtpk(p[2 * kkc + 1][0], p[2 * kkc + 1][1]);
        au[3] = cvtpk(p[2 * kkc + 1][2], p[2 * kkc + 1][3]);
        short8_t ap = __builtin_bit_cast(short8_t, au);
        #pragma unroll
        for (int dc = 0; dc < 2; ++dc) {
            int vrow = dc * 16 + l15;
            short8_t bv = *(const short8_t*)(Vt + vrow * 64 + (((kkc * 4 + g) ^ (vrow & 7)) * 8));
            o2[dc] = __builtin_amdgcn_mfma_f32_16x16x32_bf16(ap, bv, o2[dc], 0, 0, 0);
        }
    }

    // ---- normalize + store (d < 28) ----
    float irow[4];
    #pragma unroll
    for (int r = 0; r < 4; ++r) irow[r] = __shfl(inv, g * 4 + r);
    #pragma unroll
    for (int dc = 0; dc < 2; ++dc) {
        int d = dc * 16 + l15;
        if (d < 28) {
            #pragma unroll
            for (int r = 0; r < 4; ++r) {
                int row = q0 + w * 16 + g * 4 + r;
                catb[((size_t)b * N_ + row) * DIM_ + outoff + d] = bf16r(o2[dc][r] * irow[r]);
            }
        }
    }
}

// =====================================================================
extern "C" void kernel_launch(void* const* d_in, const int* in_sizes, int n_in,
                              void* d_out, int out_size, void* d_ws, size_t ws_size,
                              hipStream_t stream) {
    const float* x      = (const float*)d_in[0];
    const float* Wq     = (const float*)d_in[1];
    const float* Wkv_g  = (const float*)d_in[2];
    const float* sr_w   = (const float*)d_in[3];
    const float* sr_b   = (const float*)d_in[4];
    const float* ln_g   = (const float*)d_in[5];
    const float* ln_b   = (const float*)d_in[6];
    const float* lcg_w  = (const float*)d_in[7];
    const float* lcg_b  = (const float*)d_in[8];
    const float* kvl_dw = (const float*)d_in[9];
    const float* kvl_db = (const float*)d_in[10];
    const float* kvl_pw = (const float*)d_in[11];
    const float* kvl_pb = (const float*)d_in[12];
    const float* fc1_w  = (const float*)d_in[13];
    const float* sh1_w  = (const float*)d_in[14];
    const float* lc1_w  = (const float*)d_in[15];
    const float* lc1_b  = (const float*)d_in[16];
    const float* fc2_w  = (const float*)d_in[17];
    const float* sh2_w  = (const float*)d_in[18];
    const float* lc2_w  = (const float*)d_in[19];
    const float* lc2_b  = (const float*)d_in[20];
    const float* proj_w = (const float*)d_in[21];
    const float* proj_b = (const float*)d_in[22];
    float* out = (float*)d_out;
    char* base = (char*)d_ws;

    // ---- workspace layout (256B aligned) ----
    size_t o = 0;
    auto alloc = [&](size_t bytes) -> void* {
        void* p = base + o;
        o = (o + bytes + 255) & ~(size_t)255;
        return p;
    };
    ushort_t* q16   = (ushort_t*)alloc((size_t)B_ * N_ * DIM_ * 2);
    float*    kvl   = (float*)   alloc((size_t)B_ * N_ * DL_ * 4);   // later osp16+mls
    ushort_t* xcat  = (ushort_t*)alloc((size_t)B_ * N_ * DIM_ * 2);  // xbf, then cat
    ushort_t* dwtb  = (ushort_t*)alloc((size_t)B_ * N_ * DL_ * 2);
    ushort_t* kgb   = (ushort_t*)alloc((size_t)B_ * NR_ * 64 * 2);
    float*    vg    = (float*)   alloc((size_t)B_ * NR_ * 64 * 4);
    float*    vg2   = (float*)   alloc((size_t)B_ * NR_ * 64 * 4);
    ushort_t* vtb   = (ushort_t*)alloc((size_t)B_ * 64 * NR_ * 2);
    ushort_t* wqt   = (ushort_t*)alloc((size_t)512 * 512 * 2);
    ushort_t* pwt   = (ushort_t*)alloc((size_t)512 * 448 * 2);
    ushort_t* projt = (ushort_t*)alloc((size_t)512 * 512 * 2);
    float*    srwt  = (float*)   alloc((size_t)256 * 64 * 4);
    float*    kvm1  = (float*)   alloc((size_t)B_ * NH_ * 49 * HD_ * 4);
    float*    kvm2  = (float*)   alloc((size_t)B_ * NH_ * 49 * HD_ * 4);
    float*    kv1   = (float*)   alloc((size_t)B_ * NH_ * 49 * 56 * 4);
    float*    kv2   = (float*)   alloc((size_t)B_ * NH_ * 49 * 56 * 4);
    float*    v1c   = (float*)   alloc((size_t)B_ * NH_ * 49 * HD_ * 4);
    float*    v2c   = (float*)   alloc((size_t)B_ * NH_ * 49 * HD_ * 4);
    ushort_t* xbf  = xcat;
    ushort_t* catb = xcat;
    // osp16/mls alias kvl (consumed by local_mean before attention runs)
    ushort_t* osp16 = (ushort_t*)kvl;                         // NSPLIT*B*N*64 bf16
    float*    mls   = (float*)((char*)kvl + (size_t)NSPLIT * B_ * N_ * 64 * 2);

    const int M = B_ * N_;   // 25088

    // 0. weight converts + x -> bf16
    convw_kernel<<<512 * 512 / 256, 256, 0, stream>>>(Wq, wqt, 512, 512, 1);
    convw_kernel<<<512 * 448 / 256, 256, 0, stream>>>(kvl_pw, pwt, 448, 448, 0);
    convw_kernel<<<512 * 512 / 256, 256, 0, stream>>>(proj_w, projt, 512, 512, 1);
    srwt_kernel<<<64, 256, 0, stream>>>(sr_w, srwt);
    convx_kernel<<<(B_ * N_ * DIM_ / 8) / 256, 256, 0, stream>>>(x, xbf);

    // 1. q16 = bf16(x @ Wq)
    gemm_bf16_kernel<false, true><<<dim3(M / 128, 4), 256, 0, stream>>>(
        xbf, wqt, nullptr, q16, 512, 512, 512);

    // 2. depthwise on x_l -> dwtb (bf16)
    dwt_kernel<<<(B_ * 28 * 112 * 112) / 256, 256, 0, stream>>>(x, kvl_dw, kvl_db, dwtb);

    // 3. pointwise: kvl = dwtb @ pwt^T + pb
    gemm_bf16_kernel<true, false><<<dim3(M / 128, 4), 256, 0, stream>>>(
        dwtb, pwt, kvl_pb, kvl, 448, 448, 448);

    // 4. global branch: sr conv + LN + kv (K bf16, pre-scaled exp2 domain)
    srlnkv_kernel<<<B_ * NR_, 64, 0, stream>>>(x, srwt, sr_b, ln_g, ln_b, Wkv_g, kgb, vg);

    // 5. vg2 = vg + depthwise(vg); then transpose+convert to vtb
    lcg_kernel<<<(B_ * NR_ * 64) / 256, 256, 0, stream>>>(vg, lcg_w, lcg_b, vg2);
    vtrans_kernel<<<dim3(NR_ / 64, B_), 256, 0, stream>>>(vg2, vtb);

    // 7-9. local branch pipeline (consumes kvl BEFORE osp16 aliases it)
    {
        local_mean2_kernel<256, 16, 7, 1, 0><<<B_ * NH_ * 49, 256, 0, stream>>>(kvl, kvm1);
        local_mean2_kernel<81, 9, 13, 2, 224><<<B_ * NH_ * 49, 128, 0, stream>>>(kvl, kvm2);
        fcsh_kernel<<<B_ * NH_, 64, 0, stream>>>(kvm1, fc1_w, sh1_w, kv1);
        fcsh_kernel<<<B_ * NH_, 64, 0, stream>>>(kvm2, fc2_w, sh2_w, kv2);
        int tot = B_ * NH_ * 49 * HD_;
        int blocks = (tot + 255) / 256;
        vconv_kernel<<<blocks, 256, 0, stream>>>(kv1, lc1_w, lc1_b, v1c);
        vconv_kernel<<<blocks, 256, 0, stream>>>(kv2, lc2_w, lc2_b, v2c);
    }

    // 6. global flash attention, split-K=8 (register-PV, bf16 osp) -> combine
    attn_global_split2<<<dim3(N_ / 64, B_ * NSPLIT), 256, 0, stream>>>(q16, kgb, vtb, osp16, mls);
    attn_combine<<<(B_ * N_ * 64) / 256, 256, 0, stream>>>(osp16, mls, catb);

    // 10. local attention (MFMA, both branches) -> catb cols [64,512)
    attn_local_mfma<<<dim3(N_ / 64, B_ * NH_ * 2), 256, 0, stream>>>(
        q16, kv1, v1c, kv2, v2c, catb);

    // 11. out = catb @ projt^T + proj_b
    gemm_bf16_kernel<true, false><<<dim3(M / 128, 4), 256, 0, stream>>>(
        catb, projt, proj_b, out, 512, 512, 512);
}

// Round 16
// 306.413 us; speedup vs baseline: 1.0177x; 1.0177x over previous
//
#include <hip/hip_runtime.h>
#include <hip/hip_bf16.h>
#include <math.h>
#include <stdint.h>

// ---- problem constants ----
static constexpr int B_    = 2;
static constexpr int N_    = 12544;   // 112*112
static constexpr int DIM_  = 512;
static constexpr int D0_   = 64;
static constexpr int DL_   = 448;
static constexpr int Himg  = 112;
static constexpr int Wimg  = 112;
static constexpr int HS_   = 56;
static constexpr int NR_   = 3136;    // 56*56
static constexpr int NH_   = 8;
static constexpr int HD_   = 28;
static constexpr int NSPLIT = 8;

typedef unsigned short ushort_t;
typedef __attribute__((ext_vector_type(8))) short short8_t;
typedef __attribute__((ext_vector_type(4))) float float4v;
typedef __attribute__((ext_vector_type(4))) unsigned uint4v;
typedef __attribute__((ext_vector_type(2))) unsigned uint2v;

// round-to-nearest-even f32 -> bf16
static __device__ inline ushort_t bf16r(float x) {
    unsigned u = __builtin_bit_cast(unsigned, x);
    u = (u + 0x7FFFu + ((u >> 16) & 1u)) >> 16;
    return (ushort_t)u;
}
static __device__ inline float bf16tof(ushort_t h) {
    unsigned u = ((unsigned)h) << 16;
    return __builtin_bit_cast(float, u);
}
// pack two f32 -> u32 of 2 bf16 (lo, hi) -- software RNE
static __device__ inline unsigned pack_bf16(float lo, float hi) {
    unsigned a = __builtin_bit_cast(unsigned, lo);
    unsigned b = __builtin_bit_cast(unsigned, hi);
    a = (a + 0x7FFFu + ((a >> 16) & 1u)) >> 16;
    b = (b + 0x7FFFu + ((b >> 16) & 1u)) >> 16;
    return a | (b << 16);
}
// HW v_cvt_pk_bf16_f32 path (RNE, identical bits) for VALU-bound kernels
static __device__ inline unsigned cvtpk(float lo, float hi) {
    float2 f2; f2.x = lo; f2.y = hi;
    __hip_bfloat162 h = __float22bfloat162_rn(f2);
    unsigned u;
    __builtin_memcpy(&u, &h, 4);
    return u;
}

using gptr_t = const __attribute__((address_space(1))) void*;
using lptr_t = __attribute__((address_space(3))) void*;
static __device__ inline void gload16(const void* g, void* l) {
    __builtin_amdgcn_global_load_lds((gptr_t)(uintptr_t)g, (lptr_t)(uintptr_t)l, 16, 0, 0);
}

// =====================================================================
// bf16 MFMA GEMM: C[M][ldc] = A[M][K](bf16) @ Bt[Npad][K](bf16)^T
// OUT16: write bf16 output (for q, consumed only by attention)
// =====================================================================
template<bool HASBIAS, bool OUT16>
__global__ __launch_bounds__(256, 2)
void gemm_bf16_kernel(const ushort_t* __restrict__ A,
                      const ushort_t* __restrict__ Bt,
                      const float* __restrict__ bias,
                      void* __restrict__ Cv,
                      int Nn, int K, int ldc) {
    constexpr int BM = 128, BK = 64;
    __shared__ __align__(16) ushort_t As[BM * BK];
    __shared__ __align__(16) ushort_t Bs[BM * BK];
    const int bm = blockIdx.x * BM;
    const int bn = blockIdx.y * BM;
    const int tid = threadIdx.x;
    const int l15 = tid & 15;
    const int g   = (tid & 63) >> 4;
    const int w   = tid >> 6;
    const int wr  = w >> 1, wc = w & 1;

    float4v acc[4][4];
    #pragma unroll
    for (int m = 0; m < 4; ++m)
        #pragma unroll
        for (int n = 0; n < 4; ++n) acc[m][n] = (float4v){0.f, 0.f, 0.f, 0.f};

    for (int k0 = 0; k0 < K; k0 += BK) {
        #pragma unroll
        for (int i = 0; i < 4; ++i) {
            int c = i * 256 + tid;
            int r = c >> 3, ch = c & 7;
            int sch = ch ^ (r & 7);
            gload16(A  + (size_t)(bm + r) * K + k0 + sch * 8, (void*)(As + c * 8));
            gload16(Bt + (size_t)(bn + r) * K + k0 + sch * 8, (void*)(Bs + c * 8));
        }
        __syncthreads();

        short8_t af[4][2], bfr[4][2];
        #pragma unroll
        for (int m = 0; m < 4; ++m) {
            int ar = wr * 64 + m * 16 + l15;
            #pragma unroll
            for (int h = 0; h < 2; ++h)
                af[m][h] = *(const short8_t*)((const char*)As + ar * 128 + (((h * 4 + g) ^ (ar & 7)) * 16));
        }
        #pragma unroll
        for (int n = 0; n < 4; ++n) {
            int br = wc * 64 + n * 16 + l15;
            #pragma unroll
            for (int h = 0; h < 2; ++h)
                bfr[n][h] = *(const short8_t*)((const char*)Bs + br * 128 + (((h * 4 + g) ^ (br & 7)) * 16));
        }
        #pragma unroll
        for (int m = 0; m < 4; ++m)
            #pragma unroll
            for (int n = 0; n < 4; ++n) {
                acc[m][n] = __builtin_amdgcn_mfma_f32_16x16x32_bf16(af[m][0], bfr[n][0], acc[m][n], 0, 0, 0);
                acc[m][n] = __builtin_amdgcn_mfma_f32_16x16x32_bf16(af[m][1], bfr[n][1], acc[m][n], 0, 0, 0);
            }
        __syncthreads();
    }

    #pragma unroll
    for (int n = 0; n < 4; ++n) {
        int ccol = bn + wc * 64 + n * 16 + l15;
        if (ccol < Nn) {
            float bv = HASBIAS ? bias[ccol] : 0.f;
            #pragma unroll
            for (int m = 0; m < 4; ++m) {
                int crow = bm + wr * 64 + m * 16 + g * 4;
                #pragma unroll
                for (int j = 0; j < 4; ++j) {
                    float v = acc[m][n][j] + bv;
                    if (OUT16)
                        ((ushort_t*)Cv)[(size_t)(crow + j) * ldc + ccol] = bf16r(v);
                    else
                        ((float*)Cv)[(size_t)(crow + j) * ldc + ccol] = v;
                }
            }
        }
    }
}

// =====================================================================
// weight convert: Wt[Npad][K] bf16 from W
// =====================================================================
__global__ __launch_bounds__(256)
void convw_kernel(const float* __restrict__ W, ushort_t* __restrict__ Wt,
                  int K, int Nn, int transpose) {
    int idx = blockIdx.x * 256 + threadIdx.x;
    int n = idx / K, k = idx % K;
    float v = 0.f;
    if (n < Nn) v = transpose ? W[(size_t)k * Nn + n] : W[(size_t)n * K + k];
    Wt[idx] = bf16r(v);
}

// sr_w transpose: wT[f][o] = sr_w[o*256 + f]
__global__ __launch_bounds__(256)
void srwt_kernel(const float* __restrict__ W, float* __restrict__ wT) {
    int idx = blockIdx.x * 256 + threadIdx.x;
    int f = idx >> 6, o = idx & 63;
    wT[idx] = W[o * 256 + f];
}

// fp32 -> bf16 bulk convert, 8 elems/thread
__global__ __launch_bounds__(256)
void convx_kernel(const float* __restrict__ in, ushort_t* __restrict__ outp) {
    int i = blockIdx.x * 256 + threadIdx.x;
    const float4v* p = (const float4v*)(in + (size_t)i * 8);
    float4v a = p[0], b = p[1];
    uint4v u;
    u[0] = pack_bf16(a[0], a[1]);
    u[1] = pack_bf16(a[2], a[3]);
    u[2] = pack_bf16(b[0], b[1]);
    u[3] = pack_bf16(b[2], b[3]);
    *(uint4v*)(outp + (size_t)i * 8) = u;
}

// =====================================================================
// sr-conv (coalesced wT) + LayerNorm(64) + kv GEMM (64->128)
// K written as bf16 PRE-SCALED by 0.125*log2(e)
// =====================================================================
__global__ __launch_bounds__(64)
void srlnkv_kernel(const float* __restrict__ x,
                   const float* __restrict__ wT, const float* __restrict__ sr_b,
                   const float* __restrict__ ln_g, const float* __restrict__ ln_b,
                   const float* __restrict__ wkv,
                   ushort_t* __restrict__ kgb, float* __restrict__ vg) {
    const int pos = blockIdx.x;
    const int b = pos / NR_, n = pos % NR_;
    const int y = n / HS_, xx = n % HS_;
    const int o = threadIdx.x;
    __shared__ float xs[4][64];
    __shared__ float lnv_s[64];
    #pragma unroll
    for (int tap = 0; tap < 4; ++tap) {
        int ky = tap / 2, kx = tap % 2;
        xs[tap][o] = x[((size_t)b * N_ + (2 * y + ky) * Wimg + 2 * xx + kx) * DIM_ + o];
    }
    __syncthreads();
    float sum = sr_b[o];
    for (int i = 0; i < 64; ++i) {
        const float* wr = wT + (i * 4) * 64 + o;
        sum += xs[0][i] * wr[0] + xs[1][i] * wr[64] + xs[2][i] * wr[128] + xs[3][i] * wr[192];
    }
    float m = sum;
    #pragma unroll
    for (int off = 1; off < 64; off <<= 1) m += __shfl_xor(m, off);
    m *= (1.0f / 64.0f);
    float d = sum - m;
    float v = d * d;
    #pragma unroll
    for (int off = 1; off < 64; off <<= 1) v += __shfl_xor(v, off);
    v *= (1.0f / 64.0f);
    float lnv = d * rsqrtf(v + 1e-5f) * ln_g[o] + ln_b[o];
    lnv_s[o] = lnv;
    __syncthreads();
    float s0 = 0.f, s1 = 0.f;
    for (int i = 0; i < 64; ++i) {
        float lv = lnv_s[i];
        s0 += lv * wkv[i * 128 + o];
        s1 += lv * wkv[i * 128 + o + 64];
    }
    const float SCK = 0.125f * 1.44269504088896340736f;
    kgb[((size_t)b * NR_ + n) * 64 + o] = bf16r(s0 * SCK);
    vg[((size_t)b * NR_ + n) * 64 + o] = s1;
}

// =====================================================================
// depthwise 3x3 + bias on v_g image; vg2 = vg + conv (fp32)
// =====================================================================
__global__ __launch_bounds__(256)
void lcg_kernel(const float* __restrict__ vg, const float* __restrict__ w,
                const float* __restrict__ bias, float* __restrict__ vg2) {
    int idx = blockIdx.x * 256 + threadIdx.x;
    if (idx >= B_ * NR_ * 64) return;
    int c = idx % 64;
    int n = (idx / 64) % NR_;
    int b = idx / (64 * NR_);
    int y = n / HS_, xx = n % HS_;
    float sum = vg[idx] + bias[c];
    #pragma unroll
    for (int ky = 0; ky < 3; ++ky)
        #pragma unroll
        for (int kx = 0; kx < 3; ++kx) {
            int yy = y + ky - 1, x2 = xx + kx - 1;
            if (yy >= 0 && yy < HS_ && x2 >= 0 && x2 < HS_)
                sum += vg[((size_t)b * NR_ + yy * HS_ + x2) * 64 + c] * w[c * 9 + ky * 3 + kx];
        }
    vg2[idx] = sum;
}

// =====================================================================
// transpose+convert: vg2 fp32 [B][NR][64] -> vtb bf16 [B][64][NR]
// =====================================================================
__global__ __launch_bounds__(256)
void vtrans_kernel(const float* __restrict__ vg2, ushort_t* __restrict__ vtb) {
    __shared__ float ld[64][65];
    const int b = blockIdx.y, n0 = blockIdx.x * 64, tid = threadIdx.x;
    #pragma unroll
    for (int i = 0; i < 16; ++i) {
        int idx = i * 256 + tid;
        int n = idx >> 6, c = idx & 63;
        ld[n][c] = vg2[((size_t)b * NR_ + n0 + n) * 64 + c];
    }
    __syncthreads();
    #pragma unroll
    for (int i = 0; i < 16; ++i) {
        int idx = i * 256 + tid;
        int d = idx >> 6, nn = idx & 63;
        vtb[(size_t)(b * 64 + d) * NR_ + n0 + nn] = bf16r(ld[nn][d]);
    }
}

// =====================================================================
// Global-branch flash attention, split-K=8, bf16 MFMA, register-PV via
// K row-permutation pi. TWO-TILE batching: one barrier pair per 2 tiles.
// Lane-partial l accumulation (single cross-lane reduce at end);
// defer-max trigger via lane-local max + __any.
// =====================================================================
__global__ __launch_bounds__(256)
void attn_global_split2(const ushort_t* __restrict__ q16,
                        const ushort_t* __restrict__ kgb,
                        const ushort_t* __restrict__ vtb,
                        ushort_t* __restrict__ osp16, float* __restrict__ mls) {
    __shared__ __align__(16) ushort_t Ks[2 * 64 * 64];
    __shared__ __align__(16) ushort_t Vs[2 * 64 * 64];
    const int split = blockIdx.y & 7;
    const int b     = blockIdx.y >> 3;
    const int q0    = blockIdx.x * 64;
    const int tid   = threadIdx.x;
    const int w     = tid >> 6;
    const int l     = tid & 63;
    const int l15   = l & 15;
    const int g     = l >> 4;
    const int lx    = l15 & 7;

    // Q fragments: raw bf16 loads (scale folded into K producer)
    short8_t qf[2];
    {
        const ushort_t* qrow = q16 + ((size_t)b * N_ + q0 + w * 16 + l15) * DIM_;
        qf[0] = *(const short8_t*)(qrow + g * 8);
        qf[1] = *(const short8_t*)(qrow + g * 8 + 32);
    }

    float4v o[4];
    #pragma unroll
    for (int i = 0; i < 4; ++i) o[i] = (float4v){0.f, 0.f, 0.f, 0.f};
    float m_run = -3.0e38f, l_run = 0.f;   // l_run is LANE-PARTIAL (row l15)

    // staging addresses (2 chunks per array per tile per thread)
    int stg_c[2], stg_r[2], stg_sch[2], stg_pr[2];
    #pragma unroll
    for (int i = 0; i < 2; ++i) {
        int c = i * 256 + tid;
        int r = c >> 3, ch = c & 7;
        stg_c[i] = c;
        stg_r[i] = r;
        stg_sch[i] = ch ^ (r & 7);
        stg_pr[i] = (r & 32) | (((r >> 2) & 3) << 3) | (((r >> 4) & 1) << 2) | (r & 3);
    }
    auto stage = [&](int t, int buf) {
        const int k0 = t * 64;
        ushort_t* kd = Ks + buf * 4096;
        ushort_t* vd = Vs + buf * 4096;
        #pragma unroll
        for (int i = 0; i < 2; ++i) {
            gload16(kgb + ((size_t)(b * NR_ + k0 + stg_pr[i]) << 6) + stg_sch[i] * 8,
                    (void*)(kd + stg_c[i] * 8));
            gload16(vtb + (size_t)(b * 64 + stg_r[i]) * NR_ + k0 + stg_sch[i] * 8,
                    (void*)(vd + stg_c[i] * 8));
        }
    };

    auto compute = [&](const ushort_t* Kb, const ushort_t* Vb) {
        float4v sc[4];
        #pragma unroll
        for (int c = 0; c < 4; ++c) {
            float4v acc = (float4v){0.f, 0.f, 0.f, 0.f};
            #pragma unroll
            for (int dc = 0; dc < 2; ++dc) {
                int row = c * 16 + l15;
                short8_t ak = *(const short8_t*)((const char*)Kb + row * 128 + (((g + 4 * dc) ^ lx) * 16));
                acc = __builtin_amdgcn_mfma_f32_16x16x32_bf16(ak, qf[dc], acc, 0, 0, 0);
            }
            sc[c] = acc;
        }

        // lane-local max over this lane's 16 scores
        float tmax = fmaxf(fmaxf(fmaxf(sc[0][0], sc[0][1]), fmaxf(sc[0][2], sc[0][3])),
                           fmaxf(fmaxf(sc[1][0], sc[1][1]), fmaxf(sc[1][2], sc[1][3])));
        tmax = fmaxf(tmax, fmaxf(fmaxf(fmaxf(sc[2][0], sc[2][1]), fmaxf(sc[2][2], sc[2][3])),
                                 fmaxf(fmaxf(sc[3][0], sc[3][1]), fmaxf(sc[3][2], sc[3][3]))));

        // defer-max: rescale only when some lane's max exceeds m_run+11
        if (__any(tmax > m_run + 11.0f)) {
            float rmax = fmaxf(tmax, __shfl_xor(tmax, 16));
            rmax = fmaxf(rmax, __shfl_xor(rmax, 32));
            float m_new = fmaxf(m_run, rmax);
            float corr = __builtin_amdgcn_exp2f(m_run - m_new);
            float co[4];
            #pragma unroll
            for (int r = 0; r < 4; ++r) co[r] = __shfl(corr, g * 4 + r);
            #pragma unroll
            for (int dc = 0; dc < 4; ++dc)
                #pragma unroll
                for (int r = 0; r < 4; ++r) o[dc][r] *= co[r];
            l_run *= corr;     // lane-partial: corr is this lane's row corr
            m_run = m_new;
        }

        float p[4][4];
        float ladd = 0.f;
        #pragma unroll
        for (int c = 0; c < 4; ++c)
            #pragma unroll
            for (int r = 0; r < 4; ++r) {
                float pe = __builtin_amdgcn_exp2f(sc[c][r] - m_run);
                p[c][r] = pe;
                ladd += pe;
            }
        l_run += ladd;         // lane-partial; reduced once at the end

        #pragma unroll
        for (int kkc = 0; kkc < 2; ++kkc) {
            uint4v au;
            au[0] = cvtpk(p[2 * kkc][0],     p[2 * kkc][1]);
            au[1] = cvtpk(p[2 * kkc][2],     p[2 * kkc][3]);
            au[2] = cvtpk(p[2 * kkc + 1][0], p[2 * kkc + 1][1]);
            au[3] = cvtpk(p[2 * kkc + 1][2], p[2 * kkc + 1][3]);
            short8_t ap = __builtin_bit_cast(short8_t, au);
            #pragma unroll
            for (int dc = 0; dc < 4; ++dc) {
                int vrow = dc * 16 + l15;
                short8_t bv = *(const short8_t*)((const char*)Vb + vrow * 128 + (((kkc * 4 + g) ^ lx) * 16));
                o[dc] = __builtin_amdgcn_mfma_f32_16x16x32_bf16(ap, bv, o[dc], 0, 0, 0);
            }
        }
    };

    const int t0 = (split * 49) / 8;
    const int t1 = ((split + 1) * 49) / 8;
    int t = t0;
    for (; t + 1 < t1; t += 2) {
        stage(t, 0);
        stage(t + 1, 1);
        __syncthreads();                 // both tiles staged
        compute(Ks, Vs);
        compute(Ks + 4096, Vs + 4096);
        __syncthreads();                 // LDS free for next pair
    }
    if (t < t1) {
        stage(t, 0);
        __syncthreads();
        compute(Ks, Vs);
    }

    // final cross-lane l reduction (row l15)
    float l_tot = l_run;
    l_tot += __shfl_xor(l_tot, 16);
    l_tot += __shfl_xor(l_tot, 32);

    const size_t rbase = (size_t)(split * B_ + b) * N_;
    #pragma unroll
    for (int dc = 0; dc < 4; ++dc)
        #pragma unroll
        for (int r = 0; r < 4; ++r) {
            int row = q0 + w * 16 + g * 4 + r;
            osp16[(rbase + row) * 64 + dc * 16 + l15] = bf16r(o[dc][r]);
        }
    if (l < 16) {
        int row = q0 + w * 16 + l15;
        mls[(rbase + row) * 2]     = m_run;
        mls[(rbase + row) * 2 + 1] = l_tot;
    }
}

// =====================================================================
// combine the 8 splits (exp2 domain, bf16 osp) -> catb cols [0,64)
// =====================================================================
__global__ __launch_bounds__(256)
void attn_combine(const ushort_t* __restrict__ osp16, const float* __restrict__ mls,
                  ushort_t* __restrict__ catb) {
    int idx = blockIdx.x * 256 + threadIdx.x;
    int col = idx & 63;
    size_t rn = (size_t)(idx >> 6);
    const size_t BN = (size_t)B_ * N_;
    float ms[NSPLIT], ls[NSPLIT];
    float m = -3.0e38f;
    #pragma unroll
    for (int s = 0; s < NSPLIT; ++s) {
        ms[s] = mls[(s * BN + rn) * 2];
        ls[s] = mls[(s * BN + rn) * 2 + 1];
        m = fmaxf(m, ms[s]);
    }
    float lsum = 0.f, acc = 0.f;
    #pragma unroll
    for (int s = 0; s < NSPLIT; ++s) {
        float wgt = __builtin_amdgcn_exp2f(ms[s] - m);
        lsum += ls[s] * wgt;
        acc  += bf16tof(osp16[(s * BN + rn) * 64 + col]) * wgt;
    }
    catb[rn * DIM_ + col] = bf16r(acc / lsum);
}

// =====================================================================
// depthwise 3x3 + bias on x_l, vectorized: 4 channels x 4 y-rows / thread
// =====================================================================
__global__ __launch_bounds__(256)
void dwt_kernel(const float* __restrict__ x, const float* __restrict__ w,
                const float* __restrict__ bias, ushort_t* __restrict__ out) {
    int idx = blockIdx.x * 256 + threadIdx.x;
    int c4 = idx % 112;
    int t1 = idx / 112;
    int xx = t1 % 112;
    int t2 = t1 / 112;
    int yg = t2 % 28;
    int b  = t2 / 28;
    int c0 = c4 * 4;
    int y0 = yg * 4;

    float4v w4[9];
    #pragma unroll
    for (int kt = 0; kt < 9; ++kt) {
        w4[kt][0] = w[(c0 + 0) * 9 + kt];
        w4[kt][1] = w[(c0 + 1) * 9 + kt];
        w4[kt][2] = w[(c0 + 2) * 9 + kt];
        w4[kt][3] = w[(c0 + 3) * 9 + kt];
    }
    float4v bv = *(const float4v*)(bias + c0);
    float4v acc[4];
    #pragma unroll
    for (int o2 = 0; o2 < 4; ++o2) acc[o2] = bv;

    #pragma unroll
    for (int yy = 0; yy < 6; ++yy) {
        int Y = y0 - 1 + yy;
        if (Y < 0 || Y >= Himg) continue;
        #pragma unroll
        for (int xt = 0; xt < 3; ++xt) {
            int X = xx - 1 + xt;
            if (X < 0 || X >= Wimg) continue;
            float4v v = *(const float4v*)(x + ((size_t)b * N_ + Y * Wimg + X) * DIM_ + D0_ + c0);
            constexpr int olo_t[6] = {0, 0, 0, 1, 2, 3};
            constexpr int ohi_t[6] = {0, 1, 2, 3, 3, 3};
            #pragma unroll
            for (int o2 = olo_t[yy]; o2 <= ohi_t[yy]; ++o2) {
                float4v wv = w4[(yy - o2) * 3 + xt];
                acc[o2][0] += v[0] * wv[0];
                acc[o2][1] += v[1] * wv[1];
                acc[o2][2] += v[2] * wv[2];
                acc[o2][3] += v[3] * wv[3];
            }
        }
    }
    #pragma unroll
    for (int o2 = 0; o2 < 4; ++o2) {
        uint2v pk;
        pk[0] = pack_bf16(acc[o2][0], acc[o2][1]);
        pk[1] = pack_bf16(acc[o2][2], acc[o2][3]);
        *(uint2v*)(out + ((size_t)b * N_ + (y0 + o2) * Wimg + xx) * DL_ + c0) = pk;
    }
}

// =====================================================================
// "scrambled mean", block-parallel: one block per (b,h,n).
// =====================================================================
template<int L, int NBW, int STRIDE, int DIL, int CHOFF>
__global__ void local_mean2_kernel(const float* __restrict__ kvl,
                                   float* __restrict__ kvm) {
    __shared__ float slo[L], shi[L];
    const int blk = blockIdx.x;
    const int n = blk % 49;
    const int h = (blk / 49) % NH_;
    const int b = blk / (49 * NH_);
    const int wy = n / 7, wx = n % 7;
    const int t = threadIdx.x;

    if (t < L) {
        const int by = t / NBW, bx = t % NBW;
        int Y = by * STRIDE + DIL * wy;
        int X = bx * STRIDE + DIL * wx;
        if (Y >= Himg) Y = 2 * Himg - 2 - Y;
        if (X >= Wimg) X = 2 * Wimg - 2 - X;
        const float* src = kvl + ((size_t)b * N_ + Y * Wimg + X) * DL_ + CHOFF + h * HD_;
        float v[28];
        #pragma unroll
        for (int i = 0; i < 7; ++i) {
            float4v q4 = ((const float4v*)src)[i];
            v[i * 4] = q4[0]; v[i * 4 + 1] = q4[1]; v[i * 4 + 2] = q4[2]; v[i * 4 + 3] = q4[3];
        }
        const int f0 = t * HD_;
        const int bin0 = f0 / L;
        const int nlo = min(HD_, (bin0 + 1) * L - f0);
        float s0 = 0.f, s1 = 0.f;
        #pragma unroll
        for (int j = 0; j < HD_; ++j) {
            if (j < nlo) s0 += v[j]; else s1 += v[j];
        }
        slo[t] = s0;
        shi[t] = s1;
    }
    __syncthreads();
    if (t < HD_) {
        const int t_lo = (t * L) / HD_;
        const int t_hi = min(L - 1, (t * L + L - 1) / HD_);
        float sum = 0.f;
        for (int u = t_lo; u <= t_hi; ++u) {
            int f0 = u * HD_;
            int b0 = f0 / L;
            int b1 = (f0 + HD_ - 1) / L;
            if (b0 == t) sum += slo[u];
            if (b1 == t && b1 != b0) sum += shi[u];
        }
        kvm[(size_t)blk * HD_ + t] = sum * (1.0f / (float)L);
    }
}

// =====================================================================
// kv = kvm @ fc_w @ sh_w -> (B*NH, 49, 56)
// =====================================================================
__global__ __launch_bounds__(64)
void fcsh_kernel(const float* __restrict__ kvm, const float* __restrict__ fcw,
                 const float* __restrict__ shw, float* __restrict__ out) {
    int bh = blockIdx.x;
    __shared__ float kin[49][28];
    __shared__ float tmp[49][28];
    __shared__ float fw[28 * 28];
    __shared__ float sw[28 * 56];
    int t = threadIdx.x;
    for (int i = t; i < 49 * 28; i += 64) kin[i / 28][i % 28] = kvm[bh * 49 * 28 + i];
    for (int i = t; i < 28 * 28; i += 64) fw[i] = fcw[i];
    for (int i = t; i < 28 * 56; i += 64) sw[i] = shw[i];
    __syncthreads();
    for (int i = t; i < 49 * 28; i += 64) {
        int rr = i / 28, j = i % 28;
        float s = 0.f;
        for (int k = 0; k < 28; ++k) s += kin[rr][k] * fw[k * 28 + j];
        tmp[rr][j] = s;
    }
    __syncthreads();
    for (int i = t; i < 49 * 56; i += 64) {
        int rr = i / 56, j = i % 56;
        float s = 0.f;
        for (int k = 0; k < 28; ++k) s += tmp[rr][k] * sw[k * 56 + j];
        out[bh * 49 * 56 + i] = s;
    }
}

// =====================================================================
// v_ + depthwise3x3(v_img 7x7) + bias -> vc (B*NH, 49, 28)
// =====================================================================
__global__ __launch_bounds__(256)
void vconv_kernel(const float* __restrict__ kvsh, const float* __restrict__ w,
                  const float* __restrict__ bias, float* __restrict__ vc) {
    int idx = blockIdx.x * 256 + threadIdx.x;
    if (idx >= B_ * NH_ * 49 * HD_) return;
    int d  = idx % HD_;
    int n  = (idx / HD_) % 49;
    int bh = idx / (HD_ * 49);
    int h  = bh % NH_;
    int y = n / 7, xx = n % 7;
    int c = h * HD_ + d;
    float sum = kvsh[(bh * 49 + n) * 56 + 28 + d] + bias[c];
    #pragma unroll
    for (int ky = 0; ky < 3; ++ky)
        #pragma unroll
        for (int kx = 0; kx < 3; ++kx) {
            int yy = y + ky - 1, x2 = xx + kx - 1;
            if (yy >= 0 && yy < 7 && x2 >= 0 && x2 < 7)
                sum += kvsh[(bh * 49 + yy * 7 + x2) * 56 + 28 + d] * w[c * 9 + ky * 3 + kx];
        }
    vc[idx] = sum;
}

// =====================================================================
// Local attention via MFMA, both branches fused. One block = 64 q-rows
// of one (b,h,branch). K pre-scaled by 28^-0.5*log2e at staging; Q raw
// bf16 (g==3 upper half zeroed; K d-pad is zero).
// =====================================================================
__global__ __launch_bounds__(256)
void attn_local_mfma(const ushort_t* __restrict__ q16,
                     const float* __restrict__ kv1, const float* __restrict__ v1c,
                     const float* __restrict__ kv2, const float* __restrict__ v2c,
                     ushort_t* __restrict__ catb) {
    __shared__ __align__(16) ushort_t Ks[64 * 32];   // [pi-row][d pad32]
    __shared__ __align__(16) ushort_t Vt[32 * 64];   // [d pad32][kcol pad64]
    const int ybh    = blockIdx.y;          // 0..31
    const int branch = ybh & 1;
    const int bh     = ybh >> 1;            // b*NH + h
    const int b      = bh >> 3, h = bh & 7;
    const int q0     = blockIdx.x * 64;
    const int tid    = threadIdx.x;
    const int w      = tid >> 6;
    const int l      = tid & 63;
    const int l15    = l & 15;
    const int g      = l >> 4;
    const float SC2K = 0.1889822365046136f * 1.44269504088896340736f; // 28^-.5 * log2e

    const float* kvsh = branch ? kv2 : kv1;
    const float* vc   = branch ? v2c : v1c;
    const int qoff    = D0_ + h * 56 + branch * 28;
    const int outoff  = (branch ? D0_ + 224 : D0_) + h * HD_;

    // ---- stage K (pre-scaled): LDS row r <- kcol pi(r), d padded to 32 ----
    {
        int row = tid >> 2, lc = tid & 3;
        int pr = (row & 32) | (((row >> 2) & 3) << 3) | (((row >> 4) & 1) << 2) | (row & 3);
        uint4v u = (uint4v){0u, 0u, 0u, 0u};
        if (pr < 49) {
            const float* src = kvsh + (bh * 49 + pr) * 56 + lc * 8;
            float vv[8];
            #pragma unroll
            for (int j2 = 0; j2 < 8; ++j2)
                vv[j2] = (lc * 8 + j2 < 28) ? src[j2] * SC2K : 0.f;
            u[0] = cvtpk(vv[0], vv[1]);
            u[1] = cvtpk(vv[2], vv[3]);
            u[2] = cvtpk(vv[4], vv[5]);
            u[3] = cvtpk(vv[6], vv[7]);
        }
        *(uint4v*)(Ks + row * 32 + (lc ^ (row & 3)) * 8) = u;
    }
    // ---- stage Vt[d][kcol] ----
    {
        int row = tid >> 3, lc = tid & 7;
        uint4v u = (uint4v){0u, 0u, 0u, 0u};
        if (row < 28) {
            float vv[8];
            #pragma unroll
            for (int j2 = 0; j2 < 8; ++j2) {
                int kc = lc * 8 + j2;
                vv[j2] = (kc < 49) ? vc[(bh * 49 + kc) * 28 + row] : 0.f;
            }
            u[0] = cvtpk(vv[0], vv[1]);
            u[1] = cvtpk(vv[2], vv[3]);
            u[2] = cvtpk(vv[4], vv[5]);
            u[3] = cvtpk(vv[6], vv[7]);
        }
        *(uint4v*)(Vt + row * 64 + (lc ^ (row & 7)) * 8) = u;
    }
    // ---- Q fragment: raw bf16 (8B loads; g==3 upper half zero) ----
    short8_t qf;
    {
        const ushort_t* qp = q16 + ((size_t)b * N_ + q0 + w * 16 + l15) * DIM_ + qoff + g * 8;
        uint2v a01 = *(const uint2v*)qp;
        uint2v a23 = (g < 3) ? *(const uint2v*)(qp + 4) : (uint2v){0u, 0u};
        uint4v uv;
        uv[0] = a01[0]; uv[1] = a01[1]; uv[2] = a23[0]; uv[3] = a23[1];
        qf = __builtin_bit_cast(short8_t, uv);
    }
    __syncthreads();

    // ---- scores ----
    float4v sc4[4];
    #pragma unroll
    for (int c = 0; c < 4; ++c) {
        int row = c * 16 + l15;
        short8_t ak = *(const short8_t*)(Ks + row * 32 + ((g ^ (row & 3)) * 8));
        float4v acc = (float4v){0.f, 0.f, 0.f, 0.f};
        sc4[c] = __builtin_amdgcn_mfma_f32_16x16x32_bf16(ak, qf, acc, 0, 0, 0);
    }

    // ---- softmax over 49 keys ----
    float tmax = fmaxf(fmaxf(fmaxf(sc4[0][0], sc4[0][1]), fmaxf(sc4[0][2], sc4[0][3])),
                       fmaxf(fmaxf(sc4[1][0], sc4[1][1]), fmaxf(sc4[1][2], sc4[1][3])));
    tmax = fmaxf(tmax, fmaxf(fmaxf(fmaxf(sc4[2][0], sc4[2][1]), fmaxf(sc4[2][2], sc4[2][3])),
                             fmaxf(fmaxf(sc4[3][0], sc4[3][1]), fmaxf(sc4[3][2], sc4[3][3]))));
    tmax = fmaxf(tmax, __shfl_xor(tmax, 16));
    tmax = fmaxf(tmax, __shfl_xor(tmax, 32));

    float p[4][4];
    float lsum = 0.f;
    #pragma unroll
    for (int c = 0; c < 4; ++c)
        #pragma unroll
        for (int r = 0; r < 4; ++r) {
            float pe = __builtin_amdgcn_exp2f(sc4[c][r] - tmax);
            if (c >= 2 && (8 * g + 4 * (c & 1) + r) >= 17) pe = 0.f;
            p[c][r] = pe;
            lsum += pe;
        }
    lsum += __shfl_xor(lsum, 16);
    lsum += __shfl_xor(lsum, 32);
    float inv = 1.0f / lsum;

    // ---- PV ----
    float4v o2[2];
    o2[0] = (float4v){0.f, 0.f, 0.f, 0.f};
    o2[1] = (float4v){0.f, 0.f, 0.f, 0.f};
    #pragma unroll
    for (int kkc = 0; kkc < 2; ++kkc) {
        uint4v au;
        au[0] = cvtpk(p[2 * kkc][0],     p[2 * kkc][1]);
        au[1] = cvtpk(p[2 * kkc][2],     p[2 * kkc][3]);
        au[2] = cvtpk(p[2 * kkc + 1][0], p[2 * kkc + 1][1]);
        au[3] = cvtpk(p[2 * kkc + 1][2], p[2 * kkc + 1][3]);
        short8_t ap = __builtin_bit_cast(short8_t, au);
        #pragma unroll
        for (int dc = 0; dc < 2; ++dc) {
            int vrow = dc * 16 + l15;
            short8_t bv = *(const short8_t*)(Vt + vrow * 64 + (((kkc * 4 + g) ^ (vrow & 7)) * 8));
            o2[dc] = __builtin_amdgcn_mfma_f32_16x16x32_bf16(ap, bv, o2[dc], 0, 0, 0);
        }
    }

    // ---- normalize + store (d < 28) ----
    float irow[4];
    #pragma unroll
    for (int r = 0; r < 4; ++r) irow[r] = __shfl(inv, g * 4 + r);
    #pragma unroll
    for (int dc = 0; dc < 2; ++dc) {
        int d = dc * 16 + l15;
        if (d < 28) {
            #pragma unroll
            for (int r = 0; r < 4; ++r) {
                int row = q0 + w * 16 + g * 4 + r;
                catb[((size_t)b * N_ + row) * DIM_ + outoff + d] = bf16r(o2[dc][r] * irow[r]);
            }
        }
    }
}

// =====================================================================
extern "C" void kernel_launch(void* const* d_in, const int* in_sizes, int n_in,
                              void* d_out, int out_size, void* d_ws, size_t ws_size,
                              hipStream_t stream) {
    const float* x      = (const float*)d_in[0];
    const float* Wq     = (const float*)d_in[1];
    const float* Wkv_g  = (const float*)d_in[2];
    const float* sr_w   = (const float*)d_in[3];
    const float* sr_b   = (const float*)d_in[4];
    const float* ln_g   = (const float*)d_in[5];
    const float* ln_b   = (const float*)d_in[6];
    const float* lcg_w  = (const float*)d_in[7];
    const float* lcg_b  = (const float*)d_in[8];
    const float* kvl_dw = (const float*)d_in[9];
    const float* kvl_db = (const float*)d_in[10];
    const float* kvl_pw = (const float*)d_in[11];
    const float* kvl_pb = (const float*)d_in[12];
    const float* fc1_w  = (const float*)d_in[13];
    const float* sh1_w  = (const float*)d_in[14];
    const float* lc1_w  = (const float*)d_in[15];
    const float* lc1_b  = (const float*)d_in[16];
    const float* fc2_w  = (const float*)d_in[17];
    const float* sh2_w  = (const float*)d_in[18];
    const float* lc2_w  = (const float*)d_in[19];
    const float* lc2_b  = (const float*)d_in[20];
    const float* proj_w = (const float*)d_in[21];
    const float* proj_b = (const float*)d_in[22];
    float* out = (float*)d_out;
    char* base = (char*)d_ws;

    // ---- workspace layout (256B aligned) ----
    size_t o = 0;
    auto alloc = [&](size_t bytes) -> void* {
        void* p = base + o;
        o = (o + bytes + 255) & ~(size_t)255;
        return p;
    };
    ushort_t* q16   = (ushort_t*)alloc((size_t)B_ * N_ * DIM_ * 2);
    float*    kvl   = (float*)   alloc((size_t)B_ * N_ * DL_ * 4);   // later osp16+mls
    ushort_t* xcat  = (ushort_t*)alloc((size_t)B_ * N_ * DIM_ * 2);  // xbf, then cat
    ushort_t* dwtb  = (ushort_t*)alloc((size_t)B_ * N_ * DL_ * 2);
    ushort_t* kgb   = (ushort_t*)alloc((size_t)B_ * NR_ * 64 * 2);
    float*    vg    = (float*)   alloc((size_t)B_ * NR_ * 64 * 4);
    float*    vg2   = (float*)   alloc((size_t)B_ * NR_ * 64 * 4);
    ushort_t* vtb   = (ushort_t*)alloc((size_t)B_ * 64 * NR_ * 2);
    ushort_t* wqt   = (ushort_t*)alloc((size_t)512 * 512 * 2);
    ushort_t* pwt   = (ushort_t*)alloc((size_t)512 * 448 * 2);
    ushort_t* projt = (ushort_t*)alloc((size_t)512 * 512 * 2);
    float*    srwt  = (float*)   alloc((size_t)256 * 64 * 4);
    float*    kvm1  = (float*)   alloc((size_t)B_ * NH_ * 49 * HD_ * 4);
    float*    kvm2  = (float*)   alloc((size_t)B_ * NH_ * 49 * HD_ * 4);
    float*    kv1   = (float*)   alloc((size_t)B_ * NH_ * 49 * 56 * 4);
    float*    kv2   = (float*)   alloc((size_t)B_ * NH_ * 49 * 56 * 4);
    float*    v1c   = (float*)   alloc((size_t)B_ * NH_ * 49 * HD_ * 4);
    float*    v2c   = (float*)   alloc((size_t)B_ * NH_ * 49 * HD_ * 4);
    ushort_t* xbf  = xcat;
    ushort_t* catb = xcat;
    // osp16/mls alias kvl (consumed by local_mean before attention runs)
    ushort_t* osp16 = (ushort_t*)kvl;                         // NSPLIT*B*N*64 bf16
    float*    mls   = (float*)((char*)kvl + (size_t)NSPLIT * B_ * N_ * 64 * 2);

    const int M = B_ * N_;   // 25088

    // 0. weight converts + x -> bf16
    convw_kernel<<<512 * 512 / 256, 256, 0, stream>>>(Wq, wqt, 512, 512, 1);
    convw_kernel<<<512 * 448 / 256, 256, 0, stream>>>(kvl_pw, pwt, 448, 448, 0);
    convw_kernel<<<512 * 512 / 256, 256, 0, stream>>>(proj_w, projt, 512, 512, 1);
    srwt_kernel<<<64, 256, 0, stream>>>(sr_w, srwt);
    convx_kernel<<<(B_ * N_ * DIM_ / 8) / 256, 256, 0, stream>>>(x, xbf);

    // 1. q16 = bf16(x @ Wq)
    gemm_bf16_kernel<false, true><<<dim3(M / 128, 4), 256, 0, stream>>>(
        xbf, wqt, nullptr, q16, 512, 512, 512);

    // 2. depthwise on x_l -> dwtb (bf16)
    dwt_kernel<<<(B_ * 28 * 112 * 112) / 256, 256, 0, stream>>>(x, kvl_dw, kvl_db, dwtb);

    // 3. pointwise: kvl = dwtb @ pwt^T + pb
    gemm_bf16_kernel<true, false><<<dim3(M / 128, 4), 256, 0, stream>>>(
        dwtb, pwt, kvl_pb, kvl, 448, 448, 448);

    // 4. global branch: sr conv + LN + kv (K bf16, pre-scaled exp2 domain)
    srlnkv_kernel<<<B_ * NR_, 64, 0, stream>>>(x, srwt, sr_b, ln_g, ln_b, Wkv_g, kgb, vg);

    // 5. vg2 = vg + depthwise(vg); then transpose+convert to vtb
    lcg_kernel<<<(B_ * NR_ * 64) / 256, 256, 0, stream>>>(vg, lcg_w, lcg_b, vg2);
    vtrans_kernel<<<dim3(NR_ / 64, B_), 256, 0, stream>>>(vg2, vtb);

    // 7-9. local branch pipeline (consumes kvl BEFORE osp16 aliases it)
    {
        local_mean2_kernel<256, 16, 7, 1, 0><<<B_ * NH_ * 49, 256, 0, stream>>>(kvl, kvm1);
        local_mean2_kernel<81, 9, 13, 2, 224><<<B_ * NH_ * 49, 128, 0, stream>>>(kvl, kvm2);
        fcsh_kernel<<<B_ * NH_, 64, 0, stream>>>(kvm1, fc1_w, sh1_w, kv1);
        fcsh_kernel<<<B_ * NH_, 64, 0, stream>>>(kvm2, fc2_w, sh2_w, kv2);
        int tot = B_ * NH_ * 49 * HD_;
        int blocks = (tot + 255) / 256;
        vconv_kernel<<<blocks, 256, 0, stream>>>(kv1, lc1_w, lc1_b, v1c);
        vconv_kernel<<<blocks, 256, 0, stream>>>(kv2, lc2_w, lc2_b, v2c);
    }

    // 6. global flash attention, split-K=8 (register-PV, 2-tile batching)
    attn_global_split2<<<dim3(N_ / 64, B_ * NSPLIT), 256, 0, stream>>>(q16, kgb, vtb, osp16, mls);
    attn_combine<<<(B_ * N_ * 64) / 256, 256, 0, stream>>>(osp16, mls, catb);

    // 10. local attention (MFMA, both branches) -> catb cols [64,512)
    attn_local_mfma<<<dim3(N_ / 64, B_ * NH_ * 2), 256, 0, stream>>>(
        q16, kv1, v1c, kv2, v2c, catb);

    // 11. out = catb @ projt^T + proj_b
    gemm_bf16_kernel<true, false><<<dim3(M / 128, 4), 256, 0, stream>>>(
        catb, projt, proj_b, out, 512, 512, 512);
}

// Round 17
// 305.369 us; speedup vs baseline: 1.0212x; 1.0034x over previous
//
#include <hip/hip_runtime.h>
#include <hip/hip_bf16.h>
#include <math.h>
#include <stdint.h>

// ---- problem constants ----
static constexpr int B_    = 2;
static constexpr int N_    = 12544;   // 112*112
static constexpr int DIM_  = 512;
static constexpr int D0_   = 64;
static constexpr int DL_   = 448;
static constexpr int Himg  = 112;
static constexpr int Wimg  = 112;
static constexpr int HS_   = 56;
static constexpr int NR_   = 3136;    // 56*56
static constexpr int NH_   = 8;
static constexpr int HD_   = 28;
static constexpr int NSPLIT = 8;

typedef unsigned short ushort_t;
typedef __attribute__((ext_vector_type(8))) short short8_t;
typedef __attribute__((ext_vector_type(4))) float float4v;
typedef __attribute__((ext_vector_type(4))) unsigned uint4v;
typedef __attribute__((ext_vector_type(2))) unsigned uint2v;

// round-to-nearest-even f32 -> bf16
static __device__ inline ushort_t bf16r(float x) {
    unsigned u = __builtin_bit_cast(unsigned, x);
    u = (u + 0x7FFFu + ((u >> 16) & 1u)) >> 16;
    return (ushort_t)u;
}
static __device__ inline float bf16tof(ushort_t h) {
    unsigned u = ((unsigned)h) << 16;
    return __builtin_bit_cast(float, u);
}
// pack two f32 -> u32 of 2 bf16 (lo, hi) -- software RNE
static __device__ inline unsigned pack_bf16(float lo, float hi) {
    unsigned a = __builtin_bit_cast(unsigned, lo);
    unsigned b = __builtin_bit_cast(unsigned, hi);
    a = (a + 0x7FFFu + ((a >> 16) & 1u)) >> 16;
    b = (b + 0x7FFFu + ((b >> 16) & 1u)) >> 16;
    return a | (b << 16);
}
// HW v_cvt_pk_bf16_f32 path (RNE, identical bits) for VALU-bound kernels
static __device__ inline unsigned cvtpk(float lo, float hi) {
    float2 f2; f2.x = lo; f2.y = hi;
    __hip_bfloat162 h = __float22bfloat162_rn(f2);
    unsigned u;
    __builtin_memcpy(&u, &h, 4);
    return u;
}

using gptr_t = const __attribute__((address_space(1))) void*;
using lptr_t = __attribute__((address_space(3))) void*;
static __device__ inline void gload16(const void* g, void* l) {
    __builtin_amdgcn_global_load_lds((gptr_t)(uintptr_t)g, (lptr_t)(uintptr_t)l, 16, 0, 0);
}

// =====================================================================
// bf16 MFMA GEMM: C[M][ldc] = A[M][K](bf16) @ Bt[Npad][K](bf16)^T
// OUT16: write bf16 output (for q, consumed only by attention)
// =====================================================================
template<bool HASBIAS, bool OUT16>
__global__ __launch_bounds__(256, 2)
void gemm_bf16_kernel(const ushort_t* __restrict__ A,
                      const ushort_t* __restrict__ Bt,
                      const float* __restrict__ bias,
                      void* __restrict__ Cv,
                      int Nn, int K, int ldc) {
    constexpr int BM = 128, BK = 64;
    __shared__ __align__(16) ushort_t As[BM * BK];
    __shared__ __align__(16) ushort_t Bs[BM * BK];
    const int bm = blockIdx.x * BM;
    const int bn = blockIdx.y * BM;
    const int tid = threadIdx.x;
    const int l15 = tid & 15;
    const int g   = (tid & 63) >> 4;
    const int w   = tid >> 6;
    const int wr  = w >> 1, wc = w & 1;

    float4v acc[4][4];
    #pragma unroll
    for (int m = 0; m < 4; ++m)
        #pragma unroll
        for (int n = 0; n < 4; ++n) acc[m][n] = (float4v){0.f, 0.f, 0.f, 0.f};

    for (int k0 = 0; k0 < K; k0 += BK) {
        #pragma unroll
        for (int i = 0; i < 4; ++i) {
            int c = i * 256 + tid;
            int r = c >> 3, ch = c & 7;
            int sch = ch ^ (r & 7);
            gload16(A  + (size_t)(bm + r) * K + k0 + sch * 8, (void*)(As + c * 8));
            gload16(Bt + (size_t)(bn + r) * K + k0 + sch * 8, (void*)(Bs + c * 8));
        }
        __syncthreads();

        short8_t af[4][2], bfr[4][2];
        #pragma unroll
        for (int m = 0; m < 4; ++m) {
            int ar = wr * 64 + m * 16 + l15;
            #pragma unroll
            for (int h = 0; h < 2; ++h)
                af[m][h] = *(const short8_t*)((const char*)As + ar * 128 + (((h * 4 + g) ^ (ar & 7)) * 16));
        }
        #pragma unroll
        for (int n = 0; n < 4; ++n) {
            int br = wc * 64 + n * 16 + l15;
            #pragma unroll
            for (int h = 0; h < 2; ++h)
                bfr[n][h] = *(const short8_t*)((const char*)Bs + br * 128 + (((h * 4 + g) ^ (br & 7)) * 16));
        }
        #pragma unroll
        for (int m = 0; m < 4; ++m)
            #pragma unroll
            for (int n = 0; n < 4; ++n) {
                acc[m][n] = __builtin_amdgcn_mfma_f32_16x16x32_bf16(af[m][0], bfr[n][0], acc[m][n], 0, 0, 0);
                acc[m][n] = __builtin_amdgcn_mfma_f32_16x16x32_bf16(af[m][1], bfr[n][1], acc[m][n], 0, 0, 0);
            }
        __syncthreads();
    }

    #pragma unroll
    for (int n = 0; n < 4; ++n) {
        int ccol = bn + wc * 64 + n * 16 + l15;
        if (ccol < Nn) {
            float bv = HASBIAS ? bias[ccol] : 0.f;
            #pragma unroll
            for (int m = 0; m < 4; ++m) {
                int crow = bm + wr * 64 + m * 16 + g * 4;
                #pragma unroll
                for (int j = 0; j < 4; ++j) {
                    float v = acc[m][n][j] + bv;
                    if (OUT16)
                        ((ushort_t*)Cv)[(size_t)(crow + j) * ldc + ccol] = bf16r(v);
                    else
                        ((float*)Cv)[(size_t)(crow + j) * ldc + ccol] = v;
                }
            }
        }
    }
}

// =====================================================================
// weight convert: Wt[Npad][K] bf16 from W
// =====================================================================
__global__ __launch_bounds__(256)
void convw_kernel(const float* __restrict__ W, ushort_t* __restrict__ Wt,
                  int K, int Nn, int transpose) {
    int idx = blockIdx.x * 256 + threadIdx.x;
    int n = idx / K, k = idx % K;
    float v = 0.f;
    if (n < Nn) v = transpose ? W[(size_t)k * Nn + n] : W[(size_t)n * K + k];
    Wt[idx] = bf16r(v);
}

// sr_w transpose: wT[f][o] = sr_w[o*256 + f]
__global__ __launch_bounds__(256)
void srwt_kernel(const float* __restrict__ W, float* __restrict__ wT) {
    int idx = blockIdx.x * 256 + threadIdx.x;
    int f = idx >> 6, o = idx & 63;
    wT[idx] = W[o * 256 + f];
}

// fp32 -> bf16 bulk convert, 8 elems/thread
__global__ __launch_bounds__(256)
void convx_kernel(const float* __restrict__ in, ushort_t* __restrict__ outp) {
    int i = blockIdx.x * 256 + threadIdx.x;
    const float4v* p = (const float4v*)(in + (size_t)i * 8);
    float4v a = p[0], b = p[1];
    uint4v u;
    u[0] = pack_bf16(a[0], a[1]);
    u[1] = pack_bf16(a[2], a[3]);
    u[2] = pack_bf16(b[0], b[1]);
    u[3] = pack_bf16(b[2], b[3]);
    *(uint4v*)(outp + (size_t)i * 8) = u;
}

// =====================================================================
// sr-conv (coalesced wT) + LayerNorm(64) + kv GEMM (64->128)
// K written as bf16 PRE-SCALED by 0.125*log2(e)
// =====================================================================
__global__ __launch_bounds__(64)
void srlnkv_kernel(const float* __restrict__ x,
                   const float* __restrict__ wT, const float* __restrict__ sr_b,
                   const float* __restrict__ ln_g, const float* __restrict__ ln_b,
                   const float* __restrict__ wkv,
                   ushort_t* __restrict__ kgb, float* __restrict__ vg) {
    const int pos = blockIdx.x;
    const int b = pos / NR_, n = pos % NR_;
    const int y = n / HS_, xx = n % HS_;
    const int o = threadIdx.x;
    __shared__ float xs[4][64];
    __shared__ float lnv_s[64];
    #pragma unroll
    for (int tap = 0; tap < 4; ++tap) {
        int ky = tap / 2, kx = tap % 2;
        xs[tap][o] = x[((size_t)b * N_ + (2 * y + ky) * Wimg + 2 * xx + kx) * DIM_ + o];
    }
    __syncthreads();
    float sum = sr_b[o];
    for (int i = 0; i < 64; ++i) {
        const float* wr = wT + (i * 4) * 64 + o;
        sum += xs[0][i] * wr[0] + xs[1][i] * wr[64] + xs[2][i] * wr[128] + xs[3][i] * wr[192];
    }
    float m = sum;
    #pragma unroll
    for (int off = 1; off < 64; off <<= 1) m += __shfl_xor(m, off);
    m *= (1.0f / 64.0f);
    float d = sum - m;
    float v = d * d;
    #pragma unroll
    for (int off = 1; off < 64; off <<= 1) v += __shfl_xor(v, off);
    v *= (1.0f / 64.0f);
    float lnv = d * rsqrtf(v + 1e-5f) * ln_g[o] + ln_b[o];
    lnv_s[o] = lnv;
    __syncthreads();
    float s0 = 0.f, s1 = 0.f;
    for (int i = 0; i < 64; ++i) {
        float lv = lnv_s[i];
        s0 += lv * wkv[i * 128 + o];
        s1 += lv * wkv[i * 128 + o + 64];
    }
    const float SCK = 0.125f * 1.44269504088896340736f;
    kgb[((size_t)b * NR_ + n) * 64 + o] = bf16r(s0 * SCK);
    vg[((size_t)b * NR_ + n) * 64 + o] = s1;
}

// =====================================================================
// depthwise 3x3 + bias on v_g image; vg2 = vg + conv (fp32)
// =====================================================================
__global__ __launch_bounds__(256)
void lcg_kernel(const float* __restrict__ vg, const float* __restrict__ w,
                const float* __restrict__ bias, float* __restrict__ vg2) {
    int idx = blockIdx.x * 256 + threadIdx.x;
    if (idx >= B_ * NR_ * 64) return;
    int c = idx % 64;
    int n = (idx / 64) % NR_;
    int b = idx / (64 * NR_);
    int y = n / HS_, xx = n % HS_;
    float sum = vg[idx] + bias[c];
    #pragma unroll
    for (int ky = 0; ky < 3; ++ky)
        #pragma unroll
        for (int kx = 0; kx < 3; ++kx) {
            int yy = y + ky - 1, x2 = xx + kx - 1;
            if (yy >= 0 && yy < HS_ && x2 >= 0 && x2 < HS_)
                sum += vg[((size_t)b * NR_ + yy * HS_ + x2) * 64 + c] * w[c * 9 + ky * 3 + kx];
        }
    vg2[idx] = sum;
}

// =====================================================================
// transpose+convert: vg2 fp32 [B][NR][64] -> vtb bf16 [B][64][NR]
// =====================================================================
__global__ __launch_bounds__(256)
void vtrans_kernel(const float* __restrict__ vg2, ushort_t* __restrict__ vtb) {
    __shared__ float ld[64][65];
    const int b = blockIdx.y, n0 = blockIdx.x * 64, tid = threadIdx.x;
    #pragma unroll
    for (int i = 0; i < 16; ++i) {
        int idx = i * 256 + tid;
        int n = idx >> 6, c = idx & 63;
        ld[n][c] = vg2[((size_t)b * NR_ + n0 + n) * 64 + c];
    }
    __syncthreads();
    #pragma unroll
    for (int i = 0; i < 16; ++i) {
        int idx = i * 256 + tid;
        int d = idx >> 6, nn = idx & 63;
        vtb[(size_t)(b * 64 + d) * NR_ + n0 + nn] = bf16r(ld[nn][d]);
    }
}

// =====================================================================
// Global-branch flash attention, split-K=8, bf16 MFMA, register-PV via
// K row-permutation pi. 512 threads / 8 waves / 128 q-rows per block:
// K/V staging amortized over 2x compute. Two-tile batching.
// =====================================================================
__global__ __launch_bounds__(512)
void attn_global_split2(const ushort_t* __restrict__ q16,
                        const ushort_t* __restrict__ kgb,
                        const ushort_t* __restrict__ vtb,
                        ushort_t* __restrict__ osp16, float* __restrict__ mls) {
    __shared__ __align__(16) ushort_t Ks[2 * 64 * 64];
    __shared__ __align__(16) ushort_t Vs[2 * 64 * 64];
    const int split = blockIdx.y & 7;
    const int b     = blockIdx.y >> 3;
    const int q0    = blockIdx.x * 128;
    const int tid   = threadIdx.x;
    const int w     = tid >> 6;      // wave 0..7 -> q-rows w*16..w*16+15
    const int l     = tid & 63;
    const int l15   = l & 15;
    const int g     = l >> 4;
    const int lx    = l15 & 7;

    // Q fragments: raw bf16 loads (scale folded into K producer)
    short8_t qf[2];
    {
        const ushort_t* qrow = q16 + ((size_t)b * N_ + q0 + w * 16 + l15) * DIM_;
        qf[0] = *(const short8_t*)(qrow + g * 8);
        qf[1] = *(const short8_t*)(qrow + g * 8 + 32);
    }

    float4v o[4];
    #pragma unroll
    for (int i = 0; i < 4; ++i) o[i] = (float4v){0.f, 0.f, 0.f, 0.f};
    float m_run = -3.0e38f, l_run = 0.f;   // l_run is LANE-PARTIAL (row l15)

    // staging addresses: exactly 1 chunk per array per tile per thread
    const int stg_r   = tid >> 3;
    const int stg_sch = (tid & 7) ^ (stg_r & 7);
    const int stg_pr  = (stg_r & 32) | (((stg_r >> 2) & 3) << 3) | (((stg_r >> 4) & 1) << 2) | (stg_r & 3);
    auto stage = [&](int t, int buf) {
        const int k0 = t * 64;
        gload16(kgb + ((size_t)(b * NR_ + k0 + stg_pr) << 6) + stg_sch * 8,
                (void*)(Ks + buf * 4096 + tid * 8));
        gload16(vtb + (size_t)(b * 64 + stg_r) * NR_ + k0 + stg_sch * 8,
                (void*)(Vs + buf * 4096 + tid * 8));
    };

    auto compute = [&](const ushort_t* Kb, const ushort_t* Vb) {
        float4v sc[4];
        #pragma unroll
        for (int c = 0; c < 4; ++c) {
            float4v acc = (float4v){0.f, 0.f, 0.f, 0.f};
            #pragma unroll
            for (int dc = 0; dc < 2; ++dc) {
                int row = c * 16 + l15;
                short8_t ak = *(const short8_t*)((const char*)Kb + row * 128 + (((g + 4 * dc) ^ lx) * 16));
                acc = __builtin_amdgcn_mfma_f32_16x16x32_bf16(ak, qf[dc], acc, 0, 0, 0);
            }
            sc[c] = acc;
        }

        // lane-local max over this lane's 16 scores
        float tmax = fmaxf(fmaxf(fmaxf(sc[0][0], sc[0][1]), fmaxf(sc[0][2], sc[0][3])),
                           fmaxf(fmaxf(sc[1][0], sc[1][1]), fmaxf(sc[1][2], sc[1][3])));
        tmax = fmaxf(tmax, fmaxf(fmaxf(fmaxf(sc[2][0], sc[2][1]), fmaxf(sc[2][2], sc[2][3])),
                                 fmaxf(fmaxf(sc[3][0], sc[3][1]), fmaxf(sc[3][2], sc[3][3]))));

        // defer-max: rescale only when some lane's max exceeds m_run+11
        if (__any(tmax > m_run + 11.0f)) {
            float rmax = fmaxf(tmax, __shfl_xor(tmax, 16));
            rmax = fmaxf(rmax, __shfl_xor(rmax, 32));
            float m_new = fmaxf(m_run, rmax);
            float corr = __builtin_amdgcn_exp2f(m_run - m_new);
            float co[4];
            #pragma unroll
            for (int r = 0; r < 4; ++r) co[r] = __shfl(corr, g * 4 + r);
            #pragma unroll
            for (int dc = 0; dc < 4; ++dc)
                #pragma unroll
                for (int r = 0; r < 4; ++r) o[dc][r] *= co[r];
            l_run *= corr;
            m_run = m_new;
        }

        float p[4][4];
        float ladd = 0.f;
        #pragma unroll
        for (int c = 0; c < 4; ++c)
            #pragma unroll
            for (int r = 0; r < 4; ++r) {
                float pe = __builtin_amdgcn_exp2f(sc[c][r] - m_run);
                p[c][r] = pe;
                ladd += pe;
            }
        l_run += ladd;

        #pragma unroll
        for (int kkc = 0; kkc < 2; ++kkc) {
            uint4v au;
            au[0] = cvtpk(p[2 * kkc][0],     p[2 * kkc][1]);
            au[1] = cvtpk(p[2 * kkc][2],     p[2 * kkc][3]);
            au[2] = cvtpk(p[2 * kkc + 1][0], p[2 * kkc + 1][1]);
            au[3] = cvtpk(p[2 * kkc + 1][2], p[2 * kkc + 1][3]);
            short8_t ap = __builtin_bit_cast(short8_t, au);
            #pragma unroll
            for (int dc = 0; dc < 4; ++dc) {
                int vrow = dc * 16 + l15;
                short8_t bv = *(const short8_t*)((const char*)Vb + vrow * 128 + (((kkc * 4 + g) ^ lx) * 16));
                o[dc] = __builtin_amdgcn_mfma_f32_16x16x32_bf16(ap, bv, o[dc], 0, 0, 0);
            }
        }
    };

    const int t0 = (split * 49) / 8;
    const int t1 = ((split + 1) * 49) / 8;
    int t = t0;
    for (; t + 1 < t1; t += 2) {
        stage(t, 0);
        stage(t + 1, 1);
        __syncthreads();
        compute(Ks, Vs);
        compute(Ks + 4096, Vs + 4096);
        __syncthreads();
    }
    if (t < t1) {
        stage(t, 0);
        __syncthreads();
        compute(Ks, Vs);
    }

    // final cross-lane l reduction (row l15)
    float l_tot = l_run;
    l_tot += __shfl_xor(l_tot, 16);
    l_tot += __shfl_xor(l_tot, 32);

    const size_t rbase = (size_t)(split * B_ + b) * N_;
    #pragma unroll
    for (int dc = 0; dc < 4; ++dc)
        #pragma unroll
        for (int r = 0; r < 4; ++r) {
            int row = q0 + w * 16 + g * 4 + r;
            osp16[(rbase + row) * 64 + dc * 16 + l15] = bf16r(o[dc][r]);
        }
    if (l < 16) {
        int row = q0 + w * 16 + l15;
        mls[(rbase + row) * 2]     = m_run;
        mls[(rbase + row) * 2 + 1] = l_tot;
    }
}

// =====================================================================
// combine the 8 splits (exp2 domain, bf16 osp) -> catb cols [0,64)
// =====================================================================
__global__ __launch_bounds__(256)
void attn_combine(const ushort_t* __restrict__ osp16, const float* __restrict__ mls,
                  ushort_t* __restrict__ catb) {
    int idx = blockIdx.x * 256 + threadIdx.x;
    int col = idx & 63;
    size_t rn = (size_t)(idx >> 6);
    const size_t BN = (size_t)B_ * N_;
    float ms[NSPLIT], ls[NSPLIT];
    float m = -3.0e38f;
    #pragma unroll
    for (int s = 0; s < NSPLIT; ++s) {
        ms[s] = mls[(s * BN + rn) * 2];
        ls[s] = mls[(s * BN + rn) * 2 + 1];
        m = fmaxf(m, ms[s]);
    }
    float lsum = 0.f, acc = 0.f;
    #pragma unroll
    for (int s = 0; s < NSPLIT; ++s) {
        float wgt = __builtin_amdgcn_exp2f(ms[s] - m);
        lsum += ls[s] * wgt;
        acc  += bf16tof(osp16[(s * BN + rn) * 64 + col]) * wgt;
    }
    catb[rn * DIM_ + col] = bf16r(acc / lsum);
}

// =====================================================================
// depthwise 3x3 + bias on x_l, vectorized: 4 channels x 4 y-rows / thread
// =====================================================================
__global__ __launch_bounds__(256)
void dwt_kernel(const float* __restrict__ x, const float* __restrict__ w,
                const float* __restrict__ bias, ushort_t* __restrict__ out) {
    int idx = blockIdx.x * 256 + threadIdx.x;
    int c4 = idx % 112;
    int t1 = idx / 112;
    int xx = t1 % 112;
    int t2 = t1 / 112;
    int yg = t2 % 28;
    int b  = t2 / 28;
    int c0 = c4 * 4;
    int y0 = yg * 4;

    float4v w4[9];
    #pragma unroll
    for (int kt = 0; kt < 9; ++kt) {
        w4[kt][0] = w[(c0 + 0) * 9 + kt];
        w4[kt][1] = w[(c0 + 1) * 9 + kt];
        w4[kt][2] = w[(c0 + 2) * 9 + kt];
        w4[kt][3] = w[(c0 + 3) * 9 + kt];
    }
    float4v bv = *(const float4v*)(bias + c0);
    float4v acc[4];
    #pragma unroll
    for (int o2 = 0; o2 < 4; ++o2) acc[o2] = bv;

    #pragma unroll
    for (int yy = 0; yy < 6; ++yy) {
        int Y = y0 - 1 + yy;
        if (Y < 0 || Y >= Himg) continue;
        #pragma unroll
        for (int xt = 0; xt < 3; ++xt) {
            int X = xx - 1 + xt;
            if (X < 0 || X >= Wimg) continue;
            float4v v = *(const float4v*)(x + ((size_t)b * N_ + Y * Wimg + X) * DIM_ + D0_ + c0);
            constexpr int olo_t[6] = {0, 0, 0, 1, 2, 3};
            constexpr int ohi_t[6] = {0, 1, 2, 3, 3, 3};
            #pragma unroll
            for (int o2 = olo_t[yy]; o2 <= ohi_t[yy]; ++o2) {
                float4v wv = w4[(yy - o2) * 3 + xt];
                acc[o2][0] += v[0] * wv[0];
                acc[o2][1] += v[1] * wv[1];
                acc[o2][2] += v[2] * wv[2];
                acc[o2][3] += v[3] * wv[3];
            }
        }
    }
    #pragma unroll
    for (int o2 = 0; o2 < 4; ++o2) {
        uint2v pk;
        pk[0] = pack_bf16(acc[o2][0], acc[o2][1]);
        pk[1] = pack_bf16(acc[o2][2], acc[o2][3]);
        *(uint2v*)(out + ((size_t)b * N_ + (y0 + o2) * Wimg + xx) * DL_ + c0) = pk;
    }
}

// =====================================================================
// "scrambled mean", block-parallel: one block per (b,h,n).
// =====================================================================
template<int L, int NBW, int STRIDE, int DIL, int CHOFF>
__global__ void local_mean2_kernel(const float* __restrict__ kvl,
                                   float* __restrict__ kvm) {
    __shared__ float slo[L], shi[L];
    const int blk = blockIdx.x;
    const int n = blk % 49;
    const int h = (blk / 49) % NH_;
    const int b = blk / (49 * NH_);
    const int wy = n / 7, wx = n % 7;
    const int t = threadIdx.x;

    if (t < L) {
        const int by = t / NBW, bx = t % NBW;
        int Y = by * STRIDE + DIL * wy;
        int X = bx * STRIDE + DIL * wx;
        if (Y >= Himg) Y = 2 * Himg - 2 - Y;
        if (X >= Wimg) X = 2 * Wimg - 2 - X;
        const float* src = kvl + ((size_t)b * N_ + Y * Wimg + X) * DL_ + CHOFF + h * HD_;
        float v[28];
        #pragma unroll
        for (int i = 0; i < 7; ++i) {
            float4v q4 = ((const float4v*)src)[i];
            v[i * 4] = q4[0]; v[i * 4 + 1] = q4[1]; v[i * 4 + 2] = q4[2]; v[i * 4 + 3] = q4[3];
        }
        const int f0 = t * HD_;
        const int bin0 = f0 / L;
        const int nlo = min(HD_, (bin0 + 1) * L - f0);
        float s0 = 0.f, s1 = 0.f;
        #pragma unroll
        for (int j = 0; j < HD_; ++j) {
            if (j < nlo) s0 += v[j]; else s1 += v[j];
        }
        slo[t] = s0;
        shi[t] = s1;
    }
    __syncthreads();
    if (t < HD_) {
        const int t_lo = (t * L) / HD_;
        const int t_hi = min(L - 1, (t * L + L - 1) / HD_);
        float sum = 0.f;
        for (int u = t_lo; u <= t_hi; ++u) {
            int f0 = u * HD_;
            int b0 = f0 / L;
            int b1 = (f0 + HD_ - 1) / L;
            if (b0 == t) sum += slo[u];
            if (b1 == t && b1 != b0) sum += shi[u];
        }
        kvm[(size_t)blk * HD_ + t] = sum * (1.0f / (float)L);
    }
}

// =====================================================================
// kv = kvm @ fc_w @ sh_w -> (B*NH, 49, 56)
// =====================================================================
__global__ __launch_bounds__(64)
void fcsh_kernel(const float* __restrict__ kvm, const float* __restrict__ fcw,
                 const float* __restrict__ shw, float* __restrict__ out) {
    int bh = blockIdx.x;
    __shared__ float kin[49][28];
    __shared__ float tmp[49][28];
    __shared__ float fw[28 * 28];
    __shared__ float sw[28 * 56];
    int t = threadIdx.x;
    for (int i = t; i < 49 * 28; i += 64) kin[i / 28][i % 28] = kvm[bh * 49 * 28 + i];
    for (int i = t; i < 28 * 28; i += 64) fw[i] = fcw[i];
    for (int i = t; i < 28 * 56; i += 64) sw[i] = shw[i];
    __syncthreads();
    for (int i = t; i < 49 * 28; i += 64) {
        int rr = i / 28, j = i % 28;
        float s = 0.f;
        for (int k = 0; k < 28; ++k) s += kin[rr][k] * fw[k * 28 + j];
        tmp[rr][j] = s;
    }
    __syncthreads();
    for (int i = t; i < 49 * 56; i += 64) {
        int rr = i / 56, j = i % 56;
        float s = 0.f;
        for (int k = 0; k < 28; ++k) s += tmp[rr][k] * sw[k * 56 + j];
        out[bh * 49 * 56 + i] = s;
    }
}

// =====================================================================
// v_ + depthwise3x3(v_img 7x7) + bias -> vc (B*NH, 49, 28)
// =====================================================================
__global__ __launch_bounds__(256)
void vconv_kernel(const float* __restrict__ kvsh, const float* __restrict__ w,
                  const float* __restrict__ bias, float* __restrict__ vc) {
    int idx = blockIdx.x * 256 + threadIdx.x;
    if (idx >= B_ * NH_ * 49 * HD_) return;
    int d  = idx % HD_;
    int n  = (idx / HD_) % 49;
    int bh = idx / (HD_ * 49);
    int h  = bh % NH_;
    int y = n / 7, xx = n % 7;
    int c = h * HD_ + d;
    float sum = kvsh[(bh * 49 + n) * 56 + 28 + d] + bias[c];
    #pragma unroll
    for (int ky = 0; ky < 3; ++ky)
        #pragma unroll
        for (int kx = 0; kx < 3; ++kx) {
            int yy = y + ky - 1, x2 = xx + kx - 1;
            if (yy >= 0 && yy < 7 && x2 >= 0 && x2 < 7)
                sum += kvsh[(bh * 49 + yy * 7 + x2) * 56 + 28 + d] * w[c * 9 + ky * 3 + kx];
        }
    vc[idx] = sum;
}

// =====================================================================
// Local attention via MFMA, both branches fused. One block = 64 q-rows
// of one (b,h,branch). K pre-scaled by 28^-0.5*log2e at staging; Q raw
// bf16 (g==3 upper half zeroed; K d-pad is zero).
// =====================================================================
__global__ __launch_bounds__(256)
void attn_local_mfma(const ushort_t* __restrict__ q16,
                     const float* __restrict__ kv1, const float* __restrict__ v1c,
                     const float* __restrict__ kv2, const float* __restrict__ v2c,
                     ushort_t* __restrict__ catb) {
    __shared__ __align__(16) ushort_t Ks[64 * 32];   // [pi-row][d pad32]
    __shared__ __align__(16) ushort_t Vt[32 * 64];   // [d pad32][kcol pad64]
    const int ybh    = blockIdx.y;          // 0..31
    const int branch = ybh & 1;
    const int bh     = ybh >> 1;            // b*NH + h
    const int b      = bh >> 3, h = bh & 7;
    const int q0     = blockIdx.x * 64;
    const int tid    = threadIdx.x;
    const int w      = tid >> 6;
    const int l      = tid & 63;
    const int l15    = l & 15;
    const int g      = l >> 4;
    const float SC2K = 0.1889822365046136f * 1.44269504088896340736f; // 28^-.5 * log2e

    const float* kvsh = branch ? kv2 : kv1;
    const float* vc   = branch ? v2c : v1c;
    const int qoff    = D0_ + h * 56 + branch * 28;
    const int outoff  = (branch ? D0_ + 224 : D0_) + h * HD_;

    // ---- stage K (pre-scaled): LDS row r <- kcol pi(r), d padded to 32 ----
    {
        int row = tid >> 2, lc = tid & 3;
        int pr = (row & 32) | (((row >> 2) & 3) << 3) | (((row >> 4) & 1) << 2) | (row & 3);
        uint4v u = (uint4v){0u, 0u, 0u, 0u};
        if (pr < 49) {
            const float* src = kvsh + (bh * 49 + pr) * 56 + lc * 8;
            float vv[8];
            #pragma unroll
            for (int j2 = 0; j2 < 8; ++j2)
                vv[j2] = (lc * 8 + j2 < 28) ? src[j2] * SC2K : 0.f;
            u[0] = cvtpk(vv[0], vv[1]);
            u[1] = cvtpk(vv[2], vv[3]);
            u[2] = cvtpk(vv[4], vv[5]);
            u[3] = cvtpk(vv[6], vv[7]);
        }
        *(uint4v*)(Ks + row * 32 + (lc ^ (row & 3)) * 8) = u;
    }
    // ---- stage Vt[d][kcol] ----
    {
        int row = tid >> 3, lc = tid & 7;
        uint4v u = (uint4v){0u, 0u, 0u, 0u};
        if (row < 28) {
            float vv[8];
            #pragma unroll
            for (int j2 = 0; j2 < 8; ++j2) {
                int kc = lc * 8 + j2;
                vv[j2] = (kc < 49) ? vc[(bh * 49 + kc) * 28 + row] : 0.f;
            }
            u[0] = cvtpk(vv[0], vv[1]);
            u[1] = cvtpk(vv[2], vv[3]);
            u[2] = cvtpk(vv[4], vv[5]);
            u[3] = cvtpk(vv[6], vv[7]);
        }
        *(uint4v*)(Vt + row * 64 + (lc ^ (row & 7)) * 8) = u;
    }
    // ---- Q fragment: raw bf16 (8B loads; g==3 upper half zero) ----
    short8_t qf;
    {
        const ushort_t* qp = q16 + ((size_t)b * N_ + q0 + w * 16 + l15) * DIM_ + qoff + g * 8;
        uint2v a01 = *(const uint2v*)qp;
        uint2v a23 = (g < 3) ? *(const uint2v*)(qp + 4) : (uint2v){0u, 0u};
        uint4v uv;
        uv[0] = a01[0]; uv[1] = a01[1]; uv[2] = a23[0]; uv[3] = a23[1];
        qf = __builtin_bit_cast(short8_t, uv);
    }
    __syncthreads();

    // ---- scores ----
    float4v sc4[4];
    #pragma unroll
    for (int c = 0; c < 4; ++c) {
        int row = c * 16 + l15;
        short8_t ak = *(const short8_t*)(Ks + row * 32 + ((g ^ (row & 3)) * 8));
        float4v acc = (float4v){0.f, 0.f, 0.f, 0.f};
        sc4[c] = __builtin_amdgcn_mfma_f32_16x16x32_bf16(ak, qf, acc, 0, 0, 0);
    }

    // ---- softmax over 49 keys ----
    float tmax = fmaxf(fmaxf(fmaxf(sc4[0][0], sc4[0][1]), fmaxf(sc4[0][2], sc4[0][3])),
                       fmaxf(fmaxf(sc4[1][0], sc4[1][1]), fmaxf(sc4[1][2], sc4[1][3])));
    tmax = fmaxf(tmax, fmaxf(fmaxf(fmaxf(sc4[2][0], sc4[2][1]), fmaxf(sc4[2][2], sc4[2][3])),
                             fmaxf(fmaxf(sc4[3][0], sc4[3][1]), fmaxf(sc4[3][2], sc4[3][3]))));
    tmax = fmaxf(tmax, __shfl_xor(tmax, 16));
    tmax = fmaxf(tmax, __shfl_xor(tmax, 32));

    float p[4][4];
    float lsum = 0.f;
    #pragma unroll
    for (int c = 0; c < 4; ++c)
        #pragma unroll
        for (int r = 0; r < 4; ++r) {
            float pe = __builtin_amdgcn_exp2f(sc4[c][r] - tmax);
            if (c >= 2 && (8 * g + 4 * (c & 1) + r) >= 17) pe = 0.f;
            p[c][r] = pe;
            lsum += pe;
        }
    lsum += __shfl_xor(lsum, 16);
    lsum += __shfl_xor(lsum, 32);
    float inv = 1.0f / lsum;

    // ---- PV ----
    float4v o2[2];
    o2[0] = (float4v){0.f, 0.f, 0.f, 0.f};
    o2[1] = (float4v){0.f, 0.f, 0.f, 0.f};
    #pragma unroll
    for (int kkc = 0; kkc < 2; ++kkc) {
        uint4v au;
        au[0] = cvtpk(p[2 * kkc][0],     p[2 * kkc][1]);
        au[1] = cvtpk(p[2 * kkc][2],     p[2 * kkc][3]);
        au[2] = cvtpk(p[2 * kkc + 1][0], p[2 * kkc + 1][1]);
        au[3] = cvtpk(p[2 * kkc + 1][2], p[2 * kkc + 1][3]);
        short8_t ap = __builtin_bit_cast(short8_t, au);
        #pragma unroll
        for (int dc = 0; dc < 2; ++dc) {
            int vrow = dc * 16 + l15;
            short8_t bv = *(const short8_t*)(Vt + vrow * 64 + (((kkc * 4 + g) ^ (vrow & 7)) * 8));
            o2[dc] = __builtin_amdgcn_mfma_f32_16x16x32_bf16(ap, bv, o2[dc], 0, 0, 0);
        }
    }

    // ---- normalize + store (d < 28) ----
    float irow[4];
    #pragma unroll
    for (int r = 0; r < 4; ++r) irow[r] = __shfl(inv, g * 4 + r);
    #pragma unroll
    for (int dc = 0; dc < 2; ++dc) {
        int d = dc * 16 + l15;
        if (d < 28) {
            #pragma unroll
            for (int r = 0; r < 4; ++r) {
                int row = q0 + w * 16 + g * 4 + r;
                catb[((size_t)b * N_ + row) * DIM_ + outoff + d] = bf16r(o2[dc][r] * irow[r]);
            }
        }
    }
}

// =====================================================================
extern "C" void kernel_launch(void* const* d_in, const int* in_sizes, int n_in,
                              void* d_out, int out_size, void* d_ws, size_t ws_size,
                              hipStream_t stream) {
    const float* x      = (const float*)d_in[0];
    const float* Wq     = (const float*)d_in[1];
    const float* Wkv_g  = (const float*)d_in[2];
    const float* sr_w   = (const float*)d_in[3];
    const float* sr_b   = (const float*)d_in[4];
    const float* ln_g   = (const float*)d_in[5];
    const float* ln_b   = (const float*)d_in[6];
    const float* lcg_w  = (const float*)d_in[7];
    const float* lcg_b  = (const float*)d_in[8];
    const float* kvl_dw = (const float*)d_in[9];
    const float* kvl_db = (const float*)d_in[10];
    const float* kvl_pw = (const float*)d_in[11];
    const float* kvl_pb = (const float*)d_in[12];
    const float* fc1_w  = (const float*)d_in[13];
    const float* sh1_w  = (const float*)d_in[14];
    const float* lc1_w  = (const float*)d_in[15];
    const float* lc1_b  = (const float*)d_in[16];
    const float* fc2_w  = (const float*)d_in[17];
    const float* sh2_w  = (const float*)d_in[18];
    const float* lc2_w  = (const float*)d_in[19];
    const float* lc2_b  = (const float*)d_in[20];
    const float* proj_w = (const float*)d_in[21];
    const float* proj_b = (const float*)d_in[22];
    float* out = (float*)d_out;
    char* base = (char*)d_ws;

    // ---- workspace layout (256B aligned) ----
    size_t o = 0;
    auto alloc = [&](size_t bytes) -> void* {
        void* p = base + o;
        o = (o + bytes + 255) & ~(size_t)255;
        return p;
    };
    ushort_t* q16   = (ushort_t*)alloc((size_t)B_ * N_ * DIM_ * 2);
    float*    kvl   = (float*)   alloc((size_t)B_ * N_ * DL_ * 4);   // later osp16+mls
    ushort_t* xcat  = (ushort_t*)alloc((size_t)B_ * N_ * DIM_ * 2);  // xbf, then cat
    ushort_t* dwtb  = (ushort_t*)alloc((size_t)B_ * N_ * DL_ * 2);
    ushort_t* kgb   = (ushort_t*)alloc((size_t)B_ * NR_ * 64 * 2);
    float*    vg    = (float*)   alloc((size_t)B_ * NR_ * 64 * 4);
    float*    vg2   = (float*)   alloc((size_t)B_ * NR_ * 64 * 4);
    ushort_t* vtb   = (ushort_t*)alloc((size_t)B_ * 64 * NR_ * 2);
    ushort_t* wqt   = (ushort_t*)alloc((size_t)512 * 512 * 2);
    ushort_t* pwt   = (ushort_t*)alloc((size_t)512 * 448 * 2);
    ushort_t* projt = (ushort_t*)alloc((size_t)512 * 512 * 2);
    float*    srwt  = (float*)   alloc((size_t)256 * 64 * 4);
    float*    kvm1  = (float*)   alloc((size_t)B_ * NH_ * 49 * HD_ * 4);
    float*    kvm2  = (float*)   alloc((size_t)B_ * NH_ * 49 * HD_ * 4);
    float*    kv1   = (float*)   alloc((size_t)B_ * NH_ * 49 * 56 * 4);
    float*    kv2   = (float*)   alloc((size_t)B_ * NH_ * 49 * 56 * 4);
    float*    v1c   = (float*)   alloc((size_t)B_ * NH_ * 49 * HD_ * 4);
    float*    v2c   = (float*)   alloc((size_t)B_ * NH_ * 49 * HD_ * 4);
    ushort_t* xbf  = xcat;
    ushort_t* catb = xcat;
    // osp16/mls alias kvl (consumed by local_mean before attention runs)
    ushort_t* osp16 = (ushort_t*)kvl;                         // NSPLIT*B*N*64 bf16
    float*    mls   = (float*)((char*)kvl + (size_t)NSPLIT * B_ * N_ * 64 * 2);

    const int M = B_ * N_;   // 25088

    // 0. weight converts + x -> bf16
    convw_kernel<<<512 * 512 / 256, 256, 0, stream>>>(Wq, wqt, 512, 512, 1);
    convw_kernel<<<512 * 448 / 256, 256, 0, stream>>>(kvl_pw, pwt, 448, 448, 0);
    convw_kernel<<<512 * 512 / 256, 256, 0, stream>>>(proj_w, projt, 512, 512, 1);
    srwt_kernel<<<64, 256, 0, stream>>>(sr_w, srwt);
    convx_kernel<<<(B_ * N_ * DIM_ / 8) / 256, 256, 0, stream>>>(x, xbf);

    // 1. q16 = bf16(x @ Wq)
    gemm_bf16_kernel<false, true><<<dim3(M / 128, 4), 256, 0, stream>>>(
        xbf, wqt, nullptr, q16, 512, 512, 512);

    // 2. depthwise on x_l -> dwtb (bf16)
    dwt_kernel<<<(B_ * 28 * 112 * 112) / 256, 256, 0, stream>>>(x, kvl_dw, kvl_db, dwtb);

    // 3. pointwise: kvl = dwtb @ pwt^T + pb
    gemm_bf16_kernel<true, false><<<dim3(M / 128, 4), 256, 0, stream>>>(
        dwtb, pwt, kvl_pb, kvl, 448, 448, 448);

    // 4. global branch: sr conv + LN + kv (K bf16, pre-scaled exp2 domain)
    srlnkv_kernel<<<B_ * NR_, 64, 0, stream>>>(x, srwt, sr_b, ln_g, ln_b, Wkv_g, kgb, vg);

    // 5. vg2 = vg + depthwise(vg); then transpose+convert to vtb
    lcg_kernel<<<(B_ * NR_ * 64) / 256, 256, 0, stream>>>(vg, lcg_w, lcg_b, vg2);
    vtrans_kernel<<<dim3(NR_ / 64, B_), 256, 0, stream>>>(vg2, vtb);

    // 7-9. local branch pipeline (consumes kvl BEFORE osp16 aliases it)
    {
        local_mean2_kernel<256, 16, 7, 1, 0><<<B_ * NH_ * 49, 256, 0, stream>>>(kvl, kvm1);
        local_mean2_kernel<81, 9, 13, 2, 224><<<B_ * NH_ * 49, 128, 0, stream>>>(kvl, kvm2);
        fcsh_kernel<<<B_ * NH_, 64, 0, stream>>>(kvm1, fc1_w, sh1_w, kv1);
        fcsh_kernel<<<B_ * NH_, 64, 0, stream>>>(kvm2, fc2_w, sh2_w, kv2);
        int tot = B_ * NH_ * 49 * HD_;
        int blocks = (tot + 255) / 256;
        vconv_kernel<<<blocks, 256, 0, stream>>>(kv1, lc1_w, lc1_b, v1c);
        vconv_kernel<<<blocks, 256, 0, stream>>>(kv2, lc2_w, lc2_b, v2c);
    }

    // 6. global flash attention, split-K=8 (register-PV, 512-thread blocks)
    attn_global_split2<<<dim3(N_ / 128, B_ * NSPLIT), 512, 0, stream>>>(q16, kgb, vtb, osp16, mls);
    attn_combine<<<(B_ * N_ * 64) / 256, 256, 0, stream>>>(osp16, mls, catb);

    // 10. local attention (MFMA, both branches) -> catb cols [64,512)
    attn_local_mfma<<<dim3(N_ / 64, B_ * NH_ * 2), 256, 0, stream>>>(
        q16, kv1, v1c, kv2, v2c, catb);

    // 11. out = catb @ projt^T + proj_b
    gemm_bf16_kernel<true, false><<<dim3(M / 128, 4), 256, 0, stream>>>(
        catb, projt, proj_b, out, 512, 512, 512);
}

// Round 18
// 302.401 us; speedup vs baseline: 1.0312x; 1.0098x over previous
//
#include <hip/hip_runtime.h>
#include <hip/hip_bf16.h>
#include <math.h>
#include <stdint.h>

// ---- problem constants ----
static constexpr int B_    = 2;
static constexpr int N_    = 12544;   // 112*112
static constexpr int DIM_  = 512;
static constexpr int D0_   = 64;
static constexpr int DL_   = 448;
static constexpr int Himg  = 112;
static constexpr int Wimg  = 112;
static constexpr int HS_   = 56;
static constexpr int NR_   = 3136;    // 56*56
static constexpr int NH_   = 8;
static constexpr int HD_   = 28;
static constexpr int NSPLIT = 8;

typedef unsigned short ushort_t;
typedef __attribute__((ext_vector_type(8))) short short8_t;
typedef __attribute__((ext_vector_type(4))) float float4v;
typedef __attribute__((ext_vector_type(4))) unsigned uint4v;
typedef __attribute__((ext_vector_type(2))) unsigned uint2v;

// round-to-nearest-even f32 -> bf16
static __device__ inline ushort_t bf16r(float x) {
    unsigned u = __builtin_bit_cast(unsigned, x);
    u = (u + 0x7FFFu + ((u >> 16) & 1u)) >> 16;
    return (ushort_t)u;
}
static __device__ inline float bf16tof(ushort_t h) {
    unsigned u = ((unsigned)h) << 16;
    return __builtin_bit_cast(float, u);
}
// pack two f32 -> u32 of 2 bf16 (lo, hi) -- software RNE
static __device__ inline unsigned pack_bf16(float lo, float hi) {
    unsigned a = __builtin_bit_cast(unsigned, lo);
    unsigned b = __builtin_bit_cast(unsigned, hi);
    a = (a + 0x7FFFu + ((a >> 16) & 1u)) >> 16;
    b = (b + 0x7FFFu + ((b >> 16) & 1u)) >> 16;
    return a | (b << 16);
}
// HW v_cvt_pk_bf16_f32 path (RNE, identical bits) for VALU-bound kernels
static __device__ inline unsigned cvtpk(float lo, float hi) {
    float2 f2; f2.x = lo; f2.y = hi;
    __hip_bfloat162 h = __float22bfloat162_rn(f2);
    unsigned u;
    __builtin_memcpy(&u, &h, 4);
    return u;
}

using gptr_t = const __attribute__((address_space(1))) void*;
using lptr_t = __attribute__((address_space(3))) void*;
static __device__ inline void gload16(const void* g, void* l) {
    __builtin_amdgcn_global_load_lds((gptr_t)(uintptr_t)g, (lptr_t)(uintptr_t)l, 16, 0, 0);
}

// =====================================================================
// bf16 MFMA GEMM: C[M][ldc] = A[M][K](bf16) @ Bt[Npad][K](bf16)^T
// OUT16: write bf16 output
// =====================================================================
template<bool HASBIAS, bool OUT16>
__global__ __launch_bounds__(256, 2)
void gemm_bf16_kernel(const ushort_t* __restrict__ A,
                      const ushort_t* __restrict__ Bt,
                      const float* __restrict__ bias,
                      void* __restrict__ Cv,
                      int Nn, int K, int ldc) {
    constexpr int BM = 128, BK = 64;
    __shared__ __align__(16) ushort_t As[BM * BK];
    __shared__ __align__(16) ushort_t Bs[BM * BK];
    const int bm = blockIdx.x * BM;
    const int bn = blockIdx.y * BM;
    const int tid = threadIdx.x;
    const int l15 = tid & 15;
    const int g   = (tid & 63) >> 4;
    const int w   = tid >> 6;
    const int wr  = w >> 1, wc = w & 1;

    float4v acc[4][4];
    #pragma unroll
    for (int m = 0; m < 4; ++m)
        #pragma unroll
        for (int n = 0; n < 4; ++n) acc[m][n] = (float4v){0.f, 0.f, 0.f, 0.f};

    for (int k0 = 0; k0 < K; k0 += BK) {
        #pragma unroll
        for (int i = 0; i < 4; ++i) {
            int c = i * 256 + tid;
            int r = c >> 3, ch = c & 7;
            int sch = ch ^ (r & 7);
            gload16(A  + (size_t)(bm + r) * K + k0 + sch * 8, (void*)(As + c * 8));
            gload16(Bt + (size_t)(bn + r) * K + k0 + sch * 8, (void*)(Bs + c * 8));
        }
        __syncthreads();

        short8_t af[4][2], bfr[4][2];
        #pragma unroll
        for (int m = 0; m < 4; ++m) {
            int ar = wr * 64 + m * 16 + l15;
            #pragma unroll
            for (int h = 0; h < 2; ++h)
                af[m][h] = *(const short8_t*)((const char*)As + ar * 128 + (((h * 4 + g) ^ (ar & 7)) * 16));
        }
        #pragma unroll
        for (int n = 0; n < 4; ++n) {
            int br = wc * 64 + n * 16 + l15;
            #pragma unroll
            for (int h = 0; h < 2; ++h)
                bfr[n][h] = *(const short8_t*)((const char*)Bs + br * 128 + (((h * 4 + g) ^ (br & 7)) * 16));
        }
        #pragma unroll
        for (int m = 0; m < 4; ++m)
            #pragma unroll
            for (int n = 0; n < 4; ++n) {
                acc[m][n] = __builtin_amdgcn_mfma_f32_16x16x32_bf16(af[m][0], bfr[n][0], acc[m][n], 0, 0, 0);
                acc[m][n] = __builtin_amdgcn_mfma_f32_16x16x32_bf16(af[m][1], bfr[n][1], acc[m][n], 0, 0, 0);
            }
        __syncthreads();
    }

    #pragma unroll
    for (int n = 0; n < 4; ++n) {
        int ccol = bn + wc * 64 + n * 16 + l15;
        if (ccol < Nn) {
            float bv = HASBIAS ? bias[ccol] : 0.f;
            #pragma unroll
            for (int m = 0; m < 4; ++m) {
                int crow = bm + wr * 64 + m * 16 + g * 4;
                #pragma unroll
                for (int j = 0; j < 4; ++j) {
                    float v = acc[m][n][j] + bv;
                    if (OUT16)
                        ((ushort_t*)Cv)[(size_t)(crow + j) * ldc + ccol] = bf16r(v);
                    else
                        ((float*)Cv)[(size_t)(crow + j) * ldc + ccol] = v;
                }
            }
        }
    }
}

// =====================================================================
// weight convert: Wt[Npad][K] bf16 from W
// =====================================================================
__global__ __launch_bounds__(256)
void convw_kernel(const float* __restrict__ W, ushort_t* __restrict__ Wt,
                  int K, int Nn, int transpose) {
    int idx = blockIdx.x * 256 + threadIdx.x;
    int n = idx / K, k = idx % K;
    float v = 0.f;
    if (n < Nn) v = transpose ? W[(size_t)k * Nn + n] : W[(size_t)n * K + k];
    Wt[idx] = bf16r(v);
}

// sr_w transpose: wT[f][o] = sr_w[o*256 + f]
__global__ __launch_bounds__(256)
void srwt_kernel(const float* __restrict__ W, float* __restrict__ wT) {
    int idx = blockIdx.x * 256 + threadIdx.x;
    int f = idx >> 6, o = idx & 63;
    wT[idx] = W[o * 256 + f];
}

// fp32 -> bf16 bulk convert, 8 elems/thread
__global__ __launch_bounds__(256)
void convx_kernel(const float* __restrict__ in, ushort_t* __restrict__ outp) {
    int i = blockIdx.x * 256 + threadIdx.x;
    const float4v* p = (const float4v*)(in + (size_t)i * 8);
    float4v a = p[0], b = p[1];
    uint4v u;
    u[0] = pack_bf16(a[0], a[1]);
    u[1] = pack_bf16(a[2], a[3]);
    u[2] = pack_bf16(b[0], b[1]);
    u[3] = pack_bf16(b[2], b[3]);
    *(uint4v*)(outp + (size_t)i * 8) = u;
}

// =====================================================================
// sr-conv (coalesced wT) + LayerNorm(64) + kv GEMM (64->128)
// K written as bf16 PRE-SCALED by 0.125*log2(e)
// =====================================================================
__global__ __launch_bounds__(64)
void srlnkv_kernel(const float* __restrict__ x,
                   const float* __restrict__ wT, const float* __restrict__ sr_b,
                   const float* __restrict__ ln_g, const float* __restrict__ ln_b,
                   const float* __restrict__ wkv,
                   ushort_t* __restrict__ kgb, float* __restrict__ vg) {
    const int pos = blockIdx.x;
    const int b = pos / NR_, n = pos % NR_;
    const int y = n / HS_, xx = n % HS_;
    const int o = threadIdx.x;
    __shared__ float xs[4][64];
    __shared__ float lnv_s[64];
    #pragma unroll
    for (int tap = 0; tap < 4; ++tap) {
        int ky = tap / 2, kx = tap % 2;
        xs[tap][o] = x[((size_t)b * N_ + (2 * y + ky) * Wimg + 2 * xx + kx) * DIM_ + o];
    }
    __syncthreads();
    float sum = sr_b[o];
    for (int i = 0; i < 64; ++i) {
        const float* wr = wT + (i * 4) * 64 + o;
        sum += xs[0][i] * wr[0] + xs[1][i] * wr[64] + xs[2][i] * wr[128] + xs[3][i] * wr[192];
    }
    float m = sum;
    #pragma unroll
    for (int off = 1; off < 64; off <<= 1) m += __shfl_xor(m, off);
    m *= (1.0f / 64.0f);
    float d = sum - m;
    float v = d * d;
    #pragma unroll
    for (int off = 1; off < 64; off <<= 1) v += __shfl_xor(v, off);
    v *= (1.0f / 64.0f);
    float lnv = d * rsqrtf(v + 1e-5f) * ln_g[o] + ln_b[o];
    lnv_s[o] = lnv;
    __syncthreads();
    float s0 = 0.f, s1 = 0.f;
    for (int i = 0; i < 64; ++i) {
        float lv = lnv_s[i];
        s0 += lv * wkv[i * 128 + o];
        s1 += lv * wkv[i * 128 + o + 64];
    }
    const float SCK = 0.125f * 1.44269504088896340736f;
    kgb[((size_t)b * NR_ + n) * 64 + o] = bf16r(s0 * SCK);
    vg[((size_t)b * NR_ + n) * 64 + o] = s1;
}

// =====================================================================
// depthwise 3x3 + bias on v_g image; vg2 = vg + conv (fp32)
// =====================================================================
__global__ __launch_bounds__(256)
void lcg_kernel(const float* __restrict__ vg, const float* __restrict__ w,
                const float* __restrict__ bias, float* __restrict__ vg2) {
    int idx = blockIdx.x * 256 + threadIdx.x;
    if (idx >= B_ * NR_ * 64) return;
    int c = idx % 64;
    int n = (idx / 64) % NR_;
    int b = idx / (64 * NR_);
    int y = n / HS_, xx = n % HS_;
    float sum = vg[idx] + bias[c];
    #pragma unroll
    for (int ky = 0; ky < 3; ++ky)
        #pragma unroll
        for (int kx = 0; kx < 3; ++kx) {
            int yy = y + ky - 1, x2 = xx + kx - 1;
            if (yy >= 0 && yy < HS_ && x2 >= 0 && x2 < HS_)
                sum += vg[((size_t)b * NR_ + yy * HS_ + x2) * 64 + c] * w[c * 9 + ky * 3 + kx];
        }
    vg2[idx] = sum;
}

// =====================================================================
// transpose+convert: vg2 fp32 [B][NR][64] -> vtb bf16 [B][64][NR]
// =====================================================================
__global__ __launch_bounds__(256)
void vtrans_kernel(const float* __restrict__ vg2, ushort_t* __restrict__ vtb) {
    __shared__ float ld[64][65];
    const int b = blockIdx.y, n0 = blockIdx.x * 64, tid = threadIdx.x;
    #pragma unroll
    for (int i = 0; i < 16; ++i) {
        int idx = i * 256 + tid;
        int n = idx >> 6, c = idx & 63;
        ld[n][c] = vg2[((size_t)b * NR_ + n0 + n) * 64 + c];
    }
    __syncthreads();
    #pragma unroll
    for (int i = 0; i < 16; ++i) {
        int idx = i * 256 + tid;
        int d = idx >> 6, nn = idx & 63;
        vtb[(size_t)(b * 64 + d) * NR_ + n0 + nn] = bf16r(ld[nn][d]);
    }
}

// =====================================================================
// Global-branch flash attention, split-K=8, bf16 MFMA, register-PV via
// K row-permutation pi. 512 threads / 8 waves / 128 q-rows per block.
// Two-tile batching.
// =====================================================================
__global__ __launch_bounds__(512)
void attn_global_split2(const ushort_t* __restrict__ q16,
                        const ushort_t* __restrict__ kgb,
                        const ushort_t* __restrict__ vtb,
                        ushort_t* __restrict__ osp16, float* __restrict__ mls) {
    __shared__ __align__(16) ushort_t Ks[2 * 64 * 64];
    __shared__ __align__(16) ushort_t Vs[2 * 64 * 64];
    const int split = blockIdx.y & 7;
    const int b     = blockIdx.y >> 3;
    const int q0    = blockIdx.x * 128;
    const int tid   = threadIdx.x;
    const int w     = tid >> 6;
    const int l     = tid & 63;
    const int l15   = l & 15;
    const int g     = l >> 4;
    const int lx    = l15 & 7;

    short8_t qf[2];
    {
        const ushort_t* qrow = q16 + ((size_t)b * N_ + q0 + w * 16 + l15) * DIM_;
        qf[0] = *(const short8_t*)(qrow + g * 8);
        qf[1] = *(const short8_t*)(qrow + g * 8 + 32);
    }

    float4v o[4];
    #pragma unroll
    for (int i = 0; i < 4; ++i) o[i] = (float4v){0.f, 0.f, 0.f, 0.f};
    float m_run = -3.0e38f, l_run = 0.f;   // l_run is LANE-PARTIAL (row l15)

    const int stg_r   = tid >> 3;
    const int stg_sch = (tid & 7) ^ (stg_r & 7);
    const int stg_pr  = (stg_r & 32) | (((stg_r >> 2) & 3) << 3) | (((stg_r >> 4) & 1) << 2) | (stg_r & 3);
    auto stage = [&](int t, int buf) {
        const int k0 = t * 64;
        gload16(kgb + ((size_t)(b * NR_ + k0 + stg_pr) << 6) + stg_sch * 8,
                (void*)(Ks + buf * 4096 + tid * 8));
        gload16(vtb + (size_t)(b * 64 + stg_r) * NR_ + k0 + stg_sch * 8,
                (void*)(Vs + buf * 4096 + tid * 8));
    };

    auto compute = [&](const ushort_t* Kb, const ushort_t* Vb) {
        float4v sc[4];
        #pragma unroll
        for (int c = 0; c < 4; ++c) {
            float4v acc = (float4v){0.f, 0.f, 0.f, 0.f};
            #pragma unroll
            for (int dc = 0; dc < 2; ++dc) {
                int row = c * 16 + l15;
                short8_t ak = *(const short8_t*)((const char*)Kb + row * 128 + (((g + 4 * dc) ^ lx) * 16));
                acc = __builtin_amdgcn_mfma_f32_16x16x32_bf16(ak, qf[dc], acc, 0, 0, 0);
            }
            sc[c] = acc;
        }

        float tmax = fmaxf(fmaxf(fmaxf(sc[0][0], sc[0][1]), fmaxf(sc[0][2], sc[0][3])),
                           fmaxf(fmaxf(sc[1][0], sc[1][1]), fmaxf(sc[1][2], sc[1][3])));
        tmax = fmaxf(tmax, fmaxf(fmaxf(fmaxf(sc[2][0], sc[2][1]), fmaxf(sc[2][2], sc[2][3])),
                                 fmaxf(fmaxf(sc[3][0], sc[3][1]), fmaxf(sc[3][2], sc[3][3]))));

        if (__any(tmax > m_run + 11.0f)) {
            float rmax = fmaxf(tmax, __shfl_xor(tmax, 16));
            rmax = fmaxf(rmax, __shfl_xor(rmax, 32));
            float m_new = fmaxf(m_run, rmax);
            float corr = __builtin_amdgcn_exp2f(m_run - m_new);
            float co[4];
            #pragma unroll
            for (int r = 0; r < 4; ++r) co[r] = __shfl(corr, g * 4 + r);
            #pragma unroll
            for (int dc = 0; dc < 4; ++dc)
                #pragma unroll
                for (int r = 0; r < 4; ++r) o[dc][r] *= co[r];
            l_run *= corr;
            m_run = m_new;
        }

        float p[4][4];
        float ladd = 0.f;
        #pragma unroll
        for (int c = 0; c < 4; ++c)
            #pragma unroll
            for (int r = 0; r < 4; ++r) {
                float pe = __builtin_amdgcn_exp2f(sc[c][r] - m_run);
                p[c][r] = pe;
                ladd += pe;
            }
        l_run += ladd;

        #pragma unroll
        for (int kkc = 0; kkc < 2; ++kkc) {
            uint4v au;
            au[0] = cvtpk(p[2 * kkc][0],     p[2 * kkc][1]);
            au[1] = cvtpk(p[2 * kkc][2],     p[2 * kkc][3]);
            au[2] = cvtpk(p[2 * kkc + 1][0], p[2 * kkc + 1][1]);
            au[3] = cvtpk(p[2 * kkc + 1][2], p[2 * kkc + 1][3]);
            short8_t ap = __builtin_bit_cast(short8_t, au);
            #pragma unroll
            for (int dc = 0; dc < 4; ++dc) {
                int vrow = dc * 16 + l15;
                short8_t bv = *(const short8_t*)((const char*)Vb + vrow * 128 + (((kkc * 4 + g) ^ lx) * 16));
                o[dc] = __builtin_amdgcn_mfma_f32_16x16x32_bf16(ap, bv, o[dc], 0, 0, 0);
            }
        }
    };

    const int t0 = (split * 49) / 8;
    const int t1 = ((split + 1) * 49) / 8;
    int t = t0;
    for (; t + 1 < t1; t += 2) {
        stage(t, 0);
        stage(t + 1, 1);
        __syncthreads();
        compute(Ks, Vs);
        compute(Ks + 4096, Vs + 4096);
        __syncthreads();
    }
    if (t < t1) {
        stage(t, 0);
        __syncthreads();
        compute(Ks, Vs);
    }

    float l_tot = l_run;
    l_tot += __shfl_xor(l_tot, 16);
    l_tot += __shfl_xor(l_tot, 32);

    const size_t rbase = (size_t)(split * B_ + b) * N_;
    #pragma unroll
    for (int dc = 0; dc < 4; ++dc)
        #pragma unroll
        for (int r = 0; r < 4; ++r) {
            int row = q0 + w * 16 + g * 4 + r;
            osp16[(rbase + row) * 64 + dc * 16 + l15] = bf16r(o[dc][r]);
        }
    if (l < 16) {
        int row = q0 + w * 16 + l15;
        mls[(rbase + row) * 2]     = m_run;
        mls[(rbase + row) * 2 + 1] = l_tot;
    }
}

// =====================================================================
// combine the 8 splits (exp2 domain, bf16 osp) -> catb cols [0,64)
// =====================================================================
__global__ __launch_bounds__(256)
void attn_combine(const ushort_t* __restrict__ osp16, const float* __restrict__ mls,
                  ushort_t* __restrict__ catb) {
    int idx = blockIdx.x * 256 + threadIdx.x;
    int col = idx & 63;
    size_t rn = (size_t)(idx >> 6);
    const size_t BN = (size_t)B_ * N_;
    float ms[NSPLIT], ls[NSPLIT];
    float m = -3.0e38f;
    #pragma unroll
    for (int s = 0; s < NSPLIT; ++s) {
        ms[s] = mls[(s * BN + rn) * 2];
        ls[s] = mls[(s * BN + rn) * 2 + 1];
        m = fmaxf(m, ms[s]);
    }
    float lsum = 0.f, acc = 0.f;
    #pragma unroll
    for (int s = 0; s < NSPLIT; ++s) {
        float wgt = __builtin_amdgcn_exp2f(ms[s] - m);
        lsum += ls[s] * wgt;
        acc  += bf16tof(osp16[(s * BN + rn) * 64 + col]) * wgt;
    }
    catb[rn * DIM_ + col] = bf16r(acc / lsum);
}

// =====================================================================
// depthwise 3x3 + bias on x_l (bf16 input xbf), 4ch x 4row / thread
// =====================================================================
__global__ __launch_bounds__(256)
void dwt_kernel(const ushort_t* __restrict__ xbf, const float* __restrict__ w,
                const float* __restrict__ bias, ushort_t* __restrict__ out) {
    int idx = blockIdx.x * 256 + threadIdx.x;
    int c4 = idx % 112;
    int t1 = idx / 112;
    int xx = t1 % 112;
    int t2 = t1 / 112;
    int yg = t2 % 28;
    int b  = t2 / 28;
    int c0 = c4 * 4;
    int y0 = yg * 4;

    float4v w4[9];
    #pragma unroll
    for (int kt = 0; kt < 9; ++kt) {
        w4[kt][0] = w[(c0 + 0) * 9 + kt];
        w4[kt][1] = w[(c0 + 1) * 9 + kt];
        w4[kt][2] = w[(c0 + 2) * 9 + kt];
        w4[kt][3] = w[(c0 + 3) * 9 + kt];
    }
    float4v bv = *(const float4v*)(bias + c0);
    float4v acc[4];
    #pragma unroll
    for (int o2 = 0; o2 < 4; ++o2) acc[o2] = bv;

    #pragma unroll
    for (int yy = 0; yy < 6; ++yy) {
        int Y = y0 - 1 + yy;
        if (Y < 0 || Y >= Himg) continue;
        #pragma unroll
        for (int xt = 0; xt < 3; ++xt) {
            int X = xx - 1 + xt;
            if (X < 0 || X >= Wimg) continue;
            uint2v q2 = *(const uint2v*)(xbf + ((size_t)b * N_ + Y * Wimg + X) * DIM_ + D0_ + c0);
            float4v v;
            v[0] = bf16tof((ushort_t)(q2[0] & 0xffffu));
            v[1] = bf16tof((ushort_t)(q2[0] >> 16));
            v[2] = bf16tof((ushort_t)(q2[1] & 0xffffu));
            v[3] = bf16tof((ushort_t)(q2[1] >> 16));
            constexpr int olo_t[6] = {0, 0, 0, 1, 2, 3};
            constexpr int ohi_t[6] = {0, 1, 2, 3, 3, 3};
            #pragma unroll
            for (int o2 = olo_t[yy]; o2 <= ohi_t[yy]; ++o2) {
                float4v wv = w4[(yy - o2) * 3 + xt];
                acc[o2][0] += v[0] * wv[0];
                acc[o2][1] += v[1] * wv[1];
                acc[o2][2] += v[2] * wv[2];
                acc[o2][3] += v[3] * wv[3];
            }
        }
    }
    #pragma unroll
    for (int o2 = 0; o2 < 4; ++o2) {
        uint2v pk;
        pk[0] = pack_bf16(acc[o2][0], acc[o2][1]);
        pk[1] = pack_bf16(acc[o2][2], acc[o2][3]);
        *(uint2v*)(out + ((size_t)b * N_ + (y0 + o2) * Wimg + xx) * DL_ + c0) = pk;
    }
}

// =====================================================================
// "scrambled mean", block-parallel: one block per (b,h,n). bf16 kvl.
// =====================================================================
template<int L, int NBW, int STRIDE, int DIL, int CHOFF>
__global__ void local_mean2_kernel(const ushort_t* __restrict__ kvl16,
                                   float* __restrict__ kvm) {
    __shared__ float slo[L], shi[L];
    const int blk = blockIdx.x;
    const int n = blk % 49;
    const int h = (blk / 49) % NH_;
    const int b = blk / (49 * NH_);
    const int wy = n / 7, wx = n % 7;
    const int t = threadIdx.x;

    if (t < L) {
        const int by = t / NBW, bx = t % NBW;
        int Y = by * STRIDE + DIL * wy;
        int X = bx * STRIDE + DIL * wx;
        if (Y >= Himg) Y = 2 * Himg - 2 - Y;
        if (X >= Wimg) X = 2 * Wimg - 2 - X;
        const ushort_t* src = kvl16 + ((size_t)b * N_ + Y * Wimg + X) * DL_ + CHOFF + h * HD_;
        float v[28];
        #pragma unroll
        for (int i = 0; i < 7; ++i) {
            uint2v q2 = ((const uint2v*)src)[i];
            v[i * 4]     = bf16tof((ushort_t)(q2[0] & 0xffffu));
            v[i * 4 + 1] = bf16tof((ushort_t)(q2[0] >> 16));
            v[i * 4 + 2] = bf16tof((ushort_t)(q2[1] & 0xffffu));
            v[i * 4 + 3] = bf16tof((ushort_t)(q2[1] >> 16));
        }
        const int f0 = t * HD_;
        const int bin0 = f0 / L;
        const int nlo = min(HD_, (bin0 + 1) * L - f0);
        float s0 = 0.f, s1 = 0.f;
        #pragma unroll
        for (int j = 0; j < HD_; ++j) {
            if (j < nlo) s0 += v[j]; else s1 += v[j];
        }
        slo[t] = s0;
        shi[t] = s1;
    }
    __syncthreads();
    if (t < HD_) {
        const int t_lo = (t * L) / HD_;
        const int t_hi = min(L - 1, (t * L + L - 1) / HD_);
        float sum = 0.f;
        for (int u = t_lo; u <= t_hi; ++u) {
            int f0 = u * HD_;
            int b0 = f0 / L;
            int b1 = (f0 + HD_ - 1) / L;
            if (b0 == t) sum += slo[u];
            if (b1 == t && b1 != b0) sum += shi[u];
        }
        kvm[(size_t)blk * HD_ + t] = sum * (1.0f / (float)L);
    }
}

// =====================================================================
// kv = kvm @ fc_w @ sh_w -> (B*NH, 49, 56)
// =====================================================================
__global__ __launch_bounds__(64)
void fcsh_kernel(const float* __restrict__ kvm, const float* __restrict__ fcw,
                 const float* __restrict__ shw, float* __restrict__ out) {
    int bh = blockIdx.x;
    __shared__ float kin[49][28];
    __shared__ float tmp[49][28];
    __shared__ float fw[28 * 28];
    __shared__ float sw[28 * 56];
    int t = threadIdx.x;
    for (int i = t; i < 49 * 28; i += 64) kin[i / 28][i % 28] = kvm[bh * 49 * 28 + i];
    for (int i = t; i < 28 * 28; i += 64) fw[i] = fcw[i];
    for (int i = t; i < 28 * 56; i += 64) sw[i] = shw[i];
    __syncthreads();
    for (int i = t; i < 49 * 28; i += 64) {
        int rr = i / 28, j = i % 28;
        float s = 0.f;
        for (int k = 0; k < 28; ++k) s += kin[rr][k] * fw[k * 28 + j];
        tmp[rr][j] = s;
    }
    __syncthreads();
    for (int i = t; i < 49 * 56; i += 64) {
        int rr = i / 56, j = i % 56;
        float s = 0.f;
        for (int k = 0; k < 28; ++k) s += tmp[rr][k] * sw[k * 56 + j];
        out[bh * 49 * 56 + i] = s;
    }
}

// =====================================================================
// v_ + depthwise3x3(v_img 7x7) + bias -> vc (B*NH, 49, 28)
// =====================================================================
__global__ __launch_bounds__(256)
void vconv_kernel(const float* __restrict__ kvsh, const float* __restrict__ w,
                  const float* __restrict__ bias, float* __restrict__ vc) {
    int idx = blockIdx.x * 256 + threadIdx.x;
    if (idx >= B_ * NH_ * 49 * HD_) return;
    int d  = idx % HD_;
    int n  = (idx / HD_) % 49;
    int bh = idx / (HD_ * 49);
    int h  = bh % NH_;
    int y = n / 7, xx = n % 7;
    int c = h * HD_ + d;
    float sum = kvsh[(bh * 49 + n) * 56 + 28 + d] + bias[c];
    #pragma unroll
    for (int ky = 0; ky < 3; ++ky)
        #pragma unroll
        for (int kx = 0; kx < 3; ++kx) {
            int yy = y + ky - 1, x2 = xx + kx - 1;
            if (yy >= 0 && yy < 7 && x2 >= 0 && x2 < 7)
                sum += kvsh[(bh * 49 + yy * 7 + x2) * 56 + 28 + d] * w[c * 9 + ky * 3 + kx];
        }
    vc[idx] = sum;
}

// =====================================================================
// Local attention via MFMA, both branches fused.
// =====================================================================
__global__ __launch_bounds__(256)
void attn_local_mfma(const ushort_t* __restrict__ q16,
                     const float* __restrict__ kv1, const float* __restrict__ v1c,
                     const float* __restrict__ kv2, const float* __restrict__ v2c,
                     ushort_t* __restrict__ catb) {
    __shared__ __align__(16) ushort_t Ks[64 * 32];   // [pi-row][d pad32]
    __shared__ __align__(16) ushort_t Vt[32 * 64];   // [d pad32][kcol pad64]
    const int ybh    = blockIdx.y;          // 0..31
    const int branch = ybh & 1;
    const int bh     = ybh >> 1;            // b*NH + h
    const int b      = bh >> 3, h = bh & 7;
    const int q0     = blockIdx.x * 64;
    const int tid    = threadIdx.x;
    const int w      = tid >> 6;
    const int l      = tid & 63;
    const int l15    = l & 15;
    const int g      = l >> 4;
    const float SC2K = 0.1889822365046136f * 1.44269504088896340736f; // 28^-.5 * log2e

    const float* kvsh = branch ? kv2 : kv1;
    const float* vc   = branch ? v2c : v1c;
    const int qoff    = D0_ + h * 56 + branch * 28;
    const int outoff  = (branch ? D0_ + 224 : D0_) + h * HD_;

    // ---- stage K (pre-scaled): LDS row r <- kcol pi(r), d padded to 32 ----
    {
        int row = tid >> 2, lc = tid & 3;
        int pr = (row & 32) | (((row >> 2) & 3) << 3) | (((row >> 4) & 1) << 2) | (row & 3);
        uint4v u = (uint4v){0u, 0u, 0u, 0u};
        if (pr < 49) {
            const float* src = kvsh + (bh * 49 + pr) * 56 + lc * 8;
            float vv[8];
            #pragma unroll
            for (int j2 = 0; j2 < 8; ++j2)
                vv[j2] = (lc * 8 + j2 < 28) ? src[j2] * SC2K : 0.f;
            u[0] = cvtpk(vv[0], vv[1]);
            u[1] = cvtpk(vv[2], vv[3]);
            u[2] = cvtpk(vv[4], vv[5]);
            u[3] = cvtpk(vv[6], vv[7]);
        }
        *(uint4v*)(Ks + row * 32 + (lc ^ (row & 3)) * 8) = u;
    }
    // ---- stage Vt[d][kcol] ----
    {
        int row = tid >> 3, lc = tid & 7;
        uint4v u = (uint4v){0u, 0u, 0u, 0u};
        if (row < 28) {
            float vv[8];
            #pragma unroll
            for (int j2 = 0; j2 < 8; ++j2) {
                int kc = lc * 8 + j2;
                vv[j2] = (kc < 49) ? vc[(bh * 49 + kc) * 28 + row] : 0.f;
            }
            u[0] = cvtpk(vv[0], vv[1]);
            u[1] = cvtpk(vv[2], vv[3]);
            u[2] = cvtpk(vv[4], vv[5]);
            u[3] = cvtpk(vv[6], vv[7]);
        }
        *(uint4v*)(Vt + row * 64 + (lc ^ (row & 7)) * 8) = u;
    }
    // ---- Q fragment: raw bf16 (8B loads; g==3 upper half zero) ----
    short8_t qf;
    {
        const ushort_t* qp = q16 + ((size_t)b * N_ + q0 + w * 16 + l15) * DIM_ + qoff + g * 8;
        uint2v a01 = *(const uint2v*)qp;
        uint2v a23 = (g < 3) ? *(const uint2v*)(qp + 4) : (uint2v){0u, 0u};
        uint4v uv;
        uv[0] = a01[0]; uv[1] = a01[1]; uv[2] = a23[0]; uv[3] = a23[1];
        qf = __builtin_bit_cast(short8_t, uv);
    }
    __syncthreads();

    // ---- scores ----
    float4v sc4[4];
    #pragma unroll
    for (int c = 0; c < 4; ++c) {
        int row = c * 16 + l15;
        short8_t ak = *(const short8_t*)(Ks + row * 32 + ((g ^ (row & 3)) * 8));
        float4v acc = (float4v){0.f, 0.f, 0.f, 0.f};
        sc4[c] = __builtin_amdgcn_mfma_f32_16x16x32_bf16(ak, qf, acc, 0, 0, 0);
    }

    // ---- softmax over 49 keys ----
    float tmax = fmaxf(fmaxf(fmaxf(sc4[0][0], sc4[0][1]), fmaxf(sc4[0][2], sc4[0][3])),
                       fmaxf(fmaxf(sc4[1][0], sc4[1][1]), fmaxf(sc4[1][2], sc4[1][3])));
    tmax = fmaxf(tmax, fmaxf(fmaxf(fmaxf(sc4[2][0], sc4[2][1]), fmaxf(sc4[2][2], sc4[2][3])),
                             fmaxf(fmaxf(sc4[3][0], sc4[3][1]), fmaxf(sc4[3][2], sc4[3][3]))));
    tmax = fmaxf(tmax, __shfl_xor(tmax, 16));
    tmax = fmaxf(tmax, __shfl_xor(tmax, 32));

    float p[4][4];
    float lsum = 0.f;
    #pragma unroll
    for (int c = 0; c < 4; ++c)
        #pragma unroll
        for (int r = 0; r < 4; ++r) {
            float pe = __builtin_amdgcn_exp2f(sc4[c][r] - tmax);
            if (c >= 2 && (8 * g + 4 * (c & 1) + r) >= 17) pe = 0.f;
            p[c][r] = pe;
            lsum += pe;
        }
    lsum += __shfl_xor(lsum, 16);
    lsum += __shfl_xor(lsum, 32);
    float inv = 1.0f / lsum;

    // ---- PV ----
    float4v o2[2];
    o2[0] = (float4v){0.f, 0.f, 0.f, 0.f};
    o2[1] = (float4v){0.f, 0.f, 0.f, 0.f};
    #pragma unroll
    for (int kkc = 0; kkc < 2; ++kkc) {
        uint4v au;
        au[0] = cvtpk(p[2 * kkc][0],     p[2 * kkc][1]);
        au[1] = cvtpk(p[2 * kkc][2],     p[2 * kkc][3]);
        au[2] = cvtpk(p[2 * kkc + 1][0], p[2 * kkc + 1][1]);
        au[3] = cvtpk(p[2 * kkc + 1][2], p[2 * kkc + 1][3]);
        short8_t ap = __builtin_bit_cast(short8_t, au);
        #pragma unroll
        for (int dc = 0; dc < 2; ++dc) {
            int vrow = dc * 16 + l15;
            short8_t bv = *(const short8_t*)(Vt + vrow * 64 + (((kkc * 4 + g) ^ (vrow & 7)) * 8));
            o2[dc] = __builtin_amdgcn_mfma_f32_16x16x32_bf16(ap, bv, o2[dc], 0, 0, 0);
        }
    }

    // ---- normalize + store (d < 28) ----
    float irow[4];
    #pragma unroll
    for (int r = 0; r < 4; ++r) irow[r] = __shfl(inv, g * 4 + r);
    #pragma unroll
    for (int dc = 0; dc < 2; ++dc) {
        int d = dc * 16 + l15;
        if (d < 28) {
            #pragma unroll
            for (int r = 0; r < 4; ++r) {
                int row = q0 + w * 16 + g * 4 + r;
                catb[((size_t)b * N_ + row) * DIM_ + outoff + d] = bf16r(o2[dc][r] * irow[r]);
            }
        }
    }
}

// =====================================================================
extern "C" void kernel_launch(void* const* d_in, const int* in_sizes, int n_in,
                              void* d_out, int out_size, void* d_ws, size_t ws_size,
                              hipStream_t stream) {
    const float* x      = (const float*)d_in[0];
    const float* Wq     = (const float*)d_in[1];
    const float* Wkv_g  = (const float*)d_in[2];
    const float* sr_w   = (const float*)d_in[3];
    const float* sr_b   = (const float*)d_in[4];
    const float* ln_g   = (const float*)d_in[5];
    const float* ln_b   = (const float*)d_in[6];
    const float* lcg_w  = (const float*)d_in[7];
    const float* lcg_b  = (const float*)d_in[8];
    const float* kvl_dw = (const float*)d_in[9];
    const float* kvl_db = (const float*)d_in[10];
    const float* kvl_pw = (const float*)d_in[11];
    const float* kvl_pb = (const float*)d_in[12];
    const float* fc1_w  = (const float*)d_in[13];
    const float* sh1_w  = (const float*)d_in[14];
    const float* lc1_w  = (const float*)d_in[15];
    const float* lc1_b  = (const float*)d_in[16];
    const float* fc2_w  = (const float*)d_in[17];
    const float* sh2_w  = (const float*)d_in[18];
    const float* lc2_w  = (const float*)d_in[19];
    const float* lc2_b  = (const float*)d_in[20];
    const float* proj_w = (const float*)d_in[21];
    const float* proj_b = (const float*)d_in[22];
    float* out = (float*)d_out;
    char* base = (char*)d_ws;

    // ---- workspace layout (256B aligned) ----
    size_t o = 0;
    auto alloc = [&](size_t bytes) -> void* {
        void* p = base + o;
        o = (o + bytes + 255) & ~(size_t)255;
        return p;
    };
    // shared region: kvl16 (bf16, B*N*DL) first; later reused as osp16+mls
    const size_t kvl16_bytes = (size_t)B_ * N_ * DL_ * 2;
    const size_t ospml_bytes = (size_t)NSPLIT * B_ * N_ * 64 * 2 + (size_t)NSPLIT * B_ * N_ * 2 * 4;
    const size_t shared_bytes = kvl16_bytes > ospml_bytes ? kvl16_bytes : ospml_bytes;
    ushort_t* q16   = (ushort_t*)alloc((size_t)B_ * N_ * DIM_ * 2);
    char*     shreg = (char*)    alloc(shared_bytes);
    ushort_t* xcat  = (ushort_t*)alloc((size_t)B_ * N_ * DIM_ * 2);  // xbf, then cat
    ushort_t* dwtb  = (ushort_t*)alloc((size_t)B_ * N_ * DL_ * 2);
    ushort_t* kgb   = (ushort_t*)alloc((size_t)B_ * NR_ * 64 * 2);
    float*    vg    = (float*)   alloc((size_t)B_ * NR_ * 64 * 4);
    float*    vg2   = (float*)   alloc((size_t)B_ * NR_ * 64 * 4);
    ushort_t* vtb   = (ushort_t*)alloc((size_t)B_ * 64 * NR_ * 2);
    ushort_t* wqt   = (ushort_t*)alloc((size_t)512 * 512 * 2);
    ushort_t* pwt   = (ushort_t*)alloc((size_t)512 * 448 * 2);
    ushort_t* projt = (ushort_t*)alloc((size_t)512 * 512 * 2);
    float*    srwt  = (float*)   alloc((size_t)256 * 64 * 4);
    float*    kvm1  = (float*)   alloc((size_t)B_ * NH_ * 49 * HD_ * 4);
    float*    kvm2  = (float*)   alloc((size_t)B_ * NH_ * 49 * HD_ * 4);
    float*    kv1   = (float*)   alloc((size_t)B_ * NH_ * 49 * 56 * 4);
    float*    kv2   = (float*)   alloc((size_t)B_ * NH_ * 49 * 56 * 4);
    float*    v1c   = (float*)   alloc((size_t)B_ * NH_ * 49 * HD_ * 4);
    float*    v2c   = (float*)   alloc((size_t)B_ * NH_ * 49 * HD_ * 4);
    ushort_t* xbf   = xcat;
    ushort_t* catb  = xcat;
    ushort_t* kvl16 = (ushort_t*)shreg;                          // bf16 B*N*DL
    ushort_t* osp16 = (ushort_t*)shreg;                          // NSPLIT*B*N*64 bf16
    float*    mls   = (float*)(shreg + (size_t)NSPLIT * B_ * N_ * 64 * 2);

    const int M = B_ * N_;   // 25088

    // 0. weight converts + x -> bf16
    convw_kernel<<<512 * 512 / 256, 256, 0, stream>>>(Wq, wqt, 512, 512, 1);
    convw_kernel<<<512 * 448 / 256, 256, 0, stream>>>(kvl_pw, pwt, 448, 448, 0);
    convw_kernel<<<512 * 512 / 256, 256, 0, stream>>>(proj_w, projt, 512, 512, 1);
    srwt_kernel<<<64, 256, 0, stream>>>(sr_w, srwt);
    convx_kernel<<<(B_ * N_ * DIM_ / 8) / 256, 256, 0, stream>>>(x, xbf);

    // 1. q16 = bf16(x @ Wq)
    gemm_bf16_kernel<false, true><<<dim3(M / 128, 4), 256, 0, stream>>>(
        xbf, wqt, nullptr, q16, 512, 512, 512);

    // 2. depthwise on x_l (bf16 input) -> dwtb (bf16)
    dwt_kernel<<<(B_ * 28 * 112 * 112) / 256, 256, 0, stream>>>(xbf, kvl_dw, kvl_db, dwtb);

    // 3. pointwise: kvl16 = bf16(dwtb @ pwt^T + pb)
    gemm_bf16_kernel<true, true><<<dim3(M / 128, 4), 256, 0, stream>>>(
        dwtb, pwt, kvl_pb, kvl16, 448, 448, 448);

    // 4. global branch: sr conv + LN + kv (K bf16, pre-scaled exp2 domain)
    srlnkv_kernel<<<B_ * NR_, 64, 0, stream>>>(x, srwt, sr_b, ln_g, ln_b, Wkv_g, kgb, vg);

    // 5. vg2 = vg + depthwise(vg); then transpose+convert to vtb
    lcg_kernel<<<(B_ * NR_ * 64) / 256, 256, 0, stream>>>(vg, lcg_w, lcg_b, vg2);
    vtrans_kernel<<<dim3(NR_ / 64, B_), 256, 0, stream>>>(vg2, vtb);

    // 7-9. local branch pipeline (consumes kvl16 BEFORE osp16 aliases it)
    {
        local_mean2_kernel<256, 16, 7, 1, 0><<<B_ * NH_ * 49, 256, 0, stream>>>(kvl16, kvm1);
        local_mean2_kernel<81, 9, 13, 2, 224><<<B_ * NH_ * 49, 128, 0, stream>>>(kvl16, kvm2);
        fcsh_kernel<<<B_ * NH_, 64, 0, stream>>>(kvm1, fc1_w, sh1_w, kv1);
        fcsh_kernel<<<B_ * NH_, 64, 0, stream>>>(kvm2, fc2_w, sh2_w, kv2);
        int tot = B_ * NH_ * 49 * HD_;
        int blocks = (tot + 255) / 256;
        vconv_kernel<<<blocks, 256, 0, stream>>>(kv1, lc1_w, lc1_b, v1c);
        vconv_kernel<<<blocks, 256, 0, stream>>>(kv2, lc2_w, lc2_b, v2c);
    }

    // 6. global flash attention, split-K=8 (register-PV, 512-thread blocks)
    attn_global_split2<<<dim3(N_ / 128, B_ * NSPLIT), 512, 0, stream>>>(q16, kgb, vtb, osp16, mls);
    attn_combine<<<(B_ * N_ * 64) / 256, 256, 0, stream>>>(osp16, mls, catb);

    // 10. local attention (MFMA, both branches) -> catb cols [64,512)
    attn_local_mfma<<<dim3(N_ / 64, B_ * NH_ * 2), 256, 0, stream>>>(
        q16, kv1, v1c, kv2, v2c, catb);

    // 11. out = catb @ projt^T + proj_b
    gemm_bf16_kernel<true, false><<<dim3(M / 128, 4), 256, 0, stream>>>(
        catb, projt, proj_b, out, 512, 512, 512);
}

// Round 19
// 290.939 us; speedup vs baseline: 1.0718x; 1.0394x over previous
//
#include <hip/hip_runtime.h>
#include <hip/hip_bf16.h>
#include <math.h>
#include <stdint.h>

// ---- problem constants ----
static constexpr int B_    = 2;
static constexpr int N_    = 12544;   // 112*112
static constexpr int DIM_  = 512;
static constexpr int D0_   = 64;
static constexpr int DL_   = 448;
static constexpr int Himg  = 112;
static constexpr int Wimg  = 112;
static constexpr int HS_   = 56;
static constexpr int NR_   = 3136;    // 56*56
static constexpr int NH_   = 8;
static constexpr int HD_   = 28;
static constexpr int NSPLIT = 8;

typedef unsigned short ushort_t;
typedef __attribute__((ext_vector_type(8))) short short8_t;
typedef __attribute__((ext_vector_type(4))) float float4v;
typedef __attribute__((ext_vector_type(4))) unsigned uint4v;
typedef __attribute__((ext_vector_type(2))) unsigned uint2v;

// round-to-nearest-even f32 -> bf16
static __device__ inline ushort_t bf16r(float x) {
    unsigned u = __builtin_bit_cast(unsigned, x);
    u = (u + 0x7FFFu + ((u >> 16) & 1u)) >> 16;
    return (ushort_t)u;
}
static __device__ inline float bf16tof(ushort_t h) {
    unsigned u = ((unsigned)h) << 16;
    return __builtin_bit_cast(float, u);
}
// pack two f32 -> u32 of 2 bf16 (lo, hi) -- software RNE
static __device__ inline unsigned pack_bf16(float lo, float hi) {
    unsigned a = __builtin_bit_cast(unsigned, lo);
    unsigned b = __builtin_bit_cast(unsigned, hi);
    a = (a + 0x7FFFu + ((a >> 16) & 1u)) >> 16;
    b = (b + 0x7FFFu + ((b >> 16) & 1u)) >> 16;
    return a | (b << 16);
}
// HW v_cvt_pk_bf16_f32 path (RNE, identical bits) for VALU-bound kernels
static __device__ inline unsigned cvtpk(float lo, float hi) {
    float2 f2; f2.x = lo; f2.y = hi;
    __hip_bfloat162 h = __float22bfloat162_rn(f2);
    unsigned u;
    __builtin_memcpy(&u, &h, 4);
    return u;
}

using gptr_t = const __attribute__((address_space(1))) void*;
using lptr_t = __attribute__((address_space(3))) void*;
static __device__ inline void gload16(const void* g, void* l) {
    __builtin_amdgcn_global_load_lds((gptr_t)(uintptr_t)g, (lptr_t)(uintptr_t)l, 16, 0, 0);
}

// =====================================================================
// bf16 MFMA GEMM: C[M][ldc] = A[M][K](bf16) @ Bt[Npad][K](bf16)^T
// OUT16: write bf16 output
// =====================================================================
template<bool HASBIAS, bool OUT16>
__global__ __launch_bounds__(256, 2)
void gemm_bf16_kernel(const ushort_t* __restrict__ A,
                      const ushort_t* __restrict__ Bt,
                      const float* __restrict__ bias,
                      void* __restrict__ Cv,
                      int Nn, int K, int ldc) {
    constexpr int BM = 128, BK = 64;
    __shared__ __align__(16) ushort_t As[BM * BK];
    __shared__ __align__(16) ushort_t Bs[BM * BK];
    const int bm = blockIdx.x * BM;
    const int bn = blockIdx.y * BM;
    const int tid = threadIdx.x;
    const int l15 = tid & 15;
    const int g   = (tid & 63) >> 4;
    const int w   = tid >> 6;
    const int wr  = w >> 1, wc = w & 1;

    float4v acc[4][4];
    #pragma unroll
    for (int m = 0; m < 4; ++m)
        #pragma unroll
        for (int n = 0; n < 4; ++n) acc[m][n] = (float4v){0.f, 0.f, 0.f, 0.f};

    for (int k0 = 0; k0 < K; k0 += BK) {
        #pragma unroll
        for (int i = 0; i < 4; ++i) {
            int c = i * 256 + tid;
            int r = c >> 3, ch = c & 7;
            int sch = ch ^ (r & 7);
            gload16(A  + (size_t)(bm + r) * K + k0 + sch * 8, (void*)(As + c * 8));
            gload16(Bt + (size_t)(bn + r) * K + k0 + sch * 8, (void*)(Bs + c * 8));
        }
        __syncthreads();

        short8_t af[4][2], bfr[4][2];
        #pragma unroll
        for (int m = 0; m < 4; ++m) {
            int ar = wr * 64 + m * 16 + l15;
            #pragma unroll
            for (int h = 0; h < 2; ++h)
                af[m][h] = *(const short8_t*)((const char*)As + ar * 128 + (((h * 4 + g) ^ (ar & 7)) * 16));
        }
        #pragma unroll
        for (int n = 0; n < 4; ++n) {
            int br = wc * 64 + n * 16 + l15;
            #pragma unroll
            for (int h = 0; h < 2; ++h)
                bfr[n][h] = *(const short8_t*)((const char*)Bs + br * 128 + (((h * 4 + g) ^ (br & 7)) * 16));
        }
        #pragma unroll
        for (int m = 0; m < 4; ++m)
            #pragma unroll
            for (int n = 0; n < 4; ++n) {
                acc[m][n] = __builtin_amdgcn_mfma_f32_16x16x32_bf16(af[m][0], bfr[n][0], acc[m][n], 0, 0, 0);
                acc[m][n] = __builtin_amdgcn_mfma_f32_16x16x32_bf16(af[m][1], bfr[n][1], acc[m][n], 0, 0, 0);
            }
        __syncthreads();
    }

    #pragma unroll
    for (int n = 0; n < 4; ++n) {
        int ccol = bn + wc * 64 + n * 16 + l15;
        if (ccol < Nn) {
            float bv = HASBIAS ? bias[ccol] : 0.f;
            #pragma unroll
            for (int m = 0; m < 4; ++m) {
                int crow = bm + wr * 64 + m * 16 + g * 4;
                #pragma unroll
                for (int j = 0; j < 4; ++j) {
                    float v = acc[m][n][j] + bv;
                    if (OUT16)
                        ((ushort_t*)Cv)[(size_t)(crow + j) * ldc + ccol] = bf16r(v);
                    else
                        ((float*)Cv)[(size_t)(crow + j) * ldc + ccol] = v;
                }
            }
        }
    }
}

// =====================================================================
// merged prep: wqt, pwt, projt (bf16 weight converts), srwt, xbf
// grid-stride over 5 flat segments; bit-identical to the old 5 kernels
// =====================================================================
__global__ __launch_bounds__(256)
void prep_kernel(const float* __restrict__ Wq, const float* __restrict__ kvl_pw,
                 const float* __restrict__ proj_w, const float* __restrict__ sr_w,
                 const float* __restrict__ x,
                 ushort_t* __restrict__ wqt, ushort_t* __restrict__ pwt,
                 ushort_t* __restrict__ projt, float* __restrict__ srwt,
                 ushort_t* __restrict__ xbf) {
    int idx = blockIdx.x * 256 + threadIdx.x;
    if (idx < 262144) {                          // wqt[n][k] = Wq[k][n]
        int n = idx >> 9, k = idx & 511;
        wqt[idx] = bf16r(Wq[(size_t)k * 512 + n]);
    } else if (idx < 491520) {                   // pwt[n][k] = pw[n][k], pad n>=448
        int i = idx - 262144;
        int n = i / 448, k = i % 448;
        float v = (n < 448) ? kvl_pw[(size_t)n * 448 + k] : 0.f;
        pwt[i] = bf16r(v);
    } else if (idx < 753664) {                   // projt[n][k] = proj[k][n]
        int i = idx - 491520;
        int n = i >> 9, k = i & 511;
        projt[i] = bf16r(proj_w[(size_t)k * 512 + n]);
    } else if (idx < 770048) {                   // srwt[f][o] = sr_w[o*256+f]
        int i = idx - 753664;
        int f = i >> 6, o2 = i & 63;
        srwt[i] = sr_w[o2 * 256 + f];
    } else {                                     // convx: 8 elems per item
        int i = idx - 770048;                    // < 1605632
        const float4v* p = (const float4v*)(x + (size_t)i * 8);
        float4v a = p[0], b = p[1];
        uint4v u;
        u[0] = pack_bf16(a[0], a[1]);
        u[1] = pack_bf16(a[2], a[3]);
        u[2] = pack_bf16(b[0], b[1]);
        u[3] = pack_bf16(b[2], b[3]);
        *(uint4v*)(xbf + (size_t)i * 8) = u;
    }
}

// =====================================================================
// sr-conv (coalesced wT) + LayerNorm(64) + kv GEMM (64->128)
// K written as bf16 PRE-SCALED by 0.125*log2(e)
// =====================================================================
__global__ __launch_bounds__(64)
void srlnkv_kernel(const float* __restrict__ x,
                   const float* __restrict__ wT, const float* __restrict__ sr_b,
                   const float* __restrict__ ln_g, const float* __restrict__ ln_b,
                   const float* __restrict__ wkv,
                   ushort_t* __restrict__ kgb, float* __restrict__ vg) {
    const int pos = blockIdx.x;
    const int b = pos / NR_, n = pos % NR_;
    const int y = n / HS_, xx = n % HS_;
    const int o = threadIdx.x;
    __shared__ float xs[4][64];
    __shared__ float lnv_s[64];
    #pragma unroll
    for (int tap = 0; tap < 4; ++tap) {
        int ky = tap / 2, kx = tap % 2;
        xs[tap][o] = x[((size_t)b * N_ + (2 * y + ky) * Wimg + 2 * xx + kx) * DIM_ + o];
    }
    __syncthreads();
    float sum = sr_b[o];
    for (int i = 0; i < 64; ++i) {
        const float* wr = wT + (i * 4) * 64 + o;
        sum += xs[0][i] * wr[0] + xs[1][i] * wr[64] + xs[2][i] * wr[128] + xs[3][i] * wr[192];
    }
    float m = sum;
    #pragma unroll
    for (int off = 1; off < 64; off <<= 1) m += __shfl_xor(m, off);
    m *= (1.0f / 64.0f);
    float d = sum - m;
    float v = d * d;
    #pragma unroll
    for (int off = 1; off < 64; off <<= 1) v += __shfl_xor(v, off);
    v *= (1.0f / 64.0f);
    float lnv = d * rsqrtf(v + 1e-5f) * ln_g[o] + ln_b[o];
    lnv_s[o] = lnv;
    __syncthreads();
    float s0 = 0.f, s1 = 0.f;
    for (int i = 0; i < 64; ++i) {
        float lv = lnv_s[i];
        s0 += lv * wkv[i * 128 + o];
        s1 += lv * wkv[i * 128 + o + 64];
    }
    const float SCK = 0.125f * 1.44269504088896340736f;
    kgb[((size_t)b * NR_ + n) * 64 + o] = bf16r(s0 * SCK);
    vg[((size_t)b * NR_ + n) * 64 + o] = s1;
}

// =====================================================================
// FUSED: depthwise 3x3 on v_g + add + transpose+convert -> vtb bf16
// one block per (b, 64 n-positions); conv computed into LDS then
// transposed out. vg2 intermediate eliminated.
// =====================================================================
__global__ __launch_bounds__(256)
void lcgvt_kernel(const float* __restrict__ vg, const float* __restrict__ w,
                  const float* __restrict__ bias, ushort_t* __restrict__ vtb) {
    __shared__ float ld[64][65];
    const int b = blockIdx.y, n0 = blockIdx.x * 64, tid = threadIdx.x;
    #pragma unroll
    for (int i = 0; i < 16; ++i) {
        int idx = i * 256 + tid;
        int n = idx >> 6, c = idx & 63;
        int nn = n0 + n;
        int y = nn / HS_, xx = nn % HS_;
        float sum = vg[((size_t)b * NR_ + nn) * 64 + c] + bias[c];
        #pragma unroll
        for (int ky = 0; ky < 3; ++ky)
            #pragma unroll
            for (int kx = 0; kx < 3; ++kx) {
                int yy = y + ky - 1, x2 = xx + kx - 1;
                if (yy >= 0 && yy < HS_ && x2 >= 0 && x2 < HS_)
                    sum += vg[((size_t)b * NR_ + yy * HS_ + x2) * 64 + c] * w[c * 9 + ky * 3 + kx];
            }
        ld[n][c] = sum;
    }
    __syncthreads();
    #pragma unroll
    for (int i = 0; i < 16; ++i) {
        int idx = i * 256 + tid;
        int d = idx >> 6, nn = idx & 63;
        vtb[(size_t)(b * 64 + d) * NR_ + n0 + nn] = bf16r(ld[nn][d]);
    }
}

// =====================================================================
// Global-branch flash attention, split-K=8, bf16 MFMA, register-PV via
// K row-permutation pi. 512 threads / 8 waves / 128 q-rows per block.
// Two-tile batching.
// =====================================================================
__global__ __launch_bounds__(512)
void attn_global_split2(const ushort_t* __restrict__ q16,
                        const ushort_t* __restrict__ kgb,
                        const ushort_t* __restrict__ vtb,
                        ushort_t* __restrict__ osp16, float* __restrict__ mls) {
    __shared__ __align__(16) ushort_t Ks[2 * 64 * 64];
    __shared__ __align__(16) ushort_t Vs[2 * 64 * 64];
    const int split = blockIdx.y & 7;
    const int b     = blockIdx.y >> 3;
    const int q0    = blockIdx.x * 128;
    const int tid   = threadIdx.x;
    const int w     = tid >> 6;
    const int l     = tid & 63;
    const int l15   = l & 15;
    const int g     = l >> 4;
    const int lx    = l15 & 7;

    short8_t qf[2];
    {
        const ushort_t* qrow = q16 + ((size_t)b * N_ + q0 + w * 16 + l15) * DIM_;
        qf[0] = *(const short8_t*)(qrow + g * 8);
        qf[1] = *(const short8_t*)(qrow + g * 8 + 32);
    }

    float4v o[4];
    #pragma unroll
    for (int i = 0; i < 4; ++i) o[i] = (float4v){0.f, 0.f, 0.f, 0.f};
    float m_run = -3.0e38f, l_run = 0.f;   // l_run is LANE-PARTIAL (row l15)

    const int stg_r   = tid >> 3;
    const int stg_sch = (tid & 7) ^ (stg_r & 7);
    const int stg_pr  = (stg_r & 32) | (((stg_r >> 2) & 3) << 3) | (((stg_r >> 4) & 1) << 2) | (stg_r & 3);
    auto stage = [&](int t, int buf) {
        const int k0 = t * 64;
        gload16(kgb + ((size_t)(b * NR_ + k0 + stg_pr) << 6) + stg_sch * 8,
                (void*)(Ks + buf * 4096 + tid * 8));
        gload16(vtb + (size_t)(b * 64 + stg_r) * NR_ + k0 + stg_sch * 8,
                (void*)(Vs + buf * 4096 + tid * 8));
    };

    auto compute = [&](const ushort_t* Kb, const ushort_t* Vb) {
        float4v sc[4];
        #pragma unroll
        for (int c = 0; c < 4; ++c) {
            float4v acc = (float4v){0.f, 0.f, 0.f, 0.f};
            #pragma unroll
            for (int dc = 0; dc < 2; ++dc) {
                int row = c * 16 + l15;
                short8_t ak = *(const short8_t*)((const char*)Kb + row * 128 + (((g + 4 * dc) ^ lx) * 16));
                acc = __builtin_amdgcn_mfma_f32_16x16x32_bf16(ak, qf[dc], acc, 0, 0, 0);
            }
            sc[c] = acc;
        }

        float tmax = fmaxf(fmaxf(fmaxf(sc[0][0], sc[0][1]), fmaxf(sc[0][2], sc[0][3])),
                           fmaxf(fmaxf(sc[1][0], sc[1][1]), fmaxf(sc[1][2], sc[1][3])));
        tmax = fmaxf(tmax, fmaxf(fmaxf(fmaxf(sc[2][0], sc[2][1]), fmaxf(sc[2][2], sc[2][3])),
                                 fmaxf(fmaxf(sc[3][0], sc[3][1]), fmaxf(sc[3][2], sc[3][3]))));

        if (__any(tmax > m_run + 11.0f)) {
            float rmax = fmaxf(tmax, __shfl_xor(tmax, 16));
            rmax = fmaxf(rmax, __shfl_xor(rmax, 32));
            float m_new = fmaxf(m_run, rmax);
            float corr = __builtin_amdgcn_exp2f(m_run - m_new);
            float co[4];
            #pragma unroll
            for (int r = 0; r < 4; ++r) co[r] = __shfl(corr, g * 4 + r);
            #pragma unroll
            for (int dc = 0; dc < 4; ++dc)
                #pragma unroll
                for (int r = 0; r < 4; ++r) o[dc][r] *= co[r];
            l_run *= corr;
            m_run = m_new;
        }

        float p[4][4];
        float ladd = 0.f;
        #pragma unroll
        for (int c = 0; c < 4; ++c)
            #pragma unroll
            for (int r = 0; r < 4; ++r) {
                float pe = __builtin_amdgcn_exp2f(sc[c][r] - m_run);
                p[c][r] = pe;
                ladd += pe;
            }
        l_run += ladd;

        #pragma unroll
        for (int kkc = 0; kkc < 2; ++kkc) {
            uint4v au;
            au[0] = cvtpk(p[2 * kkc][0],     p[2 * kkc][1]);
            au[1] = cvtpk(p[2 * kkc][2],     p[2 * kkc][3]);
            au[2] = cvtpk(p[2 * kkc + 1][0], p[2 * kkc + 1][1]);
            au[3] = cvtpk(p[2 * kkc + 1][2], p[2 * kkc + 1][3]);
            short8_t ap = __builtin_bit_cast(short8_t, au);
            #pragma unroll
            for (int dc = 0; dc < 4; ++dc) {
                int vrow = dc * 16 + l15;
                short8_t bv = *(const short8_t*)((const char*)Vb + vrow * 128 + (((kkc * 4 + g) ^ lx) * 16));
                o[dc] = __builtin_amdgcn_mfma_f32_16x16x32_bf16(ap, bv, o[dc], 0, 0, 0);
            }
        }
    };

    const int t0 = (split * 49) / 8;
    const int t1 = ((split + 1) * 49) / 8;
    int t = t0;
    for (; t + 1 < t1; t += 2) {
        stage(t, 0);
        stage(t + 1, 1);
        __syncthreads();
        compute(Ks, Vs);
        compute(Ks + 4096, Vs + 4096);
        __syncthreads();
    }
    if (t < t1) {
        stage(t, 0);
        __syncthreads();
        compute(Ks, Vs);
    }

    float l_tot = l_run;
    l_tot += __shfl_xor(l_tot, 16);
    l_tot += __shfl_xor(l_tot, 32);

    const size_t rbase = (size_t)(split * B_ + b) * N_;
    #pragma unroll
    for (int dc = 0; dc < 4; ++dc)
        #pragma unroll
        for (int r = 0; r < 4; ++r) {
            int row = q0 + w * 16 + g * 4 + r;
            osp16[(rbase + row) * 64 + dc * 16 + l15] = bf16r(o[dc][r]);
        }
    if (l < 16) {
        int row = q0 + w * 16 + l15;
        mls[(rbase + row) * 2]     = m_run;
        mls[(rbase + row) * 2 + 1] = l_tot;
    }
}

// =====================================================================
// combine the 8 splits (exp2 domain, bf16 osp) -> catb cols [0,64)
// =====================================================================
__global__ __launch_bounds__(256)
void attn_combine(const ushort_t* __restrict__ osp16, const float* __restrict__ mls,
                  ushort_t* __restrict__ catb) {
    int idx = blockIdx.x * 256 + threadIdx.x;
    int col = idx & 63;
    size_t rn = (size_t)(idx >> 6);
    const size_t BN = (size_t)B_ * N_;
    float ms[NSPLIT], ls[NSPLIT];
    float m = -3.0e38f;
    #pragma unroll
    for (int s = 0; s < NSPLIT; ++s) {
        ms[s] = mls[(s * BN + rn) * 2];
        ls[s] = mls[(s * BN + rn) * 2 + 1];
        m = fmaxf(m, ms[s]);
    }
    float lsum = 0.f, acc = 0.f;
    #pragma unroll
    for (int s = 0; s < NSPLIT; ++s) {
        float wgt = __builtin_amdgcn_exp2f(ms[s] - m);
        lsum += ls[s] * wgt;
        acc  += bf16tof(osp16[(s * BN + rn) * 64 + col]) * wgt;
    }
    catb[rn * DIM_ + col] = bf16r(acc / lsum);
}

// =====================================================================
// depthwise 3x3 + bias on x_l (bf16 input xbf), 4ch x 4row / thread
// =====================================================================
__global__ __launch_bounds__(256)
void dwt_kernel(const ushort_t* __restrict__ xbf, const float* __restrict__ w,
                const float* __restrict__ bias, ushort_t* __restrict__ out) {
    int idx = blockIdx.x * 256 + threadIdx.x;
    int c4 = idx % 112;
    int t1 = idx / 112;
    int xx = t1 % 112;
    int t2 = t1 / 112;
    int yg = t2 % 28;
    int b  = t2 / 28;
    int c0 = c4 * 4;
    int y0 = yg * 4;

    float4v w4[9];
    #pragma unroll
    for (int kt = 0; kt < 9; ++kt) {
        w4[kt][0] = w[(c0 + 0) * 9 + kt];
        w4[kt][1] = w[(c0 + 1) * 9 + kt];
        w4[kt][2] = w[(c0 + 2) * 9 + kt];
        w4[kt][3] = w[(c0 + 3) * 9 + kt];
    }
    float4v bv = *(const float4v*)(bias + c0);
    float4v acc[4];
    #pragma unroll
    for (int o2 = 0; o2 < 4; ++o2) acc[o2] = bv;

    #pragma unroll
    for (int yy = 0; yy < 6; ++yy) {
        int Y = y0 - 1 + yy;
        if (Y < 0 || Y >= Himg) continue;
        #pragma unroll
        for (int xt = 0; xt < 3; ++xt) {
            int X = xx - 1 + xt;
            if (X < 0 || X >= Wimg) continue;
            uint2v q2 = *(const uint2v*)(xbf + ((size_t)b * N_ + Y * Wimg + X) * DIM_ + D0_ + c0);
            float4v v;
            v[0] = bf16tof((ushort_t)(q2[0] & 0xffffu));
            v[1] = bf16tof((ushort_t)(q2[0] >> 16));
            v[2] = bf16tof((ushort_t)(q2[1] & 0xffffu));
            v[3] = bf16tof((ushort_t)(q2[1] >> 16));
            constexpr int olo_t[6] = {0, 0, 0, 1, 2, 3};
            constexpr int ohi_t[6] = {0, 1, 2, 3, 3, 3};
            #pragma unroll
            for (int o2 = olo_t[yy]; o2 <= ohi_t[yy]; ++o2) {
                float4v wv = w4[(yy - o2) * 3 + xt];
                acc[o2][0] += v[0] * wv[0];
                acc[o2][1] += v[1] * wv[1];
                acc[o2][2] += v[2] * wv[2];
                acc[o2][3] += v[3] * wv[3];
            }
        }
    }
    #pragma unroll
    for (int o2 = 0; o2 < 4; ++o2) {
        uint2v pk;
        pk[0] = pack_bf16(acc[o2][0], acc[o2][1]);
        pk[1] = pack_bf16(acc[o2][2], acc[o2][3]);
        *(uint2v*)(out + ((size_t)b * N_ + (y0 + o2) * Wimg + xx) * DL_ + c0) = pk;
    }
}

// =====================================================================
// "scrambled mean" body (bf16 kvl), called from the merged kernel
// =====================================================================
template<int L, int NBW, int STRIDE, int DIL, int CHOFF>
__device__ inline void lm_body(const ushort_t* __restrict__ kvl16,
                               float* __restrict__ kvm) {
    __shared__ float slo[L], shi[L];
    const int blk = blockIdx.x;
    const int n = blk % 49;
    const int h = (blk / 49) % NH_;
    const int b = blk / (49 * NH_);
    const int wy = n / 7, wx = n % 7;
    const int t = threadIdx.x;

    if (t < L) {
        const int by = t / NBW, bx = t % NBW;
        int Y = by * STRIDE + DIL * wy;
        int X = bx * STRIDE + DIL * wx;
        if (Y >= Himg) Y = 2 * Himg - 2 - Y;
        if (X >= Wimg) X = 2 * Wimg - 2 - X;
        const ushort_t* src = kvl16 + ((size_t)b * N_ + Y * Wimg + X) * DL_ + CHOFF + h * HD_;
        float v[28];
        #pragma unroll
        for (int i = 0; i < 7; ++i) {
            uint2v q2 = ((const uint2v*)src)[i];
            v[i * 4]     = bf16tof((ushort_t)(q2[0] & 0xffffu));
            v[i * 4 + 1] = bf16tof((ushort_t)(q2[0] >> 16));
            v[i * 4 + 2] = bf16tof((ushort_t)(q2[1] & 0xffffu));
            v[i * 4 + 3] = bf16tof((ushort_t)(q2[1] >> 16));
        }
        const int f0 = t * HD_;
        const int bin0 = f0 / L;
        const int nlo = min(HD_, (bin0 + 1) * L - f0);
        float s0 = 0.f, s1 = 0.f;
        #pragma unroll
        for (int j = 0; j < HD_; ++j) {
            if (j < nlo) s0 += v[j]; else s1 += v[j];
        }
        slo[t] = s0;
        shi[t] = s1;
    }
    __syncthreads();
    if (t < HD_) {
        const int t_lo = (t * L) / HD_;
        const int t_hi = min(L - 1, (t * L + L - 1) / HD_);
        float sum = 0.f;
        for (int u = t_lo; u <= t_hi; ++u) {
            int f0 = u * HD_;
            int b0 = f0 / L;
            int b1 = (f0 + HD_ - 1) / L;
            if (b0 == t) sum += slo[u];
            if (b1 == t && b1 != b0) sum += shi[u];
        }
        kvm[(size_t)blk * HD_ + t] = sum * (1.0f / (float)L);
    }
}

__global__ __launch_bounds__(256)
void lm_merged_kernel(const ushort_t* __restrict__ kvl16,
                      float* __restrict__ kvm1, float* __restrict__ kvm2) {
    if (blockIdx.y == 0) lm_body<256, 16, 7, 1, 0>(kvl16, kvm1);
    else                 lm_body<81, 9, 13, 2, 224>(kvl16, kvm2);
}

// =====================================================================
// merged fc@sh for both branches: grid 32, bh2<16 -> branch1
// =====================================================================
__global__ __launch_bounds__(64)
void fcsh_merged_kernel(const float* __restrict__ kvm1, const float* __restrict__ fc1w,
                        const float* __restrict__ sh1w, float* __restrict__ kv1,
                        const float* __restrict__ kvm2, const float* __restrict__ fc2w,
                        const float* __restrict__ sh2w, float* __restrict__ kv2) {
    int bh2 = blockIdx.x;
    const float* kvm = (bh2 < 16) ? kvm1 : kvm2;
    const float* fcw = (bh2 < 16) ? fc1w : fc2w;
    const float* shw = (bh2 < 16) ? sh1w : sh2w;
    float* outp      = (bh2 < 16) ? kv1 : kv2;
    int bh = (bh2 < 16) ? bh2 : bh2 - 16;
    __shared__ float kin[49][28];
    __shared__ float tmp[49][28];
    __shared__ float fw[28 * 28];
    __shared__ float sw[28 * 56];
    int t = threadIdx.x;
    for (int i = t; i < 49 * 28; i += 64) kin[i / 28][i % 28] = kvm[bh * 49 * 28 + i];
    for (int i = t; i < 28 * 28; i += 64) fw[i] = fcw[i];
    for (int i = t; i < 28 * 56; i += 64) sw[i] = shw[i];
    __syncthreads();
    for (int i = t; i < 49 * 28; i += 64) {
        int rr = i / 28, j = i % 28;
        float s = 0.f;
        for (int k = 0; k < 28; ++k) s += kin[rr][k] * fw[k * 28 + j];
        tmp[rr][j] = s;
    }
    __syncthreads();
    for (int i = t; i < 49 * 56; i += 64) {
        int rr = i / 56, j = i % 56;
        float s = 0.f;
        for (int k = 0; k < 28; ++k) s += tmp[rr][k] * sw[k * 56 + j];
        outp[bh * 49 * 56 + i] = s;
    }
}

// =====================================================================
// merged v-conv for both branches: grid (86, 2)
// =====================================================================
__global__ __launch_bounds__(256)
void vconv_merged_kernel(const float* __restrict__ kv1, const float* __restrict__ lc1w,
                         const float* __restrict__ lc1b, float* __restrict__ v1c,
                         const float* __restrict__ kv2, const float* __restrict__ lc2w,
                         const float* __restrict__ lc2b, float* __restrict__ v2c) {
    const float* kvsh = (blockIdx.y == 0) ? kv1 : kv2;
    const float* w    = (blockIdx.y == 0) ? lc1w : lc2w;
    const float* bias = (blockIdx.y == 0) ? lc1b : lc2b;
    float* vc         = (blockIdx.y == 0) ? v1c : v2c;
    int idx = blockIdx.x * 256 + threadIdx.x;
    if (idx >= B_ * NH_ * 49 * HD_) return;
    int d  = idx % HD_;
    int n  = (idx / HD_) % 49;
    int bh = idx / (HD_ * 49);
    int h  = bh % NH_;
    int y = n / 7, xx = n % 7;
    int c = h * HD_ + d;
    float sum = kvsh[(bh * 49 + n) * 56 + 28 + d] + bias[c];
    #pragma unroll
    for (int ky = 0; ky < 3; ++ky)
        #pragma unroll
        for (int kx = 0; kx < 3; ++kx) {
            int yy = y + ky - 1, x2 = xx + kx - 1;
            if (yy >= 0 && yy < 7 && x2 >= 0 && x2 < 7)
                sum += kvsh[(bh * 49 + yy * 7 + x2) * 56 + 28 + d] * w[c * 9 + ky * 3 + kx];
        }
    vc[idx] = sum;
}

// =====================================================================
// Local attention via MFMA, both branches fused.
// =====================================================================
__global__ __launch_bounds__(256)
void attn_local_mfma(const ushort_t* __restrict__ q16,
                     const float* __restrict__ kv1, const float* __restrict__ v1c,
                     const float* __restrict__ kv2, const float* __restrict__ v2c,
                     ushort_t* __restrict__ catb) {
    __shared__ __align__(16) ushort_t Ks[64 * 32];   // [pi-row][d pad32]
    __shared__ __align__(16) ushort_t Vt[32 * 64];   // [d pad32][kcol pad64]
    const int ybh    = blockIdx.y;          // 0..31
    const int branch = ybh & 1;
    const int bh     = ybh >> 1;            // b*NH + h
    const int b      = bh >> 3, h = bh & 7;
    const int q0     = blockIdx.x * 64;
    const int tid    = threadIdx.x;
    const int w      = tid >> 6;
    const int l      = tid & 63;
    const int l15    = l & 15;
    const int g      = l >> 4;
    const float SC2K = 0.1889822365046136f * 1.44269504088896340736f; // 28^-.5 * log2e

    const float* kvsh = branch ? kv2 : kv1;
    const float* vc   = branch ? v2c : v1c;
    const int qoff    = D0_ + h * 56 + branch * 28;
    const int outoff  = (branch ? D0_ + 224 : D0_) + h * HD_;

    // ---- stage K (pre-scaled): LDS row r <- kcol pi(r), d padded to 32 ----
    {
        int row = tid >> 2, lc = tid & 3;
        int pr = (row & 32) | (((row >> 2) & 3) << 3) | (((row >> 4) & 1) << 2) | (row & 3);
        uint4v u = (uint4v){0u, 0u, 0u, 0u};
        if (pr < 49) {
            const float* src = kvsh + (bh * 49 + pr) * 56 + lc * 8;
            float vv[8];
            #pragma unroll
            for (int j2 = 0; j2 < 8; ++j2)
                vv[j2] = (lc * 8 + j2 < 28) ? src[j2] * SC2K : 0.f;
            u[0] = cvtpk(vv[0], vv[1]);
            u[1] = cvtpk(vv[2], vv[3]);
            u[2] = cvtpk(vv[4], vv[5]);
            u[3] = cvtpk(vv[6], vv[7]);
        }
        *(uint4v*)(Ks + row * 32 + (lc ^ (row & 3)) * 8) = u;
    }
    // ---- stage Vt[d][kcol] ----
    {
        int row = tid >> 3, lc = tid & 7;
        uint4v u = (uint4v){0u, 0u, 0u, 0u};
        if (row < 28) {
            float vv[8];
            #pragma unroll
            for (int j2 = 0; j2 < 8; ++j2) {
                int kc = lc * 8 + j2;
                vv[j2] = (kc < 49) ? vc[(bh * 49 + kc) * 28 + row] : 0.f;
            }
            u[0] = cvtpk(vv[0], vv[1]);
            u[1] = cvtpk(vv[2], vv[3]);
            u[2] = cvtpk(vv[4], vv[5]);
            u[3] = cvtpk(vv[6], vv[7]);
        }
        *(uint4v*)(Vt + row * 64 + (lc ^ (row & 7)) * 8) = u;
    }
    // ---- Q fragment: raw bf16 (8B loads; g==3 upper half zero) ----
    short8_t qf;
    {
        const ushort_t* qp = q16 + ((size_t)b * N_ + q0 + w * 16 + l15) * DIM_ + qoff + g * 8;
        uint2v a01 = *(const uint2v*)qp;
        uint2v a23 = (g < 3) ? *(const uint2v*)(qp + 4) : (uint2v){0u, 0u};
        uint4v uv;
        uv[0] = a01[0]; uv[1] = a01[1]; uv[2] = a23[0]; uv[3] = a23[1];
        qf = __builtin_bit_cast(short8_t, uv);
    }
    __syncthreads();

    // ---- scores ----
    float4v sc4[4];
    #pragma unroll
    for (int c = 0; c < 4; ++c) {
        int row = c * 16 + l15;
        short8_t ak = *(const short8_t*)(Ks + row * 32 + ((g ^ (row & 3)) * 8));
        float4v acc = (float4v){0.f, 0.f, 0.f, 0.f};
        sc4[c] = __builtin_amdgcn_mfma_f32_16x16x32_bf16(ak, qf, acc, 0, 0, 0);
    }

    // ---- softmax over 49 keys ----
    float tmax = fmaxf(fmaxf(fmaxf(sc4[0][0], sc4[0][1]), fmaxf(sc4[0][2], sc4[0][3])),
                       fmaxf(fmaxf(sc4[1][0], sc4[1][1]), fmaxf(sc4[1][2], sc4[1][3])));
    tmax = fmaxf(tmax, fmaxf(fmaxf(fmaxf(sc4[2][0], sc4[2][1]), fmaxf(sc4[2][2], sc4[2][3])),
                             fmaxf(fmaxf(sc4[3][0], sc4[3][1]), fmaxf(sc4[3][2], sc4[3][3]))));
    tmax = fmaxf(tmax, __shfl_xor(tmax, 16));
    tmax = fmaxf(tmax, __shfl_xor(tmax, 32));

    float p[4][4];
    float lsum = 0.f;
    #pragma unroll
    for (int c = 0; c < 4; ++c)
        #pragma unroll
        for (int r = 0; r < 4; ++r) {
            float pe = __builtin_amdgcn_exp2f(sc4[c][r] - tmax);
            if (c >= 2 && (8 * g + 4 * (c & 1) + r) >= 17) pe = 0.f;
            p[c][r] = pe;
            lsum += pe;
        }
    lsum += __shfl_xor(lsum, 16);
    lsum += __shfl_xor(lsum, 32);
    float inv = 1.0f / lsum;

    // ---- PV ----
    float4v o2[2];
    o2[0] = (float4v){0.f, 0.f, 0.f, 0.f};
    o2[1] = (float4v){0.f, 0.f, 0.f, 0.f};
    #pragma unroll
    for (int kkc = 0; kkc < 2; ++kkc) {
        uint4v au;
        au[0] = cvtpk(p[2 * kkc][0],     p[2 * kkc][1]);
        au[1] = cvtpk(p[2 * kkc][2],     p[2 * kkc][3]);
        au[2] = cvtpk(p[2 * kkc + 1][0], p[2 * kkc + 1][1]);
        au[3] = cvtpk(p[2 * kkc + 1][2], p[2 * kkc + 1][3]);
        short8_t ap = __builtin_bit_cast(short8_t, au);
        #pragma unroll
        for (int dc = 0; dc < 2; ++dc) {
            int vrow = dc * 16 + l15;
            short8_t bv = *(const short8_t*)(Vt + vrow * 64 + (((kkc * 4 + g) ^ (vrow & 7)) * 8));
            o2[dc] = __builtin_amdgcn_mfma_f32_16x16x32_bf16(ap, bv, o2[dc], 0, 0, 0);
        }
    }

    // ---- normalize + store (d < 28) ----
    float irow[4];
    #pragma unroll
    for (int r = 0; r < 4; ++r) irow[r] = __shfl(inv, g * 4 + r);
    #pragma unroll
    for (int dc = 0; dc < 2; ++dc) {
        int d = dc * 16 + l15;
        if (d < 28) {
            #pragma unroll
            for (int r = 0; r < 4; ++r) {
                int row = q0 + w * 16 + g * 4 + r;
                catb[((size_t)b * N_ + row) * DIM_ + outoff + d] = bf16r(o2[dc][r] * irow[r]);
            }
        }
    }
}

// =====================================================================
extern "C" void kernel_launch(void* const* d_in, const int* in_sizes, int n_in,
                              void* d_out, int out_size, void* d_ws, size_t ws_size,
                              hipStream_t stream) {
    const float* x      = (const float*)d_in[0];
    const float* Wq     = (const float*)d_in[1];
    const float* Wkv_g  = (const float*)d_in[2];
    const float* sr_w   = (const float*)d_in[3];
    const float* sr_b   = (const float*)d_in[4];
    const float* ln_g   = (const float*)d_in[5];
    const float* ln_b   = (const float*)d_in[6];
    const float* lcg_w  = (const float*)d_in[7];
    const float* lcg_b  = (const float*)d_in[8];
    const float* kvl_dw = (const float*)d_in[9];
    const float* kvl_db = (const float*)d_in[10];
    const float* kvl_pw = (const float*)d_in[11];
    const float* kvl_pb = (const float*)d_in[12];
    const float* fc1_w  = (const float*)d_in[13];
    const float* sh1_w  = (const float*)d_in[14];
    const float* lc1_w  = (const float*)d_in[15];
    const float* lc1_b  = (const float*)d_in[16];
    const float* fc2_w  = (const float*)d_in[17];
    const float* sh2_w  = (const float*)d_in[18];
    const float* lc2_w  = (const float*)d_in[19];
    const float* lc2_b  = (const float*)d_in[20];
    const float* proj_w = (const float*)d_in[21];
    const float* proj_b = (const float*)d_in[22];
    float* out = (float*)d_out;
    char* base = (char*)d_ws;

    // ---- workspace layout (256B aligned) ----
    size_t o = 0;
    auto alloc = [&](size_t bytes) -> void* {
        void* p = base + o;
        o = (o + bytes + 255) & ~(size_t)255;
        return p;
    };
    const size_t kvl16_bytes = (size_t)B_ * N_ * DL_ * 2;
    const size_t ospml_bytes = (size_t)NSPLIT * B_ * N_ * 64 * 2 + (size_t)NSPLIT * B_ * N_ * 2 * 4;
    const size_t shared_bytes = kvl16_bytes > ospml_bytes ? kvl16_bytes : ospml_bytes;
    ushort_t* q16   = (ushort_t*)alloc((size_t)B_ * N_ * DIM_ * 2);
    char*     shreg = (char*)    alloc(shared_bytes);
    ushort_t* xcat  = (ushort_t*)alloc((size_t)B_ * N_ * DIM_ * 2);  // xbf, then cat
    ushort_t* dwtb  = (ushort_t*)alloc((size_t)B_ * N_ * DL_ * 2);
    ushort_t* kgb   = (ushort_t*)alloc((size_t)B_ * NR_ * 64 * 2);
    float*    vg    = (float*)   alloc((size_t)B_ * NR_ * 64 * 4);
    ushort_t* vtb   = (ushort_t*)alloc((size_t)B_ * 64 * NR_ * 2);
    ushort_t* wqt   = (ushort_t*)alloc((size_t)512 * 512 * 2);
    ushort_t* pwt   = (ushort_t*)alloc((size_t)512 * 448 * 2);
    ushort_t* projt = (ushort_t*)alloc((size_t)512 * 512 * 2);
    float*    srwt  = (float*)   alloc((size_t)256 * 64 * 4);
    float*    kvm1  = (float*)   alloc((size_t)B_ * NH_ * 49 * HD_ * 4);
    float*    kvm2  = (float*)   alloc((size_t)B_ * NH_ * 49 * HD_ * 4);
    float*    kv1   = (float*)   alloc((size_t)B_ * NH_ * 49 * 56 * 4);
    float*    kv2   = (float*)   alloc((size_t)B_ * NH_ * 49 * 56 * 4);
    float*    v1c   = (float*)   alloc((size_t)B_ * NH_ * 49 * HD_ * 4);
    float*    v2c   = (float*)   alloc((size_t)B_ * NH_ * 49 * HD_ * 4);
    ushort_t* xbf   = xcat;
    ushort_t* catb  = xcat;
    ushort_t* kvl16 = (ushort_t*)shreg;
    ushort_t* osp16 = (ushort_t*)shreg;
    float*    mls   = (float*)(shreg + (size_t)NSPLIT * B_ * N_ * 64 * 2);

    const int M = B_ * N_;   // 25088

    // 0. merged prep: 3 weight converts + sr_w transpose + x->bf16
    prep_kernel<<<9280, 256, 0, stream>>>(Wq, kvl_pw, proj_w, sr_w, x,
                                          wqt, pwt, projt, srwt, xbf);

    // 1. q16 = bf16(x @ Wq)
    gemm_bf16_kernel<false, true><<<dim3(M / 128, 4), 256, 0, stream>>>(
        xbf, wqt, nullptr, q16, 512, 512, 512);

    // 2. depthwise on x_l (bf16 input) -> dwtb (bf16)
    dwt_kernel<<<(B_ * 28 * 112 * 112) / 256, 256, 0, stream>>>(xbf, kvl_dw, kvl_db, dwtb);

    // 3. pointwise: kvl16 = bf16(dwtb @ pwt^T + pb)
    gemm_bf16_kernel<true, true><<<dim3(M / 128, 4), 256, 0, stream>>>(
        dwtb, pwt, kvl_pb, kvl16, 448, 448, 448);

    // 4. global branch: sr conv + LN + kv (K bf16, pre-scaled exp2 domain)
    srlnkv_kernel<<<B_ * NR_, 64, 0, stream>>>(x, srwt, sr_b, ln_g, ln_b, Wkv_g, kgb, vg);

    // 5. fused lcg + transpose+convert -> vtb
    lcgvt_kernel<<<dim3(NR_ / 64, B_), 256, 0, stream>>>(vg, lcg_w, lcg_b, vtb);

    // 7-9. local branch pipeline (merged; consumes kvl16 BEFORE osp16 aliases)
    lm_merged_kernel<<<dim3(B_ * NH_ * 49, 2), 256, 0, stream>>>(kvl16, kvm1, kvm2);
    fcsh_merged_kernel<<<32, 64, 0, stream>>>(kvm1, fc1_w, sh1_w, kv1,
                                              kvm2, fc2_w, sh2_w, kv2);
    {
        int blocks = (B_ * NH_ * 49 * HD_ + 255) / 256;
        vconv_merged_kernel<<<dim3(blocks, 2), 256, 0, stream>>>(
            kv1, lc1_w, lc1_b, v1c, kv2, lc2_w, lc2_b, v2c);
    }

    // 6. global flash attention, split-K=8 (register-PV, 512-thread blocks)
    attn_global_split2<<<dim3(N_ / 128, B_ * NSPLIT), 512, 0, stream>>>(q16, kgb, vtb, osp16, mls);
    attn_combine<<<(B_ * N_ * 64) / 256, 256, 0, stream>>>(osp16, mls, catb);

    // 10. local attention (MFMA, both branches) -> catb cols [64,512)
    attn_local_mfma<<<dim3(N_ / 64, B_ * NH_ * 2), 256, 0, stream>>>(
        q16, kv1, v1c, kv2, v2c, catb);

    // 11. out = catb @ projt^T + proj_b
    gemm_bf16_kernel<true, false><<<dim3(M / 128, 4), 256, 0, stream>>>(
        catb, projt, proj_b, out, 512, 512, 512);
}

// Round 21
// 265.308 us; speedup vs baseline: 1.1754x; 1.0966x over previous
//
#include <hip/hip_runtime.h>
#include <hip/hip_bf16.h>
#include <math.h>
#include <stdint.h>

// ---- problem constants ----
static constexpr int B_    = 2;
static constexpr int N_    = 12544;   // 112*112
static constexpr int DIM_  = 512;
static constexpr int D0_   = 64;
static constexpr int DL_   = 448;
static constexpr int Himg  = 112;
static constexpr int Wimg  = 112;
static constexpr int HS_   = 56;
static constexpr int NR_   = 3136;    // 56*56
static constexpr int NH_   = 8;
static constexpr int HD_   = 28;
static constexpr int NSPLIT = 8;

typedef unsigned short ushort_t;
typedef __attribute__((ext_vector_type(8))) short short8_t;
typedef __attribute__((ext_vector_type(4))) float float4v;
typedef __attribute__((ext_vector_type(4))) unsigned uint4v;
typedef __attribute__((ext_vector_type(2))) unsigned uint2v;

static __device__ inline ushort_t bf16r(float x) {
    unsigned u = __builtin_bit_cast(unsigned, x);
    u = (u + 0x7FFFu + ((u >> 16) & 1u)) >> 16;
    return (ushort_t)u;
}
static __device__ inline float bf16tof(ushort_t h) {
    unsigned u = ((unsigned)h) << 16;
    return __builtin_bit_cast(float, u);
}
static __device__ inline unsigned pack_bf16(float lo, float hi) {
    unsigned a = __builtin_bit_cast(unsigned, lo);
    unsigned b = __builtin_bit_cast(unsigned, hi);
    a = (a + 0x7FFFu + ((a >> 16) & 1u)) >> 16;
    b = (b + 0x7FFFu + ((b >> 16) & 1u)) >> 16;
    return a | (b << 16);
}
static __device__ inline unsigned cvtpk(float lo, float hi) {
    float2 f2; f2.x = lo; f2.y = hi;
    __hip_bfloat162 h = __float22bfloat162_rn(f2);
    unsigned u;
    __builtin_memcpy(&u, &h, 4);
    return u;
}

using gptr_t = const __attribute__((address_space(1))) void*;
using lptr_t = __attribute__((address_space(3))) void*;
static __device__ inline void gload16(const void* g, void* l) {
    __builtin_amdgcn_global_load_lds((gptr_t)(uintptr_t)g, (lptr_t)(uintptr_t)l, 16, 0, 0);
}

// =====================================================================
// bf16 MFMA GEMM (standalone, used for proj only)
// =====================================================================
template<bool HASBIAS, bool OUT16>
__global__ __launch_bounds__(256, 2)
void gemm_bf16_kernel(const ushort_t* __restrict__ A,
                      const ushort_t* __restrict__ Bt,
                      const float* __restrict__ bias,
                      void* __restrict__ Cv,
                      int Nn, int K, int ldc) {
    constexpr int BM = 128, BK = 64;
    __shared__ __align__(16) ushort_t As[BM * BK];
    __shared__ __align__(16) ushort_t Bs[BM * BK];
    const int bm = blockIdx.x * BM;
    const int bn = blockIdx.y * BM;
    const int tid = threadIdx.x;
    const int l15 = tid & 15;
    const int g   = (tid & 63) >> 4;
    const int w   = tid >> 6;
    const int wr  = w >> 1, wc = w & 1;

    float4v acc[4][4];
    #pragma unroll
    for (int m = 0; m < 4; ++m)
        #pragma unroll
        for (int n = 0; n < 4; ++n) acc[m][n] = (float4v){0.f, 0.f, 0.f, 0.f};

    for (int k0 = 0; k0 < K; k0 += BK) {
        #pragma unroll
        for (int i = 0; i < 4; ++i) {
            int c = i * 256 + tid;
            int r = c >> 3, ch = c & 7;
            int sch = ch ^ (r & 7);
            gload16(A  + (size_t)(bm + r) * K + k0 + sch * 8, (void*)(As + c * 8));
            gload16(Bt + (size_t)(bn + r) * K + k0 + sch * 8, (void*)(Bs + c * 8));
        }
        __syncthreads();

        short8_t af[4][2], bfr[4][2];
        #pragma unroll
        for (int m = 0; m < 4; ++m) {
            int ar = wr * 64 + m * 16 + l15;
            #pragma unroll
            for (int h = 0; h < 2; ++h)
                af[m][h] = *(const short8_t*)((const char*)As + ar * 128 + (((h * 4 + g) ^ (ar & 7)) * 16));
        }
        #pragma unroll
        for (int n = 0; n < 4; ++n) {
            int br = wc * 64 + n * 16 + l15;
            #pragma unroll
            for (int h = 0; h < 2; ++h)
                bfr[n][h] = *(const short8_t*)((const char*)Bs + br * 128 + (((h * 4 + g) ^ (br & 7)) * 16));
        }
        #pragma unroll
        for (int m = 0; m < 4; ++m)
            #pragma unroll
            for (int n = 0; n < 4; ++n) {
                acc[m][n] = __builtin_amdgcn_mfma_f32_16x16x32_bf16(af[m][0], bfr[n][0], acc[m][n], 0, 0, 0);
                acc[m][n] = __builtin_amdgcn_mfma_f32_16x16x32_bf16(af[m][1], bfr[n][1], acc[m][n], 0, 0, 0);
            }
        __syncthreads();
    }

    #pragma unroll
    for (int n = 0; n < 4; ++n) {
        int ccol = bn + wc * 64 + n * 16 + l15;
        if (ccol < Nn) {
            float bv = HASBIAS ? bias[ccol] : 0.f;
            #pragma unroll
            for (int m = 0; m < 4; ++m) {
                int crow = bm + wr * 64 + m * 16 + g * 4;
                #pragma unroll
                for (int j = 0; j < 4; ++j) {
                    float v = acc[m][n][j] + bv;
                    if (OUT16)
                        ((ushort_t*)Cv)[(size_t)(crow + j) * ldc + ccol] = bf16r(v);
                    else
                        ((float*)Cv)[(size_t)(crow + j) * ldc + ccol] = v;
                }
            }
        }
    }
}

// =====================================================================
// merged prep: wqt, pwt, projt, srwt, xbf
// =====================================================================
__global__ __launch_bounds__(256)
void prep_kernel(const float* __restrict__ Wq, const float* __restrict__ kvl_pw,
                 const float* __restrict__ proj_w, const float* __restrict__ sr_w,
                 const float* __restrict__ x,
                 ushort_t* __restrict__ wqt, ushort_t* __restrict__ pwt,
                 ushort_t* __restrict__ projt, float* __restrict__ srwt,
                 ushort_t* __restrict__ xbf) {
    int idx = blockIdx.x * 256 + threadIdx.x;
    if (idx < 262144) {
        int n = idx >> 9, k = idx & 511;
        wqt[idx] = bf16r(Wq[(size_t)k * 512 + n]);
    } else if (idx < 491520) {
        int i = idx - 262144;
        int n = i / 448, k = i % 448;
        float v = (n < 448) ? kvl_pw[(size_t)n * 448 + k] : 0.f;
        pwt[i] = bf16r(v);
    } else if (idx < 753664) {
        int i = idx - 491520;
        int n = i >> 9, k = i & 511;
        projt[i] = bf16r(proj_w[(size_t)k * 512 + n]);
    } else if (idx < 770048) {
        int i = idx - 753664;
        int f = i >> 6, o2 = i & 63;
        srwt[i] = sr_w[o2 * 256 + f];
    } else {
        int i = idx - 770048;
        const float4v* p = (const float4v*)(x + (size_t)i * 8);
        float4v a = p[0], b = p[1];
        uint4v u;
        u[0] = pack_bf16(a[0], a[1]);
        u[1] = pack_bf16(a[2], a[3]);
        u[2] = pack_bf16(b[0], b[1]);
        u[3] = pack_bf16(b[2], b[3]);
        *(uint4v*)(xbf + (size_t)i * 8) = u;
    }
}

// =====================================================================
// FUSED3: [0,784) q-GEMM | [784,3528) dwt | [3528,5096) srlnkv x4
// =====================================================================
__global__ __launch_bounds__(256, 2)
void fused3_kernel(const ushort_t* __restrict__ xbf, const ushort_t* __restrict__ wqt,
                   ushort_t* __restrict__ q16,
                   const float* __restrict__ kvl_dw, const float* __restrict__ kvl_db,
                   ushort_t* __restrict__ dwtb,
                   const float* __restrict__ x, const float* __restrict__ srwt,
                   const float* __restrict__ sr_b, const float* __restrict__ ln_g,
                   const float* __restrict__ ln_b, const float* __restrict__ wkv,
                   ushort_t* __restrict__ kgb, float* __restrict__ vg) {
    const int bid = blockIdx.x;
    const int tid = threadIdx.x;
    __shared__ __align__(16) ushort_t As[128 * 64];
    __shared__ __align__(16) ushort_t Bs[128 * 64];
    __shared__ float xs[4][4][64];
    __shared__ float lnv_s[4][64];

    if (bid < 784) {
        const int bm = (bid % 196) * 128;
        const int bn = (bid / 196) * 128;
        const int l15 = tid & 15;
        const int g   = (tid & 63) >> 4;
        const int w   = tid >> 6;
        const int wr  = w >> 1, wc = w & 1;
        float4v acc[4][4];
        #pragma unroll
        for (int m = 0; m < 4; ++m)
            #pragma unroll
            for (int n = 0; n < 4; ++n) acc[m][n] = (float4v){0.f, 0.f, 0.f, 0.f};
        for (int k0 = 0; k0 < 512; k0 += 64) {
            #pragma unroll
            for (int i = 0; i < 4; ++i) {
                int c = i * 256 + tid;
                int r = c >> 3, ch = c & 7;
                int sch = ch ^ (r & 7);
                gload16(xbf + (size_t)(bm + r) * 512 + k0 + sch * 8, (void*)(As + c * 8));
                gload16(wqt + (size_t)(bn + r) * 512 + k0 + sch * 8, (void*)(Bs + c * 8));
            }
            __syncthreads();
            short8_t af[4][2], bfr[4][2];
            #pragma unroll
            for (int m = 0; m < 4; ++m) {
                int ar = wr * 64 + m * 16 + l15;
                #pragma unroll
                for (int h = 0; h < 2; ++h)
                    af[m][h] = *(const short8_t*)((const char*)As + ar * 128 + (((h * 4 + g) ^ (ar & 7)) * 16));
            }
            #pragma unroll
            for (int n = 0; n < 4; ++n) {
                int br = wc * 64 + n * 16 + l15;
                #pragma unroll
                for (int h = 0; h < 2; ++h)
                    bfr[n][h] = *(const short8_t*)((const char*)Bs + br * 128 + (((h * 4 + g) ^ (br & 7)) * 16));
            }
            #pragma unroll
            for (int m = 0; m < 4; ++m)
                #pragma unroll
                for (int n = 0; n < 4; ++n) {
                    acc[m][n] = __builtin_amdgcn_mfma_f32_16x16x32_bf16(af[m][0], bfr[n][0], acc[m][n], 0, 0, 0);
                    acc[m][n] = __builtin_amdgcn_mfma_f32_16x16x32_bf16(af[m][1], bfr[n][1], acc[m][n], 0, 0, 0);
                }
            __syncthreads();
        }
        #pragma unroll
        for (int n = 0; n < 4; ++n) {
            int ccol = bn + wc * 64 + n * 16 + l15;
            #pragma unroll
            for (int m = 0; m < 4; ++m) {
                int crow = bm + wr * 64 + m * 16 + g * 4;
                #pragma unroll
                for (int j = 0; j < 4; ++j)
                    q16[(size_t)(crow + j) * 512 + ccol] = bf16r(acc[m][n][j]);
            }
        }
    } else if (bid < 3528) {
        int idx = (bid - 784) * 256 + tid;
        int c4 = idx % 112;
        int t1 = idx / 112;
        int xx = t1 % 112;
        int t2 = t1 / 112;
        int yg = t2 % 28;
        int b  = t2 / 28;
        int c0 = c4 * 4;
        int y0 = yg * 4;
        float4v w4[9];
        #pragma unroll
        for (int kt = 0; kt < 9; ++kt) {
            w4[kt][0] = kvl_dw[(c0 + 0) * 9 + kt];
            w4[kt][1] = kvl_dw[(c0 + 1) * 9 + kt];
            w4[kt][2] = kvl_dw[(c0 + 2) * 9 + kt];
            w4[kt][3] = kvl_dw[(c0 + 3) * 9 + kt];
        }
        float4v bv = *(const float4v*)(kvl_db + c0);
        float4v acc[4];
        #pragma unroll
        for (int o2 = 0; o2 < 4; ++o2) acc[o2] = bv;
        #pragma unroll
        for (int yy = 0; yy < 6; ++yy) {
            int Y = y0 - 1 + yy;
            if (Y < 0 || Y >= Himg) continue;
            #pragma unroll
            for (int xt = 0; xt < 3; ++xt) {
                int X = xx - 1 + xt;
                if (X < 0 || X >= Wimg) continue;
                uint2v q2 = *(const uint2v*)(xbf + ((size_t)b * N_ + Y * Wimg + X) * DIM_ + D0_ + c0);
                float4v v;
                v[0] = bf16tof((ushort_t)(q2[0] & 0xffffu));
                v[1] = bf16tof((ushort_t)(q2[0] >> 16));
                v[2] = bf16tof((ushort_t)(q2[1] & 0xffffu));
                v[3] = bf16tof((ushort_t)(q2[1] >> 16));
                constexpr int olo_t[6] = {0, 0, 0, 1, 2, 3};
                constexpr int ohi_t[6] = {0, 1, 2, 3, 3, 3};
                #pragma unroll
                for (int o2 = olo_t[yy]; o2 <= ohi_t[yy]; ++o2) {
                    float4v wv = w4[(yy - o2) * 3 + xt];
                    acc[o2][0] += v[0] * wv[0];
                    acc[o2][1] += v[1] * wv[1];
                    acc[o2][2] += v[2] * wv[2];
                    acc[o2][3] += v[3] * wv[3];
                }
            }
        }
        #pragma unroll
        for (int o2 = 0; o2 < 4; ++o2) {
            uint2v pk;
            pk[0] = pack_bf16(acc[o2][0], acc[o2][1]);
            pk[1] = pack_bf16(acc[o2][2], acc[o2][3]);
            *(uint2v*)(dwtb + ((size_t)b * N_ + (y0 + o2) * Wimg + xx) * DL_ + c0) = pk;
        }
    } else {
        const int blk4 = bid - 3528;
        const int grp  = tid >> 6;
        const int o    = tid & 63;
        const int pos  = blk4 * 4 + grp;
        const int b = pos / NR_, n = pos % NR_;
        const int y = n / HS_, xx = n % HS_;
        #pragma unroll
        for (int tap = 0; tap < 4; ++tap) {
            int ky = tap / 2, kx = tap % 2;
            xs[grp][tap][o] = x[((size_t)b * N_ + (2 * y + ky) * Wimg + 2 * xx + kx) * DIM_ + o];
        }
        __syncthreads();
        float sum = sr_b[o];
        for (int i = 0; i < 64; ++i) {
            const float* wr = srwt + (i * 4) * 64 + o;
            sum += xs[grp][0][i] * wr[0] + xs[grp][1][i] * wr[64]
                 + xs[grp][2][i] * wr[128] + xs[grp][3][i] * wr[192];
        }
        float m = sum;
        #pragma unroll
        for (int off = 1; off < 64; off <<= 1) m += __shfl_xor(m, off);
        m *= (1.0f / 64.0f);
        float d = sum - m;
        float v = d * d;
        #pragma unroll
        for (int off = 1; off < 64; off <<= 1) v += __shfl_xor(v, off);
        v *= (1.0f / 64.0f);
        float lnv = d * rsqrtf(v + 1e-5f) * ln_g[o] + ln_b[o];
        lnv_s[grp][o] = lnv;
        __syncthreads();
        float s0 = 0.f, s1 = 0.f;
        for (int i = 0; i < 64; ++i) {
            float lv = lnv_s[grp][i];
            s0 += lv * wkv[i * 128 + o];
            s1 += lv * wkv[i * 128 + o + 64];
        }
        const float SCK = 0.125f * 1.44269504088896340736f;
        kgb[((size_t)b * NR_ + n) * 64 + o] = bf16r(s0 * SCK);
        vg[((size_t)b * NR_ + n) * 64 + o] = s1;
    }
}

// =====================================================================
// FUSED2: [0,784) pointwise GEMM -> kvl16 | [784,882) lcg+vtrans
// =====================================================================
__global__ __launch_bounds__(256, 2)
void fused2_kernel(const ushort_t* __restrict__ dwtb, const ushort_t* __restrict__ pwt,
                   const float* __restrict__ kvl_pb, ushort_t* __restrict__ kvl16,
                   const float* __restrict__ vg, const float* __restrict__ lcg_w,
                   const float* __restrict__ lcg_b, ushort_t* __restrict__ vtb) {
    const int bid = blockIdx.x;
    const int tid = threadIdx.x;
    __shared__ __align__(16) ushort_t As[128 * 64];
    __shared__ __align__(16) ushort_t Bs[128 * 64];
    __shared__ float ld[64][65];

    if (bid < 784) {
        const int bm = (bid % 196) * 128;
        const int bn = (bid / 196) * 128;
        const int l15 = tid & 15;
        const int g   = (tid & 63) >> 4;
        const int w   = tid >> 6;
        const int wr  = w >> 1, wc = w & 1;
        float4v acc[4][4];
        #pragma unroll
        for (int m = 0; m < 4; ++m)
            #pragma unroll
            for (int n = 0; n < 4; ++n) acc[m][n] = (float4v){0.f, 0.f, 0.f, 0.f};
        for (int k0 = 0; k0 < 448; k0 += 64) {
            #pragma unroll
            for (int i = 0; i < 4; ++i) {
                int c = i * 256 + tid;
                int r = c >> 3, ch = c & 7;
                int sch = ch ^ (r & 7);
                gload16(dwtb + (size_t)(bm + r) * 448 + k0 + sch * 8, (void*)(As + c * 8));
                gload16(pwt  + (size_t)(bn + r) * 448 + k0 + sch * 8, (void*)(Bs + c * 8));
            }
            __syncthreads();
            short8_t af[4][2], bfr[4][2];
            #pragma unroll
            for (int m = 0; m < 4; ++m) {
                int ar = wr * 64 + m * 16 + l15;
                #pragma unroll
                for (int h = 0; h < 2; ++h)
                    af[m][h] = *(const short8_t*)((const char*)As + ar * 128 + (((h * 4 + g) ^ (ar & 7)) * 16));
            }
            #pragma unroll
            for (int n = 0; n < 4; ++n) {
                int br = wc * 64 + n * 16 + l15;
                #pragma unroll
                for (int h = 0; h < 2; ++h)
                    bfr[n][h] = *(const short8_t*)((const char*)Bs + br * 128 + (((h * 4 + g) ^ (br & 7)) * 16));
            }
            #pragma unroll
            for (int m = 0; m < 4; ++m)
                #pragma unroll
                for (int n = 0; n < 4; ++n) {
                    acc[m][n] = __builtin_amdgcn_mfma_f32_16x16x32_bf16(af[m][0], bfr[n][0], acc[m][n], 0, 0, 0);
                    acc[m][n] = __builtin_amdgcn_mfma_f32_16x16x32_bf16(af[m][1], bfr[n][1], acc[m][n], 0, 0, 0);
                }
            __syncthreads();
        }
        #pragma unroll
        for (int n = 0; n < 4; ++n) {
            int ccol = bn + wc * 64 + n * 16 + l15;
            if (ccol < 448) {
                float bv = kvl_pb[ccol];
                #pragma unroll
                for (int m = 0; m < 4; ++m) {
                    int crow = bm + wr * 64 + m * 16 + g * 4;
                    #pragma unroll
                    for (int j = 0; j < 4; ++j)
                        kvl16[(size_t)(crow + j) * 448 + ccol] = bf16r(acc[m][n][j] + bv);
                }
            }
        }
    } else {
        const int lb = bid - 784;
        const int b = lb / 49, n0 = (lb % 49) * 64;
        #pragma unroll
        for (int i = 0; i < 16; ++i) {
            int idx = i * 256 + tid;
            int n = idx >> 6, c = idx & 63;
            int nn = n0 + n;
            int y = nn / HS_, xx = nn % HS_;
            float sum = vg[((size_t)b * NR_ + nn) * 64 + c] + lcg_b[c];
            #pragma unroll
            for (int ky = 0; ky < 3; ++ky)
                #pragma unroll
                for (int kx = 0; kx < 3; ++kx) {
                    int yy = y + ky - 1, x2 = xx + kx - 1;
                    if (yy >= 0 && yy < HS_ && x2 >= 0 && x2 < HS_)
                        sum += vg[((size_t)b * NR_ + yy * HS_ + x2) * 64 + c] * lcg_w[c * 9 + ky * 3 + kx];
                }
            ld[n][c] = sum;
        }
        __syncthreads();
        #pragma unroll
        for (int i = 0; i < 16; ++i) {
            int idx = i * 256 + tid;
            int d = idx >> 6, nn = idx & 63;
            vtb[(size_t)(b * 64 + d) * NR_ + n0 + nn] = bf16r(ld[nn][d]);
        }
    }
}

// =====================================================================
// "scrambled mean" body (bf16 kvl), blk passed explicitly
// =====================================================================
template<int L, int NBW, int STRIDE, int DIL, int CHOFF>
__device__ inline void lm_body(int blk, int t, const ushort_t* __restrict__ kvl16,
                               float* __restrict__ kvm) {
    __shared__ float slo[L], shi[L];
    const int n = blk % 49;
    const int h = (blk / 49) % NH_;
    const int b = blk / (49 * NH_);
    const int wy = n / 7, wx = n % 7;

    if (t < L) {
        const int by = t / NBW, bx = t % NBW;
        int Y = by * STRIDE + DIL * wy;
        int X = bx * STRIDE + DIL * wx;
        if (Y >= Himg) Y = 2 * Himg - 2 - Y;
        if (X >= Wimg) X = 2 * Wimg - 2 - X;
        const ushort_t* src = kvl16 + ((size_t)b * N_ + Y * Wimg + X) * DL_ + CHOFF + h * HD_;
        float v[28];
        #pragma unroll
        for (int i = 0; i < 7; ++i) {
            uint2v q2 = ((const uint2v*)src)[i];
            v[i * 4]     = bf16tof((ushort_t)(q2[0] & 0xffffu));
            v[i * 4 + 1] = bf16tof((ushort_t)(q2[0] >> 16));
            v[i * 4 + 2] = bf16tof((ushort_t)(q2[1] & 0xffffu));
            v[i * 4 + 3] = bf16tof((ushort_t)(q2[1] >> 16));
        }
        const int f0 = t * HD_;
        const int bin0 = f0 / L;
        const int nlo = min(HD_, (bin0 + 1) * L - f0);
        float s0 = 0.f, s1 = 0.f;
        #pragma unroll
        for (int j = 0; j < HD_; ++j) {
            if (j < nlo) s0 += v[j]; else s1 += v[j];
        }
        slo[t] = s0;
        shi[t] = s1;
    }
    __syncthreads();
    if (t < HD_) {
        const int t_lo = (t * L) / HD_;
        const int t_hi = min(L - 1, (t * L + L - 1) / HD_);
        float sum = 0.f;
        for (int u = t_lo; u <= t_hi; ++u) {
            int f0 = u * HD_;
            int b0 = f0 / L;
            int b1 = (f0 + HD_ - 1) / L;
            if (b0 == t) sum += slo[u];
            if (b1 == t && b1 != b0) sum += shi[u];
        }
        kvm[(size_t)blk * HD_ + t] = sum * (1.0f / (float)L);
    }
}

// =====================================================================
// FUSED attn_global + local_mean
// [0,1568): attn_global (512 thr); [1568,3136): lm
// =====================================================================
__global__ __launch_bounds__(512)
void fused_ag_lm_kernel(const ushort_t* __restrict__ q16,
                        const ushort_t* __restrict__ kgb,
                        const ushort_t* __restrict__ vtb,
                        ushort_t* __restrict__ osp16, float* __restrict__ mls,
                        const ushort_t* __restrict__ kvl16,
                        float* __restrict__ kvm1, float* __restrict__ kvm2) {
    const int bid = blockIdx.x;
    const int tid = threadIdx.x;
    __shared__ __align__(16) ushort_t Ks[2 * 64 * 64];
    __shared__ __align__(16) ushort_t Vs[2 * 64 * 64];

    if (bid >= 1568) {
        int lmid = bid - 1568;
        int blk = lmid % 784;
        if (lmid < 784) lm_body<256, 16, 7, 1, 0>(blk, tid, kvl16, kvm1);
        else            lm_body<81, 9, 13, 2, 224>(blk, tid, kvl16, kvm2);
        return;
    }

    const int split = (bid / 98) & 7;
    const int b     = (bid / 98) >> 3;
    const int q0    = (bid % 98) * 128;
    const int w     = tid >> 6;
    const int l     = tid & 63;
    const int l15   = l & 15;
    const int g     = l >> 4;
    const int lx    = l15 & 7;

    short8_t qf[2];
    {
        const ushort_t* qrow = q16 + ((size_t)b * N_ + q0 + w * 16 + l15) * DIM_;
        qf[0] = *(const short8_t*)(qrow + g * 8);
        qf[1] = *(const short8_t*)(qrow + g * 8 + 32);
    }

    float4v o[4];
    #pragma unroll
    for (int i = 0; i < 4; ++i) o[i] = (float4v){0.f, 0.f, 0.f, 0.f};
    float m_run = -3.0e38f, l_run = 0.f;

    const int stg_r   = tid >> 3;
    const int stg_sch = (tid & 7) ^ (stg_r & 7);
    const int stg_pr  = (stg_r & 32) | (((stg_r >> 2) & 3) << 3) | (((stg_r >> 4) & 1) << 2) | (stg_r & 3);
    auto stage = [&](int t, int buf) {
        const int k0 = t * 64;
        gload16(kgb + ((size_t)(b * NR_ + k0 + stg_pr) << 6) + stg_sch * 8,
                (void*)(Ks + buf * 4096 + tid * 8));
        gload16(vtb + (size_t)(b * 64 + stg_r) * NR_ + k0 + stg_sch * 8,
                (void*)(Vs + buf * 4096 + tid * 8));
    };

    auto compute = [&](const ushort_t* Kb, const ushort_t* Vb) {
        float4v sc[4];
        #pragma unroll
        for (int c = 0; c < 4; ++c) {
            float4v acc = (float4v){0.f, 0.f, 0.f, 0.f};
            #pragma unroll
            for (int dc = 0; dc < 2; ++dc) {
                int row = c * 16 + l15;
                short8_t ak = *(const short8_t*)((const char*)Kb + row * 128 + (((g + 4 * dc) ^ lx) * 16));
                acc = __builtin_amdgcn_mfma_f32_16x16x32_bf16(ak, qf[dc], acc, 0, 0, 0);
            }
            sc[c] = acc;
        }

        float tmax = fmaxf(fmaxf(fmaxf(sc[0][0], sc[0][1]), fmaxf(sc[0][2], sc[0][3])),
                           fmaxf(fmaxf(sc[1][0], sc[1][1]), fmaxf(sc[1][2], sc[1][3])));
        tmax = fmaxf(tmax, fmaxf(fmaxf(fmaxf(sc[2][0], sc[2][1]), fmaxf(sc[2][2], sc[2][3])),
                                 fmaxf(fmaxf(sc[3][0], sc[3][1]), fmaxf(sc[3][2], sc[3][3]))));

        if (__any(tmax > m_run + 11.0f)) {
            float rmax = fmaxf(tmax, __shfl_xor(tmax, 16));
            rmax = fmaxf(rmax, __shfl_xor(rmax, 32));
            float m_new = fmaxf(m_run, rmax);
            float corr = __builtin_amdgcn_exp2f(m_run - m_new);
            float co[4];
            #pragma unroll
            for (int r = 0; r < 4; ++r) co[r] = __shfl(corr, g * 4 + r);
            #pragma unroll
            for (int dc = 0; dc < 4; ++dc)
                #pragma unroll
                for (int r = 0; r < 4; ++r) o[dc][r] *= co[r];
            l_run *= corr;
            m_run = m_new;
        }

        float p[4][4];
        float ladd = 0.f;
        #pragma unroll
        for (int c = 0; c < 4; ++c)
            #pragma unroll
            for (int r = 0; r < 4; ++r) {
                float pe = __builtin_amdgcn_exp2f(sc[c][r] - m_run);
                p[c][r] = pe;
                ladd += pe;
            }
        l_run += ladd;

        #pragma unroll
        for (int kkc = 0; kkc < 2; ++kkc) {
            uint4v au;
            au[0] = cvtpk(p[2 * kkc][0],     p[2 * kkc][1]);
            au[1] = cvtpk(p[2 * kkc][2],     p[2 * kkc][3]);
            au[2] = cvtpk(p[2 * kkc + 1][0], p[2 * kkc + 1][1]);
            au[3] = cvtpk(p[2 * kkc + 1][2], p[2 * kkc + 1][3]);
            short8_t ap = __builtin_bit_cast(short8_t, au);
            #pragma unroll
            for (int dc = 0; dc < 4; ++dc) {
                int vrow = dc * 16 + l15;
                short8_t bv = *(const short8_t*)((const char*)Vb + vrow * 128 + (((kkc * 4 + g) ^ lx) * 16));
                o[dc] = __builtin_amdgcn_mfma_f32_16x16x32_bf16(ap, bv, o[dc], 0, 0, 0);
            }
        }
    };

    const int t0 = (split * 49) / 8;
    const int t1 = ((split + 1) * 49) / 8;
    int t = t0;
    for (; t + 1 < t1; t += 2) {
        stage(t, 0);
        stage(t + 1, 1);
        __syncthreads();
        compute(Ks, Vs);
        compute(Ks + 4096, Vs + 4096);
        __syncthreads();
    }
    if (t < t1) {
        stage(t, 0);
        __syncthreads();
        compute(Ks, Vs);
    }

    float l_tot = l_run;
    l_tot += __shfl_xor(l_tot, 16);
    l_tot += __shfl_xor(l_tot, 32);

    const size_t rbase = (size_t)(split * B_ + b) * N_;
    #pragma unroll
    for (int dc = 0; dc < 4; ++dc)
        #pragma unroll
        for (int r = 0; r < 4; ++r) {
            int row = q0 + w * 16 + g * 4 + r;
            osp16[(rbase + row) * 64 + dc * 16 + l15] = bf16r(o[dc][r]);
        }
    if (l < 16) {
        int row = q0 + w * 16 + l15;
        mls[(rbase + row) * 2]     = m_run;
        mls[(rbase + row) * 2 + 1] = l_tot;
    }
}

// =====================================================================
// merged fc@sh for both branches
// =====================================================================
__global__ __launch_bounds__(64)
void fcsh_merged_kernel(const float* __restrict__ kvm1, const float* __restrict__ fc1w,
                        const float* __restrict__ sh1w, float* __restrict__ kv1,
                        const float* __restrict__ kvm2, const float* __restrict__ fc2w,
                        const float* __restrict__ sh2w, float* __restrict__ kv2) {
    int bh2 = blockIdx.x;
    const float* kvm = (bh2 < 16) ? kvm1 : kvm2;
    const float* fcw = (bh2 < 16) ? fc1w : fc2w;
    const float* shw = (bh2 < 16) ? sh1w : sh2w;
    float* outp      = (bh2 < 16) ? kv1 : kv2;
    int bh = (bh2 < 16) ? bh2 : bh2 - 16;
    __shared__ float kin[49][28];
    __shared__ float tmp[49][28];
    __shared__ float fw[28 * 28];
    __shared__ float sw[28 * 56];
    int t = threadIdx.x;
    for (int i = t; i < 49 * 28; i += 64) kin[i / 28][i % 28] = kvm[bh * 49 * 28 + i];
    for (int i = t; i < 28 * 28; i += 64) fw[i] = fcw[i];
    for (int i = t; i < 28 * 56; i += 64) sw[i] = shw[i];
    __syncthreads();
    for (int i = t; i < 49 * 28; i += 64) {
        int rr = i / 28, j = i % 28;
        float s = 0.f;
        for (int k = 0; k < 28; ++k) s += kin[rr][k] * fw[k * 28 + j];
        tmp[rr][j] = s;
    }
    __syncthreads();
    for (int i = t; i < 49 * 56; i += 64) {
        int rr = i / 56, j = i % 56;
        float s = 0.f;
        for (int k = 0; k < 28; ++k) s += tmp[rr][k] * sw[k * 56 + j];
        outp[bh * 49 * 56 + i] = s;
    }
}

// =====================================================================
// merged v-conv for both branches
// =====================================================================
__global__ __launch_bounds__(256)
void vconv_merged_kernel(const float* __restrict__ kv1, const float* __restrict__ lc1w,
                         const float* __restrict__ lc1b, float* __restrict__ v1c,
                         const float* __restrict__ kv2, const float* __restrict__ lc2w,
                         const float* __restrict__ lc2b, float* __restrict__ v2c) {
    const float* kvsh = (blockIdx.y == 0) ? kv1 : kv2;
    const float* w    = (blockIdx.y == 0) ? lc1w : lc2w;
    const float* bias = (blockIdx.y == 0) ? lc1b : lc2b;
    float* vc         = (blockIdx.y == 0) ? v1c : v2c;
    int idx = blockIdx.x * 256 + threadIdx.x;
    if (idx >= B_ * NH_ * 49 * HD_) return;
    int d  = idx % HD_;
    int n  = (idx / HD_) % 49;
    int bh = idx / (HD_ * 49);
    int h  = bh % NH_;
    int y = n / 7, xx = n % 7;
    int c = h * HD_ + d;
    float sum = kvsh[(bh * 49 + n) * 56 + 28 + d] + bias[c];
    #pragma unroll
    for (int ky = 0; ky < 3; ++ky)
        #pragma unroll
        for (int kx = 0; kx < 3; ++kx) {
            int yy = y + ky - 1, x2 = xx + kx - 1;
            if (yy >= 0 && yy < 7 && x2 >= 0 && x2 < 7)
                sum += kvsh[(bh * 49 + yy * 7 + x2) * 56 + 28 + d] * w[c * 9 + ky * 3 + kx];
        }
    vc[idx] = sum;
}

// =====================================================================
// FUSED attn_local + combine
// [0,6272): attn_local; [6272,12544): combine
// =====================================================================
__global__ __launch_bounds__(256)
void fused_local_comb_kernel(const ushort_t* __restrict__ q16,
                             const float* __restrict__ kv1, const float* __restrict__ v1c,
                             const float* __restrict__ kv2, const float* __restrict__ v2c,
                             const ushort_t* __restrict__ osp16, const float* __restrict__ mls,
                             ushort_t* __restrict__ catb) {
    const int bid = blockIdx.x;
    const int tid = threadIdx.x;
    __shared__ __align__(16) ushort_t Ks[64 * 32];
    __shared__ __align__(16) ushort_t Vt[32 * 64];

    if (bid >= 6272) {
        int idx = (bid - 6272) * 256 + tid;
        int col = idx & 63;
        size_t rn = (size_t)(idx >> 6);
        const size_t BN = (size_t)B_ * N_;
        float ms[NSPLIT], ls[NSPLIT];
        float m = -3.0e38f;
        #pragma unroll
        for (int s = 0; s < NSPLIT; ++s) {
            ms[s] = mls[(s * BN + rn) * 2];
            ls[s] = mls[(s * BN + rn) * 2 + 1];
            m = fmaxf(m, ms[s]);
        }
        float lsum = 0.f, acc = 0.f;
        #pragma unroll
        for (int s = 0; s < NSPLIT; ++s) {
            float wgt = __builtin_amdgcn_exp2f(ms[s] - m);
            lsum += ls[s] * wgt;
            acc  += bf16tof(osp16[(s * BN + rn) * 64 + col]) * wgt;
        }
        catb[rn * DIM_ + col] = bf16r(acc / lsum);
        return;
    }

    const int ybh    = bid / 196;
    const int branch = ybh & 1;
    const int bh     = ybh >> 1;
    const int b      = bh >> 3, h = bh & 7;
    const int q0     = (bid % 196) * 64;
    const int w      = tid >> 6;
    const int l      = tid & 63;
    const int l15    = l & 15;
    const int g      = l >> 4;
    const float SC2K = 0.1889822365046136f * 1.44269504088896340736f;

    const float* kvsh = branch ? kv2 : kv1;
    const float* vc   = branch ? v2c : v1c;
    const int qoff    = D0_ + h * 56 + branch * 28;
    const int outoff  = (branch ? D0_ + 224 : D0_) + h * HD_;

    {
        int row = tid >> 2, lc = tid & 3;
        int pr = (row & 32) | (((row >> 2) & 3) << 3) | (((row >> 4) & 1) << 2) | (row & 3);
        uint4v u = (uint4v){0u, 0u, 0u, 0u};
        if (pr < 49) {
            const float* src = kvsh + (bh * 49 + pr) * 56 + lc * 8;
            float vv[8];
            #pragma unroll
            for (int j2 = 0; j2 < 8; ++j2)
                vv[j2] = (lc * 8 + j2 < 28) ? src[j2] * SC2K : 0.f;
            u[0] = cvtpk(vv[0], vv[1]);
            u[1] = cvtpk(vv[2], vv[3]);
            u[2] = cvtpk(vv[4], vv[5]);
            u[3] = cvtpk(vv[6], vv[7]);
        }
        *(uint4v*)(Ks + row * 32 + (lc ^ (row & 3)) * 8) = u;
    }
    {
        int row = tid >> 3, lc = tid & 7;
        uint4v u = (uint4v){0u, 0u, 0u, 0u};
        if (row < 28) {
            float vv[8];
            #pragma unroll
            for (int j2 = 0; j2 < 8; ++j2) {
                int kc = lc * 8 + j2;
                vv[j2] = (kc < 49) ? vc[(bh * 49 + kc) * 28 + row] : 0.f;
            }
            u[0] = cvtpk(vv[0], vv[1]);
            u[1] = cvtpk(vv[2], vv[3]);
            u[2] = cvtpk(vv[4], vv[5]);
            u[3] = cvtpk(vv[6], vv[7]);
        }
        *(uint4v*)(Vt + row * 64 + (lc ^ (row & 7)) * 8) = u;
    }
    short8_t qf;
    {
        const ushort_t* qp = q16 + ((size_t)b * N_ + q0 + w * 16 + l15) * DIM_ + qoff + g * 8;
        uint2v a01 = *(const uint2v*)qp;
        uint2v a23 = (g < 3) ? *(const uint2v*)(qp + 4) : (uint2v){0u, 0u};
        uint4v uv;
        uv[0] = a01[0]; uv[1] = a01[1]; uv[2] = a23[0]; uv[3] = a23[1];
        qf = __builtin_bit_cast(short8_t, uv);
    }
    __syncthreads();

    float4v sc4[4];
    #pragma unroll
    for (int c = 0; c < 4; ++c) {
        int row = c * 16 + l15;
        short8_t ak = *(const short8_t*)(Ks + row * 32 + ((g ^ (row & 3)) * 8));
        float4v acc = (float4v){0.f, 0.f, 0.f, 0.f};
        sc4[c] = __builtin_amdgcn_mfma_f32_16x16x32_bf16(ak, qf, acc, 0, 0, 0);
    }

    float tmax = fmaxf(fmaxf(fmaxf(sc4[0][0], sc4[0][1]), fmaxf(sc4[0][2], sc4[0][3])),
                       fmaxf(fmaxf(sc4[1][0], sc4[1][1]), fmaxf(sc4[1][2], sc4[1][3])));
    tmax = fmaxf(tmax, fmaxf(fmaxf(fmaxf(sc4[2][0], sc4[2][1]), fmaxf(sc4[2][2], sc4[2][3])),
                             fmaxf(fmaxf(sc4[3][0], sc4[3][1]), fmaxf(sc4[3][2], sc4[3][3]))));
    tmax = fmaxf(tmax, __shfl_xor(tmax, 16));
    tmax = fmaxf(tmax, __shfl_xor(tmax, 32));

    float p[4][4];
    float lsum = 0.f;
    #pragma unroll
    for (int c = 0; c < 4; ++c)
        #pragma unroll
        for (int r = 0; r < 4; ++r) {
            float pe = __builtin_amdgcn_exp2f(sc4[c][r] - tmax);
            if (c >= 2 && (8 * g + 4 * (c & 1) + r) >= 17) pe = 0.f;
            p[c][r] = pe;
            lsum += pe;
        }
    lsum += __shfl_xor(lsum, 16);
    lsum += __shfl_xor(lsum, 32);
    float inv = 1.0f / lsum;

    float4v o2[2];
    o2[0] = (float4v){0.f, 0.f, 0.f, 0.f};
    o2[1] = (float4v){0.f, 0.f, 0.f, 0.f};
    #pragma unroll
    for (int kkc = 0; kkc < 2; ++kkc) {
        uint4v au;
        au[0] = cvtpk(p[2 * kkc][0],     p[2 * kkc][1]);
        au[1] = cvtpk(p[2 * kkc][2],     p[2 * kkc][3]);
        au[2] = cvtpk(p[2 * kkc + 1][0], p[2 * kkc + 1][1]);
        au[3] = cvtpk(p[2 * kkc + 1][2], p[2 * kkc + 1][3]);
        short8_t ap = __builtin_bit_cast(short8_t, au);
        #pragma unroll
        for (int dc = 0; dc < 2; ++dc) {
            int vrow = dc * 16 + l15;
            short8_t bv = *(const short8_t*)(Vt + vrow * 64 + (((kkc * 4 + g) ^ (vrow & 7)) * 8));
            o2[dc] = __builtin_amdgcn_mfma_f32_16x16x32_bf16(ap, bv, o2[dc], 0, 0, 0);
        }
    }

    float irow[4];
    #pragma unroll
    for (int r = 0; r < 4; ++r) irow[r] = __shfl(inv, g * 4 + r);
    #pragma unroll
    for (int dc = 0; dc < 2; ++dc) {
        int d = dc * 16 + l15;
        if (d < 28) {
            #pragma unroll
            for (int r = 0; r < 4; ++r) {
                int row = q0 + w * 16 + g * 4 + r;
                catb[((size_t)b * N_ + row) * DIM_ + outoff + d] = bf16r(o2[dc][r] * irow[r]);
            }
        }
    }
}

// =====================================================================
extern "C" void kernel_launch(void* const* d_in, const int* in_sizes, int n_in,
                              void* d_out, int out_size, void* d_ws, size_t ws_size,
                              hipStream_t stream) {
    const float* x      = (const float*)d_in[0];
    const float* Wq     = (const float*)d_in[1];
    const float* Wkv_g  = (const float*)d_in[2];
    const float* sr_w   = (const float*)d_in[3];
    const float* sr_b   = (const float*)d_in[4];
    const float* ln_g   = (const float*)d_in[5];
    const float* ln_b   = (const float*)d_in[6];
    const float* lcg_w  = (const float*)d_in[7];
    const float* lcg_b  = (const float*)d_in[8];
    const float* kvl_dw = (const float*)d_in[9];
    const float* kvl_db = (const float*)d_in[10];
    const float* kvl_pw = (const float*)d_in[11];
    const float* kvl_pb = (const float*)d_in[12];
    const float* fc1_w  = (const float*)d_in[13];
    const float* sh1_w  = (const float*)d_in[14];
    const float* lc1_w  = (const float*)d_in[15];
    const float* lc1_b  = (const float*)d_in[16];
    const float* fc2_w  = (const float*)d_in[17];
    const float* sh2_w  = (const float*)d_in[18];
    const float* lc2_w  = (const float*)d_in[19];
    const float* lc2_b  = (const float*)d_in[20];
    const float* proj_w = (const float*)d_in[21];
    const float* proj_b = (const float*)d_in[22];
    float* out = (float*)d_out;
    char* base = (char*)d_ws;

    size_t o = 0;
    auto alloc = [&](size_t bytes) -> void* {
        void* p = base + o;
        o = (o + bytes + 255) & ~(size_t)255;
        return p;
    };
    ushort_t* q16   = (ushort_t*)alloc((size_t)B_ * N_ * DIM_ * 2);
    ushort_t* kvl16 = (ushort_t*)alloc((size_t)B_ * N_ * DL_ * 2);
    ushort_t* osp16 = (ushort_t*)alloc((size_t)NSPLIT * B_ * N_ * 64 * 2);
    float*    mls   = (float*)   alloc((size_t)NSPLIT * B_ * N_ * 2 * 4);
    ushort_t* xcat  = (ushort_t*)alloc((size_t)B_ * N_ * DIM_ * 2);  // xbf, then cat
    ushort_t* dwtb  = (ushort_t*)alloc((size_t)B_ * N_ * DL_ * 2);
    ushort_t* kgb   = (ushort_t*)alloc((size_t)B_ * NR_ * 64 * 2);
    float*    vg    = (float*)   alloc((size_t)B_ * NR_ * 64 * 4);
    ushort_t* vtb   = (ushort_t*)alloc((size_t)B_ * 64 * NR_ * 2);
    ushort_t* wqt   = (ushort_t*)alloc((size_t)512 * 512 * 2);
    ushort_t* pwt   = (ushort_t*)alloc((size_t)512 * 448 * 2);
    ushort_t* projt = (ushort_t*)alloc((size_t)512 * 512 * 2);
    float*    srwt  = (float*)   alloc((size_t)256 * 64 * 4);
    float*    kvm1  = (float*)   alloc((size_t)B_ * NH_ * 49 * HD_ * 4);
    float*    kvm2  = (float*)   alloc((size_t)B_ * NH_ * 49 * HD_ * 4);
    float*    kv1   = (float*)   alloc((size_t)B_ * NH_ * 49 * 56 * 4);
    float*    kv2   = (float*)   alloc((size_t)B_ * NH_ * 49 * 56 * 4);
    float*    v1c   = (float*)   alloc((size_t)B_ * NH_ * 49 * HD_ * 4);
    float*    v2c   = (float*)   alloc((size_t)B_ * NH_ * 49 * HD_ * 4);
    ushort_t* xbf   = xcat;
    ushort_t* catb  = xcat;

    const int M = B_ * N_;   // 25088

    // 1. merged prep
    prep_kernel<<<9280, 256, 0, stream>>>(Wq, kvl_pw, proj_w, sr_w, x,
                                          wqt, pwt, projt, srwt, xbf);

    // 2. fused: q-GEMM + dwt + srlnkv (mutually independent)
    fused3_kernel<<<5096, 256, 0, stream>>>(xbf, wqt, q16,
                                            kvl_dw, kvl_db, dwtb,
                                            x, srwt, sr_b, ln_g, ln_b, Wkv_g,
                                            kgb, vg);

    // 3. fused: pointwise GEMM -> kvl16 + lcg/vtrans -> vtb
    fused2_kernel<<<882, 256, 0, stream>>>(dwtb, pwt, kvl_pb, kvl16,
                                           vg, lcg_w, lcg_b, vtb);

    // 4. fused: attn_global (split-K=8) + local_mean (independent)
    fused_ag_lm_kernel<<<3136, 512, 0, stream>>>(q16, kgb, vtb, osp16, mls,
                                                 kvl16, kvm1, kvm2);

    // 5. fc @ sh (both branches)
    fcsh_merged_kernel<<<32, 64, 0, stream>>>(kvm1, fc1_w, sh1_w, kv1,
                                              kvm2, fc2_w, sh2_w, kv2);

    // 6. v-conv (both branches)
    {
        int blocks = (B_ * NH_ * 49 * HD_ + 255) / 256;
        vconv_merged_kernel<<<dim3(blocks, 2), 256, 0, stream>>>(
            kv1, lc1_w, lc1_b, v1c, kv2, lc2_w, lc2_b, v2c);
    }

    // 7. fused: attn_local + combine (disjoint catb columns)
    fused_local_comb_kernel<<<12544, 256, 0, stream>>>(q16, kv1, v1c, kv2, v2c,
                                                       osp16, mls, catb);

    // 8. out = catb @ projt^T + proj_b
    gemm_bf16_kernel<true, false><<<dim3(M / 128, 4), 256, 0, stream>>>(
        catb, projt, proj_b, out, 512, 512, 512);
}

// Round 22
// 263.976 us; speedup vs baseline: 1.1813x; 1.0050x over previous
//
#include <hip/hip_runtime.h>
#include <hip/hip_bf16.h>
#include <math.h>
#include <stdint.h>

// ---- problem constants ----
static constexpr int B_    = 2;
static constexpr int N_    = 12544;   // 112*112
static constexpr int DIM_  = 512;
static constexpr int D0_   = 64;
static constexpr int DL_   = 448;
static constexpr int Himg  = 112;
static constexpr int Wimg  = 112;
static constexpr int HS_   = 56;
static constexpr int NR_   = 3136;    // 56*56
static constexpr int NH_   = 8;
static constexpr int HD_   = 28;
static constexpr int NSPLIT = 8;

typedef unsigned short ushort_t;
typedef __attribute__((ext_vector_type(8))) short short8_t;
typedef __attribute__((ext_vector_type(4))) float float4v;
typedef __attribute__((ext_vector_type(4))) unsigned uint4v;
typedef __attribute__((ext_vector_type(2))) unsigned uint2v;

static __device__ inline ushort_t bf16r(float x) {
    unsigned u = __builtin_bit_cast(unsigned, x);
    u = (u + 0x7FFFu + ((u >> 16) & 1u)) >> 16;
    return (ushort_t)u;
}
static __device__ inline float bf16tof(ushort_t h) {
    unsigned u = ((unsigned)h) << 16;
    return __builtin_bit_cast(float, u);
}
static __device__ inline unsigned pack_bf16(float lo, float hi) {
    unsigned a = __builtin_bit_cast(unsigned, lo);
    unsigned b = __builtin_bit_cast(unsigned, hi);
    a = (a + 0x7FFFu + ((a >> 16) & 1u)) >> 16;
    b = (b + 0x7FFFu + ((b >> 16) & 1u)) >> 16;
    return a | (b << 16);
}
static __device__ inline unsigned cvtpk(float lo, float hi) {
    float2 f2; f2.x = lo; f2.y = hi;
    __hip_bfloat162 h = __float22bfloat162_rn(f2);
    unsigned u;
    __builtin_memcpy(&u, &h, 4);
    return u;
}

using gptr_t = const __attribute__((address_space(1))) void*;
using lptr_t = __attribute__((address_space(3))) void*;
static __device__ inline void gload16(const void* g, void* l) {
    __builtin_amdgcn_global_load_lds((gptr_t)(uintptr_t)g, (lptr_t)(uintptr_t)l, 16, 0, 0);
}

// =====================================================================
// bf16 MFMA GEMM (standalone, used for proj only)
// =====================================================================
template<bool HASBIAS, bool OUT16>
__global__ __launch_bounds__(256, 2)
void gemm_bf16_kernel(const ushort_t* __restrict__ A,
                      const ushort_t* __restrict__ Bt,
                      const float* __restrict__ bias,
                      void* __restrict__ Cv,
                      int Nn, int K, int ldc) {
    constexpr int BM = 128, BK = 64;
    __shared__ __align__(16) ushort_t As[BM * BK];
    __shared__ __align__(16) ushort_t Bs[BM * BK];
    const int bm = blockIdx.x * BM;
    const int bn = blockIdx.y * BM;
    const int tid = threadIdx.x;
    const int l15 = tid & 15;
    const int g   = (tid & 63) >> 4;
    const int w   = tid >> 6;
    const int wr  = w >> 1, wc = w & 1;

    float4v acc[4][4];
    #pragma unroll
    for (int m = 0; m < 4; ++m)
        #pragma unroll
        for (int n = 0; n < 4; ++n) acc[m][n] = (float4v){0.f, 0.f, 0.f, 0.f};

    for (int k0 = 0; k0 < K; k0 += BK) {
        #pragma unroll
        for (int i = 0; i < 4; ++i) {
            int c = i * 256 + tid;
            int r = c >> 3, ch = c & 7;
            int sch = ch ^ (r & 7);
            gload16(A  + (size_t)(bm + r) * K + k0 + sch * 8, (void*)(As + c * 8));
            gload16(Bt + (size_t)(bn + r) * K + k0 + sch * 8, (void*)(Bs + c * 8));
        }
        __syncthreads();

        short8_t af[4][2], bfr[4][2];
        #pragma unroll
        for (int m = 0; m < 4; ++m) {
            int ar = wr * 64 + m * 16 + l15;
            #pragma unroll
            for (int h = 0; h < 2; ++h)
                af[m][h] = *(const short8_t*)((const char*)As + ar * 128 + (((h * 4 + g) ^ (ar & 7)) * 16));
        }
        #pragma unroll
        for (int n = 0; n < 4; ++n) {
            int br = wc * 64 + n * 16 + l15;
            #pragma unroll
            for (int h = 0; h < 2; ++h)
                bfr[n][h] = *(const short8_t*)((const char*)Bs + br * 128 + (((h * 4 + g) ^ (br & 7)) * 16));
        }
        #pragma unroll
        for (int m = 0; m < 4; ++m)
            #pragma unroll
            for (int n = 0; n < 4; ++n) {
                acc[m][n] = __builtin_amdgcn_mfma_f32_16x16x32_bf16(af[m][0], bfr[n][0], acc[m][n], 0, 0, 0);
                acc[m][n] = __builtin_amdgcn_mfma_f32_16x16x32_bf16(af[m][1], bfr[n][1], acc[m][n], 0, 0, 0);
            }
        __syncthreads();
    }

    #pragma unroll
    for (int n = 0; n < 4; ++n) {
        int ccol = bn + wc * 64 + n * 16 + l15;
        if (ccol < Nn) {
            float bv = HASBIAS ? bias[ccol] : 0.f;
            #pragma unroll
            for (int m = 0; m < 4; ++m) {
                int crow = bm + wr * 64 + m * 16 + g * 4;
                #pragma unroll
                for (int j = 0; j < 4; ++j) {
                    float v = acc[m][n][j] + bv;
                    if (OUT16)
                        ((ushort_t*)Cv)[(size_t)(crow + j) * ldc + ccol] = bf16r(v);
                    else
                        ((float*)Cv)[(size_t)(crow + j) * ldc + ccol] = v;
                }
            }
        }
    }
}

// =====================================================================
// merged prep: wqt, pwt, projt, srwt, xbf
// =====================================================================
__global__ __launch_bounds__(256)
void prep_kernel(const float* __restrict__ Wq, const float* __restrict__ kvl_pw,
                 const float* __restrict__ proj_w, const float* __restrict__ sr_w,
                 const float* __restrict__ x,
                 ushort_t* __restrict__ wqt, ushort_t* __restrict__ pwt,
                 ushort_t* __restrict__ projt, float* __restrict__ srwt,
                 ushort_t* __restrict__ xbf) {
    int idx = blockIdx.x * 256 + threadIdx.x;
    if (idx < 262144) {
        int n = idx >> 9, k = idx & 511;
        wqt[idx] = bf16r(Wq[(size_t)k * 512 + n]);
    } else if (idx < 491520) {
        int i = idx - 262144;
        int n = i / 448, k = i % 448;
        float v = (n < 448) ? kvl_pw[(size_t)n * 448 + k] : 0.f;
        pwt[i] = bf16r(v);
    } else if (idx < 753664) {
        int i = idx - 491520;
        int n = i >> 9, k = i & 511;
        projt[i] = bf16r(proj_w[(size_t)k * 512 + n]);
    } else if (idx < 770048) {
        int i = idx - 753664;
        int f = i >> 6, o2 = i & 63;
        srwt[i] = sr_w[o2 * 256 + f];
    } else {
        int i = idx - 770048;
        const float4v* p = (const float4v*)(x + (size_t)i * 8);
        float4v a = p[0], b = p[1];
        uint4v u;
        u[0] = pack_bf16(a[0], a[1]);
        u[1] = pack_bf16(a[2], a[3]);
        u[2] = pack_bf16(b[0], b[1]);
        u[3] = pack_bf16(b[2], b[3]);
        *(uint4v*)(xbf + (size_t)i * 8) = u;
    }
}

// =====================================================================
// FUSED3: [0,784) q-GEMM | [784,3528) dwt | [3528,5096) srlnkv x4
// single 32KB LDS union across branches (occupancy-friendly)
// =====================================================================
__global__ __launch_bounds__(256, 2)
void fused3_kernel(const ushort_t* __restrict__ xbf, const ushort_t* __restrict__ wqt,
                   ushort_t* __restrict__ q16,
                   const float* __restrict__ kvl_dw, const float* __restrict__ kvl_db,
                   ushort_t* __restrict__ dwtb,
                   const float* __restrict__ x, const float* __restrict__ srwt,
                   const float* __restrict__ sr_b, const float* __restrict__ ln_g,
                   const float* __restrict__ ln_b, const float* __restrict__ wkv,
                   ushort_t* __restrict__ kgb, float* __restrict__ vg) {
    const int bid = blockIdx.x;
    const int tid = threadIdx.x;
    __shared__ __align__(16) char smem[32768];

    if (bid < 784) {
        ushort_t* As = (ushort_t*)smem;
        ushort_t* Bs = (ushort_t*)(smem + 16384);
        const int bm = (bid % 196) * 128;
        const int bn = (bid / 196) * 128;
        const int l15 = tid & 15;
        const int g   = (tid & 63) >> 4;
        const int w   = tid >> 6;
        const int wr  = w >> 1, wc = w & 1;
        float4v acc[4][4];
        #pragma unroll
        for (int m = 0; m < 4; ++m)
            #pragma unroll
            for (int n = 0; n < 4; ++n) acc[m][n] = (float4v){0.f, 0.f, 0.f, 0.f};
        for (int k0 = 0; k0 < 512; k0 += 64) {
            #pragma unroll
            for (int i = 0; i < 4; ++i) {
                int c = i * 256 + tid;
                int r = c >> 3, ch = c & 7;
                int sch = ch ^ (r & 7);
                gload16(xbf + (size_t)(bm + r) * 512 + k0 + sch * 8, (void*)(As + c * 8));
                gload16(wqt + (size_t)(bn + r) * 512 + k0 + sch * 8, (void*)(Bs + c * 8));
            }
            __syncthreads();
            short8_t af[4][2], bfr[4][2];
            #pragma unroll
            for (int m = 0; m < 4; ++m) {
                int ar = wr * 64 + m * 16 + l15;
                #pragma unroll
                for (int h = 0; h < 2; ++h)
                    af[m][h] = *(const short8_t*)((const char*)As + ar * 128 + (((h * 4 + g) ^ (ar & 7)) * 16));
            }
            #pragma unroll
            for (int n = 0; n < 4; ++n) {
                int br = wc * 64 + n * 16 + l15;
                #pragma unroll
                for (int h = 0; h < 2; ++h)
                    bfr[n][h] = *(const short8_t*)((const char*)Bs + br * 128 + (((h * 4 + g) ^ (br & 7)) * 16));
            }
            #pragma unroll
            for (int m = 0; m < 4; ++m)
                #pragma unroll
                for (int n = 0; n < 4; ++n) {
                    acc[m][n] = __builtin_amdgcn_mfma_f32_16x16x32_bf16(af[m][0], bfr[n][0], acc[m][n], 0, 0, 0);
                    acc[m][n] = __builtin_amdgcn_mfma_f32_16x16x32_bf16(af[m][1], bfr[n][1], acc[m][n], 0, 0, 0);
                }
            __syncthreads();
        }
        #pragma unroll
        for (int n = 0; n < 4; ++n) {
            int ccol = bn + wc * 64 + n * 16 + l15;
            #pragma unroll
            for (int m = 0; m < 4; ++m) {
                int crow = bm + wr * 64 + m * 16 + g * 4;
                #pragma unroll
                for (int j = 0; j < 4; ++j)
                    q16[(size_t)(crow + j) * 512 + ccol] = bf16r(acc[m][n][j]);
            }
        }
    } else if (bid < 3528) {
        int idx = (bid - 784) * 256 + tid;
        int c4 = idx % 112;
        int t1 = idx / 112;
        int xx = t1 % 112;
        int t2 = t1 / 112;
        int yg = t2 % 28;
        int b  = t2 / 28;
        int c0 = c4 * 4;
        int y0 = yg * 4;
        float4v w4[9];
        #pragma unroll
        for (int kt = 0; kt < 9; ++kt) {
            w4[kt][0] = kvl_dw[(c0 + 0) * 9 + kt];
            w4[kt][1] = kvl_dw[(c0 + 1) * 9 + kt];
            w4[kt][2] = kvl_dw[(c0 + 2) * 9 + kt];
            w4[kt][3] = kvl_dw[(c0 + 3) * 9 + kt];
        }
        float4v bv = *(const float4v*)(kvl_db + c0);
        float4v acc[4];
        #pragma unroll
        for (int o2 = 0; o2 < 4; ++o2) acc[o2] = bv;
        #pragma unroll
        for (int yy = 0; yy < 6; ++yy) {
            int Y = y0 - 1 + yy;
            if (Y < 0 || Y >= Himg) continue;
            #pragma unroll
            for (int xt = 0; xt < 3; ++xt) {
                int X = xx - 1 + xt;
                if (X < 0 || X >= Wimg) continue;
                uint2v q2 = *(const uint2v*)(xbf + ((size_t)b * N_ + Y * Wimg + X) * DIM_ + D0_ + c0);
                float4v v;
                v[0] = bf16tof((ushort_t)(q2[0] & 0xffffu));
                v[1] = bf16tof((ushort_t)(q2[0] >> 16));
                v[2] = bf16tof((ushort_t)(q2[1] & 0xffffu));
                v[3] = bf16tof((ushort_t)(q2[1] >> 16));
                constexpr int olo_t[6] = {0, 0, 0, 1, 2, 3};
                constexpr int ohi_t[6] = {0, 1, 2, 3, 3, 3};
                #pragma unroll
                for (int o2 = olo_t[yy]; o2 <= ohi_t[yy]; ++o2) {
                    float4v wv = w4[(yy - o2) * 3 + xt];
                    acc[o2][0] += v[0] * wv[0];
                    acc[o2][1] += v[1] * wv[1];
                    acc[o2][2] += v[2] * wv[2];
                    acc[o2][3] += v[3] * wv[3];
                }
            }
        }
        #pragma unroll
        for (int o2 = 0; o2 < 4; ++o2) {
            uint2v pk;
            pk[0] = pack_bf16(acc[o2][0], acc[o2][1]);
            pk[1] = pack_bf16(acc[o2][2], acc[o2][3]);
            *(uint2v*)(dwtb + ((size_t)b * N_ + (y0 + o2) * Wimg + xx) * DL_ + c0) = pk;
        }
    } else {
        // srlnkv: 4 positions per block; LDS overlays smem
        float* xs    = (float*)smem;            // [grp*256 + tap*64 + o], 4KB
        float* lnv_s = (float*)(smem + 4096);   // [grp*64 + o], 1KB
        const int blk4 = bid - 3528;
        const int grp  = tid >> 6;
        const int o    = tid & 63;
        const int pos  = blk4 * 4 + grp;
        const int b = pos / NR_, n = pos % NR_;
        const int y = n / HS_, xx = n % HS_;
        #pragma unroll
        for (int tap = 0; tap < 4; ++tap) {
            int ky = tap / 2, kx = tap % 2;
            xs[grp * 256 + tap * 64 + o] =
                x[((size_t)b * N_ + (2 * y + ky) * Wimg + 2 * xx + kx) * DIM_ + o];
        }
        __syncthreads();
        float sum = sr_b[o];
        for (int i = 0; i < 64; ++i) {
            const float* wr = srwt + (i * 4) * 64 + o;
            sum += xs[grp * 256 + 0 * 64 + i] * wr[0] + xs[grp * 256 + 1 * 64 + i] * wr[64]
                 + xs[grp * 256 + 2 * 64 + i] * wr[128] + xs[grp * 256 + 3 * 64 + i] * wr[192];
        }
        float m = sum;
        #pragma unroll
        for (int off = 1; off < 64; off <<= 1) m += __shfl_xor(m, off);
        m *= (1.0f / 64.0f);
        float d = sum - m;
        float v = d * d;
        #pragma unroll
        for (int off = 1; off < 64; off <<= 1) v += __shfl_xor(v, off);
        v *= (1.0f / 64.0f);
        float lnv = d * rsqrtf(v + 1e-5f) * ln_g[o] + ln_b[o];
        lnv_s[grp * 64 + o] = lnv;
        __syncthreads();
        float s0 = 0.f, s1 = 0.f;
        for (int i = 0; i < 64; ++i) {
            float lv = lnv_s[grp * 64 + i];
            s0 += lv * wkv[i * 128 + o];
            s1 += lv * wkv[i * 128 + o + 64];
        }
        const float SCK = 0.125f * 1.44269504088896340736f;
        kgb[((size_t)b * NR_ + n) * 64 + o] = bf16r(s0 * SCK);
        vg[((size_t)b * NR_ + n) * 64 + o] = s1;
    }
}

// =====================================================================
// FUSED2: [0,784) pointwise GEMM -> kvl16 | [784,882) lcg+vtrans
// single 32KB LDS union
// =====================================================================
__global__ __launch_bounds__(256, 2)
void fused2_kernel(const ushort_t* __restrict__ dwtb, const ushort_t* __restrict__ pwt,
                   const float* __restrict__ kvl_pb, ushort_t* __restrict__ kvl16,
                   const float* __restrict__ vg, const float* __restrict__ lcg_w,
                   const float* __restrict__ lcg_b, ushort_t* __restrict__ vtb) {
    const int bid = blockIdx.x;
    const int tid = threadIdx.x;
    __shared__ __align__(16) char smem[32768];

    if (bid < 784) {
        ushort_t* As = (ushort_t*)smem;
        ushort_t* Bs = (ushort_t*)(smem + 16384);
        const int bm = (bid % 196) * 128;
        const int bn = (bid / 196) * 128;
        const int l15 = tid & 15;
        const int g   = (tid & 63) >> 4;
        const int w   = tid >> 6;
        const int wr  = w >> 1, wc = w & 1;
        float4v acc[4][4];
        #pragma unroll
        for (int m = 0; m < 4; ++m)
            #pragma unroll
            for (int n = 0; n < 4; ++n) acc[m][n] = (float4v){0.f, 0.f, 0.f, 0.f};
        for (int k0 = 0; k0 < 448; k0 += 64) {
            #pragma unroll
            for (int i = 0; i < 4; ++i) {
                int c = i * 256 + tid;
                int r = c >> 3, ch = c & 7;
                int sch = ch ^ (r & 7);
                gload16(dwtb + (size_t)(bm + r) * 448 + k0 + sch * 8, (void*)(As + c * 8));
                gload16(pwt  + (size_t)(bn + r) * 448 + k0 + sch * 8, (void*)(Bs + c * 8));
            }
            __syncthreads();
            short8_t af[4][2], bfr[4][2];
            #pragma unroll
            for (int m = 0; m < 4; ++m) {
                int ar = wr * 64 + m * 16 + l15;
                #pragma unroll
                for (int h = 0; h < 2; ++h)
                    af[m][h] = *(const short8_t*)((const char*)As + ar * 128 + (((h * 4 + g) ^ (ar & 7)) * 16));
            }
            #pragma unroll
            for (int n = 0; n < 4; ++n) {
                int br = wc * 64 + n * 16 + l15;
                #pragma unroll
                for (int h = 0; h < 2; ++h)
                    bfr[n][h] = *(const short8_t*)((const char*)Bs + br * 128 + (((h * 4 + g) ^ (br & 7)) * 16));
            }
            #pragma unroll
            for (int m = 0; m < 4; ++m)
                #pragma unroll
                for (int n = 0; n < 4; ++n) {
                    acc[m][n] = __builtin_amdgcn_mfma_f32_16x16x32_bf16(af[m][0], bfr[n][0], acc[m][n], 0, 0, 0);
                    acc[m][n] = __builtin_amdgcn_mfma_f32_16x16x32_bf16(af[m][1], bfr[n][1], acc[m][n], 0, 0, 0);
                }
            __syncthreads();
        }
        #pragma unroll
        for (int n = 0; n < 4; ++n) {
            int ccol = bn + wc * 64 + n * 16 + l15;
            if (ccol < 448) {
                float bv = kvl_pb[ccol];
                #pragma unroll
                for (int m = 0; m < 4; ++m) {
                    int crow = bm + wr * 64 + m * 16 + g * 4;
                    #pragma unroll
                    for (int j = 0; j < 4; ++j)
                        kvl16[(size_t)(crow + j) * 448 + ccol] = bf16r(acc[m][n][j] + bv);
                }
            }
        }
    } else {
        float* ld = (float*)smem;   // [n*65 + c], 64*65*4 = 16.6KB
        const int lb = bid - 784;
        const int b = lb / 49, n0 = (lb % 49) * 64;
        #pragma unroll
        for (int i = 0; i < 16; ++i) {
            int idx = i * 256 + tid;
            int n = idx >> 6, c = idx & 63;
            int nn = n0 + n;
            int y = nn / HS_, xx = nn % HS_;
            float sum = vg[((size_t)b * NR_ + nn) * 64 + c] + lcg_b[c];
            #pragma unroll
            for (int ky = 0; ky < 3; ++ky)
                #pragma unroll
                for (int kx = 0; kx < 3; ++kx) {
                    int yy = y + ky - 1, x2 = xx + kx - 1;
                    if (yy >= 0 && yy < HS_ && x2 >= 0 && x2 < HS_)
                        sum += vg[((size_t)b * NR_ + yy * HS_ + x2) * 64 + c] * lcg_w[c * 9 + ky * 3 + kx];
                }
            ld[n * 65 + c] = sum;
        }
        __syncthreads();
        #pragma unroll
        for (int i = 0; i < 16; ++i) {
            int idx = i * 256 + tid;
            int d = idx >> 6, nn = idx & 63;
            vtb[(size_t)(b * 64 + d) * NR_ + n0 + nn] = bf16r(ld[nn * 65 + d]);
        }
    }
}

// =====================================================================
// "scrambled mean" body (bf16 kvl), shared mem passed in
// =====================================================================
template<int L, int NBW, int STRIDE, int DIL, int CHOFF>
__device__ inline void lm_body(int blk, int t, float* slo, float* shi,
                               const ushort_t* __restrict__ kvl16,
                               float* __restrict__ kvm) {
    const int n = blk % 49;
    const int h = (blk / 49) % NH_;
    const int b = blk / (49 * NH_);
    const int wy = n / 7, wx = n % 7;

    if (t < L) {
        const int by = t / NBW, bx = t % NBW;
        int Y = by * STRIDE + DIL * wy;
        int X = bx * STRIDE + DIL * wx;
        if (Y >= Himg) Y = 2 * Himg - 2 - Y;
        if (X >= Wimg) X = 2 * Wimg - 2 - X;
        const ushort_t* src = kvl16 + ((size_t)b * N_ + Y * Wimg + X) * DL_ + CHOFF + h * HD_;
        float v[28];
        #pragma unroll
        for (int i = 0; i < 7; ++i) {
            uint2v q2 = ((const uint2v*)src)[i];
            v[i * 4]     = bf16tof((ushort_t)(q2[0] & 0xffffu));
            v[i * 4 + 1] = bf16tof((ushort_t)(q2[0] >> 16));
            v[i * 4 + 2] = bf16tof((ushort_t)(q2[1] & 0xffffu));
            v[i * 4 + 3] = bf16tof((ushort_t)(q2[1] >> 16));
        }
        const int f0 = t * HD_;
        const int bin0 = f0 / L;
        const int nlo = min(HD_, (bin0 + 1) * L - f0);
        float s0 = 0.f, s1 = 0.f;
        #pragma unroll
        for (int j = 0; j < HD_; ++j) {
            if (j < nlo) s0 += v[j]; else s1 += v[j];
        }
        slo[t] = s0;
        shi[t] = s1;
    }
    __syncthreads();
    if (t < HD_) {
        const int t_lo = (t * L) / HD_;
        const int t_hi = min(L - 1, (t * L + L - 1) / HD_);
        float sum = 0.f;
        for (int u = t_lo; u <= t_hi; ++u) {
            int f0 = u * HD_;
            int b0 = f0 / L;
            int b1 = (f0 + HD_ - 1) / L;
            if (b0 == t) sum += slo[u];
            if (b1 == t && b1 != b0) sum += shi[u];
        }
        kvm[(size_t)blk * HD_ + t] = sum * (1.0f / (float)L);
    }
}

// =====================================================================
// FUSED attn_global + local_mean (32KB LDS union)
// [0,1568): attn_global (512 thr); [1568,3136): lm
// =====================================================================
__global__ __launch_bounds__(512)
void fused_ag_lm_kernel(const ushort_t* __restrict__ q16,
                        const ushort_t* __restrict__ kgb,
                        const ushort_t* __restrict__ vtb,
                        ushort_t* __restrict__ osp16, float* __restrict__ mls,
                        const ushort_t* __restrict__ kvl16,
                        float* __restrict__ kvm1, float* __restrict__ kvm2) {
    const int bid = blockIdx.x;
    const int tid = threadIdx.x;
    __shared__ __align__(16) char smem[32768];
    ushort_t* Ks = (ushort_t*)smem;
    ushort_t* Vs = (ushort_t*)(smem + 16384);

    if (bid >= 1568) {
        float* slo = (float*)smem;            // up to 256 floats
        float* shi = (float*)(smem + 1024);
        int lmid = bid - 1568;
        int blk = lmid % 784;
        if (lmid < 784) lm_body<256, 16, 7, 1, 0>(blk, tid, slo, shi, kvl16, kvm1);
        else            lm_body<81, 9, 13, 2, 224>(blk, tid, slo, shi, kvl16, kvm2);
        return;
    }

    const int split = (bid / 98) & 7;
    const int b     = (bid / 98) >> 3;
    const int q0    = (bid % 98) * 128;
    const int w     = tid >> 6;
    const int l     = tid & 63;
    const int l15   = l & 15;
    const int g     = l >> 4;
    const int lx    = l15 & 7;

    short8_t qf[2];
    {
        const ushort_t* qrow = q16 + ((size_t)b * N_ + q0 + w * 16 + l15) * DIM_;
        qf[0] = *(const short8_t*)(qrow + g * 8);
        qf[1] = *(const short8_t*)(qrow + g * 8 + 32);
    }

    float4v o[4];
    #pragma unroll
    for (int i = 0; i < 4; ++i) o[i] = (float4v){0.f, 0.f, 0.f, 0.f};
    float m_run = -3.0e38f, l_run = 0.f;

    const int stg_r   = tid >> 3;
    const int stg_sch = (tid & 7) ^ (stg_r & 7);
    const int stg_pr  = (stg_r & 32) | (((stg_r >> 2) & 3) << 3) | (((stg_r >> 4) & 1) << 2) | (stg_r & 3);
    auto stage = [&](int t, int buf) {
        const int k0 = t * 64;
        gload16(kgb + ((size_t)(b * NR_ + k0 + stg_pr) << 6) + stg_sch * 8,
                (void*)(Ks + buf * 4096 + tid * 8));
        gload16(vtb + (size_t)(b * 64 + stg_r) * NR_ + k0 + stg_sch * 8,
                (void*)(Vs + buf * 4096 + tid * 8));
    };

    auto compute = [&](const ushort_t* Kb, const ushort_t* Vb) {
        float4v sc[4];
        #pragma unroll
        for (int c = 0; c < 4; ++c) {
            float4v acc = (float4v){0.f, 0.f, 0.f, 0.f};
            #pragma unroll
            for (int dc = 0; dc < 2; ++dc) {
                int row = c * 16 + l15;
                short8_t ak = *(const short8_t*)((const char*)Kb + row * 128 + (((g + 4 * dc) ^ lx) * 16));
                acc = __builtin_amdgcn_mfma_f32_16x16x32_bf16(ak, qf[dc], acc, 0, 0, 0);
            }
            sc[c] = acc;
        }

        float tmax = fmaxf(fmaxf(fmaxf(sc[0][0], sc[0][1]), fmaxf(sc[0][2], sc[0][3])),
                           fmaxf(fmaxf(sc[1][0], sc[1][1]), fmaxf(sc[1][2], sc[1][3])));
        tmax = fmaxf(tmax, fmaxf(fmaxf(fmaxf(sc[2][0], sc[2][1]), fmaxf(sc[2][2], sc[2][3])),
                                 fmaxf(fmaxf(sc[3][0], sc[3][1]), fmaxf(sc[3][2], sc[3][3]))));

        if (__any(tmax > m_run + 11.0f)) {
            float rmax = fmaxf(tmax, __shfl_xor(tmax, 16));
            rmax = fmaxf(rmax, __shfl_xor(rmax, 32));
            float m_new = fmaxf(m_run, rmax);
            float corr = __builtin_amdgcn_exp2f(m_run - m_new);
            float co[4];
            #pragma unroll
            for (int r = 0; r < 4; ++r) co[r] = __shfl(corr, g * 4 + r);
            #pragma unroll
            for (int dc = 0; dc < 4; ++dc)
                #pragma unroll
                for (int r = 0; r < 4; ++r) o[dc][r] *= co[r];
            l_run *= corr;
            m_run = m_new;
        }

        float p[4][4];
        float ladd = 0.f;
        #pragma unroll
        for (int c = 0; c < 4; ++c)
            #pragma unroll
            for (int r = 0; r < 4; ++r) {
                float pe = __builtin_amdgcn_exp2f(sc[c][r] - m_run);
                p[c][r] = pe;
                ladd += pe;
            }
        l_run += ladd;

        #pragma unroll
        for (int kkc = 0; kkc < 2; ++kkc) {
            uint4v au;
            au[0] = cvtpk(p[2 * kkc][0],     p[2 * kkc][1]);
            au[1] = cvtpk(p[2 * kkc][2],     p[2 * kkc][3]);
            au[2] = cvtpk(p[2 * kkc + 1][0], p[2 * kkc + 1][1]);
            au[3] = cvtpk(p[2 * kkc + 1][2], p[2 * kkc + 1][3]);
            short8_t ap = __builtin_bit_cast(short8_t, au);
            #pragma unroll
            for (int dc = 0; dc < 4; ++dc) {
                int vrow = dc * 16 + l15;
                short8_t bv = *(const short8_t*)((const char*)Vb + vrow * 128 + (((kkc * 4 + g) ^ lx) * 16));
                o[dc] = __builtin_amdgcn_mfma_f32_16x16x32_bf16(ap, bv, o[dc], 0, 0, 0);
            }
        }
    };

    const int t0 = (split * 49) / 8;
    const int t1 = ((split + 1) * 49) / 8;
    int t = t0;
    for (; t + 1 < t1; t += 2) {
        stage(t, 0);
        stage(t + 1, 1);
        __syncthreads();
        compute(Ks, Vs);
        compute(Ks + 4096, Vs + 4096);
        __syncthreads();
    }
    if (t < t1) {
        stage(t, 0);
        __syncthreads();
        compute(Ks, Vs);
    }

    float l_tot = l_run;
    l_tot += __shfl_xor(l_tot, 16);
    l_tot += __shfl_xor(l_tot, 32);

    const size_t rbase = (size_t)(split * B_ + b) * N_;
    #pragma unroll
    for (int dc = 0; dc < 4; ++dc)
        #pragma unroll
        for (int r = 0; r < 4; ++r) {
            int row = q0 + w * 16 + g * 4 + r;
            osp16[(rbase + row) * 64 + dc * 16 + l15] = bf16r(o[dc][r]);
        }
    if (l < 16) {
        int row = q0 + w * 16 + l15;
        mls[(rbase + row) * 2]     = m_run;
        mls[(rbase + row) * 2 + 1] = l_tot;
    }
}

// =====================================================================
// merged fc@sh for both branches
// =====================================================================
__global__ __launch_bounds__(64)
void fcsh_merged_kernel(const float* __restrict__ kvm1, const float* __restrict__ fc1w,
                        const float* __restrict__ sh1w, float* __restrict__ kv1,
                        const float* __restrict__ kvm2, const float* __restrict__ fc2w,
                        const float* __restrict__ sh2w, float* __restrict__ kv2) {
    int bh2 = blockIdx.x;
    const float* kvm = (bh2 < 16) ? kvm1 : kvm2;
    const float* fcw = (bh2 < 16) ? fc1w : fc2w;
    const float* shw = (bh2 < 16) ? sh1w : sh2w;
    float* outp      = (bh2 < 16) ? kv1 : kv2;
    int bh = (bh2 < 16) ? bh2 : bh2 - 16;
    __shared__ float kin[49][28];
    __shared__ float tmp[49][28];
    __shared__ float fw[28 * 28];
    __shared__ float sw[28 * 56];
    int t = threadIdx.x;
    for (int i = t; i < 49 * 28; i += 64) kin[i / 28][i % 28] = kvm[bh * 49 * 28 + i];
    for (int i = t; i < 28 * 28; i += 64) fw[i] = fcw[i];
    for (int i = t; i < 28 * 56; i += 64) sw[i] = shw[i];
    __syncthreads();
    for (int i = t; i < 49 * 28; i += 64) {
        int rr = i / 28, j = i % 28;
        float s = 0.f;
        for (int k = 0; k < 28; ++k) s += kin[rr][k] * fw[k * 28 + j];
        tmp[rr][j] = s;
    }
    __syncthreads();
    for (int i = t; i < 49 * 56; i += 64) {
        int rr = i / 56, j = i % 56;
        float s = 0.f;
        for (int k = 0; k < 28; ++k) s += tmp[rr][k] * sw[k * 56 + j];
        outp[bh * 49 * 56 + i] = s;
    }
}

// =====================================================================
// merged v-conv for both branches
// =====================================================================
__global__ __launch_bounds__(256)
void vconv_merged_kernel(const float* __restrict__ kv1, const float* __restrict__ lc1w,
                         const float* __restrict__ lc1b, float* __restrict__ v1c,
                         const float* __restrict__ kv2, const float* __restrict__ lc2w,
                         const float* __restrict__ lc2b, float* __restrict__ v2c) {
    const float* kvsh = (blockIdx.y == 0) ? kv1 : kv2;
    const float* w    = (blockIdx.y == 0) ? lc1w : lc2w;
    const float* bias = (blockIdx.y == 0) ? lc1b : lc2b;
    float* vc         = (blockIdx.y == 0) ? v1c : v2c;
    int idx = blockIdx.x * 256 + threadIdx.x;
    if (idx >= B_ * NH_ * 49 * HD_) return;
    int d  = idx % HD_;
    int n  = (idx / HD_) % 49;
    int bh = idx / (HD_ * 49);
    int h  = bh % NH_;
    int y = n / 7, xx = n % 7;
    int c = h * HD_ + d;
    float sum = kvsh[(bh * 49 + n) * 56 + 28 + d] + bias[c];
    #pragma unroll
    for (int ky = 0; ky < 3; ++ky)
        #pragma unroll
        for (int kx = 0; kx < 3; ++kx) {
            int yy = y + ky - 1, x2 = xx + kx - 1;
            if (yy >= 0 && yy < 7 && x2 >= 0 && x2 < 7)
                sum += kvsh[(bh * 49 + yy * 7 + x2) * 56 + 28 + d] * w[c * 9 + ky * 3 + kx];
        }
    vc[idx] = sum;
}

// =====================================================================
// FUSED attn_local + combine
// [0,6272): attn_local; [6272,12544): combine
// =====================================================================
__global__ __launch_bounds__(256)
void fused_local_comb_kernel(const ushort_t* __restrict__ q16,
                             const float* __restrict__ kv1, const float* __restrict__ v1c,
                             const float* __restrict__ kv2, const float* __restrict__ v2c,
                             const ushort_t* __restrict__ osp16, const float* __restrict__ mls,
                             ushort_t* __restrict__ catb) {
    const int bid = blockIdx.x;
    const int tid = threadIdx.x;
    __shared__ __align__(16) ushort_t Ks[64 * 32];
    __shared__ __align__(16) ushort_t Vt[32 * 64];

    if (bid >= 6272) {
        int idx = (bid - 6272) * 256 + tid;
        int col = idx & 63;
        size_t rn = (size_t)(idx >> 6);
        const size_t BN = (size_t)B_ * N_;
        float ms[NSPLIT], ls[NSPLIT];
        float m = -3.0e38f;
        #pragma unroll
        for (int s = 0; s < NSPLIT; ++s) {
            ms[s] = mls[(s * BN + rn) * 2];
            ls[s] = mls[(s * BN + rn) * 2 + 1];
            m = fmaxf(m, ms[s]);
        }
        float lsum = 0.f, acc = 0.f;
        #pragma unroll
        for (int s = 0; s < NSPLIT; ++s) {
            float wgt = __builtin_amdgcn_exp2f(ms[s] - m);
            lsum += ls[s] * wgt;
            acc  += bf16tof(osp16[(s * BN + rn) * 64 + col]) * wgt;
        }
        catb[rn * DIM_ + col] = bf16r(acc / lsum);
        return;
    }

    const int ybh    = bid / 196;
    const int branch = ybh & 1;
    const int bh     = ybh >> 1;
    const int b      = bh >> 3, h = bh & 7;
    const int q0     = (bid % 196) * 64;
    const int w      = tid >> 6;
    const int l      = tid & 63;
    const int l15    = l & 15;
    const int g      = l >> 4;
    const float SC2K = 0.1889822365046136f * 1.44269504088896340736f;

    const float* kvsh = branch ? kv2 : kv1;
    const float* vc   = branch ? v2c : v1c;
    const int qoff    = D0_ + h * 56 + branch * 28;
    const int outoff  = (branch ? D0_ + 224 : D0_) + h * HD_;

    {
        int row = tid >> 2, lc = tid & 3;
        int pr = (row & 32) | (((row >> 2) & 3) << 3) | (((row >> 4) & 1) << 2) | (row & 3);
        uint4v u = (uint4v){0u, 0u, 0u, 0u};
        if (pr < 49) {
            const float* src = kvsh + (bh * 49 + pr) * 56 + lc * 8;
            float vv[8];
            #pragma unroll
            for (int j2 = 0; j2 < 8; ++j2)
                vv[j2] = (lc * 8 + j2 < 28) ? src[j2] * SC2K : 0.f;
            u[0] = cvtpk(vv[0], vv[1]);
            u[1] = cvtpk(vv[2], vv[3]);
            u[2] = cvtpk(vv[4], vv[5]);
            u[3] = cvtpk(vv[6], vv[7]);
        }
        *(uint4v*)(Ks + row * 32 + (lc ^ (row & 3)) * 8) = u;
    }
    {
        int row = tid >> 3, lc = tid & 7;
        uint4v u = (uint4v){0u, 0u, 0u, 0u};
        if (row < 28) {
            float vv[8];
            #pragma unroll
            for (int j2 = 0; j2 < 8; ++j2) {
                int kc = lc * 8 + j2;
                vv[j2] = (kc < 49) ? vc[(bh * 49 + kc) * 28 + row] : 0.f;
            }
            u[0] = cvtpk(vv[0], vv[1]);
            u[1] = cvtpk(vv[2], vv[3]);
            u[2] = cvtpk(vv[4], vv[5]);
            u[3] = cvtpk(vv[6], vv[7]);
        }
        *(uint4v*)(Vt + row * 64 + (lc ^ (row & 7)) * 8) = u;
    }
    short8_t qf;
    {
        const ushort_t* qp = q16 + ((size_t)b * N_ + q0 + w * 16 + l15) * DIM_ + qoff + g * 8;
        uint2v a01 = *(const uint2v*)qp;
        uint2v a23 = (g < 3) ? *(const uint2v*)(qp + 4) : (uint2v){0u, 0u};
        uint4v uv;
        uv[0] = a01[0]; uv[1] = a01[1]; uv[2] = a23[0]; uv[3] = a23[1];
        qf = __builtin_bit_cast(short8_t, uv);
    }
    __syncthreads();

    float4v sc4[4];
    #pragma unroll
    for (int c = 0; c < 4; ++c) {
        int row = c * 16 + l15;
        short8_t ak = *(const short8_t*)(Ks + row * 32 + ((g ^ (row & 3)) * 8));
        float4v acc = (float4v){0.f, 0.f, 0.f, 0.f};
        sc4[c] = __builtin_amdgcn_mfma_f32_16x16x32_bf16(ak, qf, acc, 0, 0, 0);
    }

    float tmax = fmaxf(fmaxf(fmaxf(sc4[0][0], sc4[0][1]), fmaxf(sc4[0][2], sc4[0][3])),
                       fmaxf(fmaxf(sc4[1][0], sc4[1][1]), fmaxf(sc4[1][2], sc4[1][3])));
    tmax = fmaxf(tmax, fmaxf(fmaxf(fmaxf(sc4[2][0], sc4[2][1]), fmaxf(sc4[2][2], sc4[2][3])),
                             fmaxf(fmaxf(sc4[3][0], sc4[3][1]), fmaxf(sc4[3][2], sc4[3][3]))));
    tmax = fmaxf(tmax, __shfl_xor(tmax, 16));
    tmax = fmaxf(tmax, __shfl_xor(tmax, 32));

    float p[4][4];
    float lsum = 0.f;
    #pragma unroll
    for (int c = 0; c < 4; ++c)
        #pragma unroll
        for (int r = 0; r < 4; ++r) {
            float pe = __builtin_amdgcn_exp2f(sc4[c][r] - tmax);
            if (c >= 2 && (8 * g + 4 * (c & 1) + r) >= 17) pe = 0.f;
            p[c][r] = pe;
            lsum += pe;
        }
    lsum += __shfl_xor(lsum, 16);
    lsum += __shfl_xor(lsum, 32);
    float inv = 1.0f / lsum;

    float4v o2[2];
    o2[0] = (float4v){0.f, 0.f, 0.f, 0.f};
    o2[1] = (float4v){0.f, 0.f, 0.f, 0.f};
    #pragma unroll
    for (int kkc = 0; kkc < 2; ++kkc) {
        uint4v au;
        au[0] = cvtpk(p[2 * kkc][0],     p[2 * kkc][1]);
        au[1] = cvtpk(p[2 * kkc][2],     p[2 * kkc][3]);
        au[2] = cvtpk(p[2 * kkc + 1][0], p[2 * kkc + 1][1]);
        au[3] = cvtpk(p[2 * kkc + 1][2], p[2 * kkc + 1][3]);
        short8_t ap = __builtin_bit_cast(short8_t, au);
        #pragma unroll
        for (int dc = 0; dc < 2; ++dc) {
            int vrow = dc * 16 + l15;
            short8_t bv = *(const short8_t*)(Vt + vrow * 64 + (((kkc * 4 + g) ^ (vrow & 7)) * 8));
            o2[dc] = __builtin_amdgcn_mfma_f32_16x16x32_bf16(ap, bv, o2[dc], 0, 0, 0);
        }
    }

    float irow[4];
    #pragma unroll
    for (int r = 0; r < 4; ++r) irow[r] = __shfl(inv, g * 4 + r);
    #pragma unroll
    for (int dc = 0; dc < 2; ++dc) {
        int d = dc * 16 + l15;
        if (d < 28) {
            #pragma unroll
            for (int r = 0; r < 4; ++r) {
                int row = q0 + w * 16 + g * 4 + r;
                catb[((size_t)b * N_ + row) * DIM_ + outoff + d] = bf16r(o2[dc][r] * irow[r]);
            }
        }
    }
}

// =====================================================================
extern "C" void kernel_launch(void* const* d_in, const int* in_sizes, int n_in,
                              void* d_out, int out_size, void* d_ws, size_t ws_size,
                              hipStream_t stream) {
    const float* x      = (const float*)d_in[0];
    const float* Wq     = (const float*)d_in[1];
    const float* Wkv_g  = (const float*)d_in[2];
    const float* sr_w   = (const float*)d_in[3];
    const float* sr_b   = (const float*)d_in[4];
    const float* ln_g   = (const float*)d_in[5];
    const float* ln_b   = (const float*)d_in[6];
    const float* lcg_w  = (const float*)d_in[7];
    const float* lcg_b  = (const float*)d_in[8];
    const float* kvl_dw = (const float*)d_in[9];
    const float* kvl_db = (const float*)d_in[10];
    const float* kvl_pw = (const float*)d_in[11];
    const float* kvl_pb = (const float*)d_in[12];
    const float* fc1_w  = (const float*)d_in[13];
    const float* sh1_w  = (const float*)d_in[14];
    const float* lc1_w  = (const float*)d_in[15];
    const float* lc1_b  = (const float*)d_in[16];
    const float* fc2_w  = (const float*)d_in[17];
    const float* sh2_w  = (const float*)d_in[18];
    const float* lc2_w  = (const float*)d_in[19];
    const float* lc2_b  = (const float*)d_in[20];
    const float* proj_w = (const float*)d_in[21];
    const float* proj_b = (const float*)d_in[22];
    float* out = (float*)d_out;
    char* base = (char*)d_ws;

    size_t o = 0;
    auto alloc = [&](size_t bytes) -> void* {
        void* p = base + o;
        o = (o + bytes + 255) & ~(size_t)255;
        return p;
    };
    ushort_t* q16   = (ushort_t*)alloc((size_t)B_ * N_ * DIM_ * 2);
    ushort_t* kvl16 = (ushort_t*)alloc((size_t)B_ * N_ * DL_ * 2);
    ushort_t* osp16 = (ushort_t*)alloc((size_t)NSPLIT * B_ * N_ * 64 * 2);
    float*    mls   = (float*)   alloc((size_t)NSPLIT * B_ * N_ * 2 * 4);
    ushort_t* xcat  = (ushort_t*)alloc((size_t)B_ * N_ * DIM_ * 2);  // xbf, then cat
    ushort_t* dwtb  = (ushort_t*)alloc((size_t)B_ * N_ * DL_ * 2);
    ushort_t* kgb   = (ushort_t*)alloc((size_t)B_ * NR_ * 64 * 2);
    float*    vg    = (float*)   alloc((size_t)B_ * NR_ * 64 * 4);
    ushort_t* vtb   = (ushort_t*)alloc((size_t)B_ * 64 * NR_ * 2);
    ushort_t* wqt   = (ushort_t*)alloc((size_t)512 * 512 * 2);
    ushort_t* pwt   = (ushort_t*)alloc((size_t)512 * 448 * 2);
    ushort_t* projt = (ushort_t*)alloc((size_t)512 * 512 * 2);
    float*    srwt  = (float*)   alloc((size_t)256 * 64 * 4);
    float*    kvm1  = (float*)   alloc((size_t)B_ * NH_ * 49 * HD_ * 4);
    float*    kvm2  = (float*)   alloc((size_t)B_ * NH_ * 49 * HD_ * 4);
    float*    kv1   = (float*)   alloc((size_t)B_ * NH_ * 49 * 56 * 4);
    float*    kv2   = (float*)   alloc((size_t)B_ * NH_ * 49 * 56 * 4);
    float*    v1c   = (float*)   alloc((size_t)B_ * NH_ * 49 * HD_ * 4);
    float*    v2c   = (float*)   alloc((size_t)B_ * NH_ * 49 * HD_ * 4);
    ushort_t* xbf   = xcat;
    ushort_t* catb  = xcat;

    const int M = B_ * N_;   // 25088

    // 1. merged prep
    prep_kernel<<<9280, 256, 0, stream>>>(Wq, kvl_pw, proj_w, sr_w, x,
                                          wqt, pwt, projt, srwt, xbf);

    // 2. fused: q-GEMM + dwt + srlnkv
    fused3_kernel<<<5096, 256, 0, stream>>>(xbf, wqt, q16,
                                            kvl_dw, kvl_db, dwtb,
                                            x, srwt, sr_b, ln_g, ln_b, Wkv_g,
                                            kgb, vg);

    // 3. fused: pointwise GEMM -> kvl16 + lcg/vtrans -> vtb
    fused2_kernel<<<882, 256, 0, stream>>>(dwtb, pwt, kvl_pb, kvl16,
                                           vg, lcg_w, lcg_b, vtb);

    // 4. fused: attn_global (split-K=8) + local_mean
    fused_ag_lm_kernel<<<3136, 512, 0, stream>>>(q16, kgb, vtb, osp16, mls,
                                                 kvl16, kvm1, kvm2);

    // 5. fc @ sh (both branches)
    fcsh_merged_kernel<<<32, 64, 0, stream>>>(kvm1, fc1_w, sh1_w, kv1,
                                              kvm2, fc2_w, sh2_w, kv2);

    // 6. v-conv (both branches)
    {
        int blocks = (B_ * NH_ * 49 * HD_ + 255) / 256;
        vconv_merged_kernel<<<dim3(blocks, 2), 256, 0, stream>>>(
            kv1, lc1_w, lc1_b, v1c, kv2, lc2_w, lc2_b, v2c);
    }

    // 7. fused: attn_local + combine (disjoint catb columns)
    fused_local_comb_kernel<<<12544, 256, 0, stream>>>(q16, kv1, v1c, kv2, v2c,
                                                       osp16, mls, catb);

    // 8. out = catb @ projt^T + proj_b
    gemm_bf16_kernel<true, false><<<dim3(M / 128, 4), 256, 0, stream>>>(
        catb, projt, proj_b, out, 512, 512, 512);
}